// Round 1
// baseline (3419.134 us; speedup 1.0000x reference)
//
#include <hip/hip_runtime.h>

#define N_NODES 100000
#define N_EDGES 600000
#define D_NODE 128
#define D_EDGE 16
#define KINIT (D_NODE + D_EDGE)   // 144
#define UNITS 128

// ---------------- CSR build ----------------
__global__ void hist_kernel(const int* __restrict__ dst, int* __restrict__ cnt) {
  int e = blockIdx.x * 256 + threadIdx.x;
  if (e < N_EDGES) atomicAdd(&cnt[dst[e]], 1);
}

__global__ void scan_kernel(const int* __restrict__ cnt, int* __restrict__ off) {
  __shared__ int sums[1024];
  int tid = threadIdx.x;
  const int n = N_NODES;
  int chunk = (n + 1023) / 1024;
  int s0 = tid * chunk;
  int s1 = min(s0 + chunk, n);
  int s = 0;
  for (int i = s0; i < s1; ++i) s += cnt[i];
  sums[tid] = s;
  __syncthreads();
  for (int d = 1; d < 1024; d <<= 1) {
    int v = (tid >= d) ? sums[tid - d] : 0;
    __syncthreads();
    sums[tid] += v;
    __syncthreads();
  }
  int run = (tid == 0) ? 0 : sums[tid - 1];
  for (int i = s0; i < s1; ++i) { off[i] = run; run += cnt[i]; }
  if (tid == 1023) off[n] = sums[1023];
}

__global__ void fill_kernel(const int* __restrict__ dst, const int* __restrict__ src,
                            const int* __restrict__ off, int* __restrict__ cur,
                            int* __restrict__ csr_e, int* __restrict__ csr_s) {
  int e = blockIdx.x * 256 + threadIdx.x;
  if (e < N_EDGES) {
    int d = dst[e];
    int p = off[d] + atomicAdd(&cur[d], 1);
    csr_e[p] = e;
    csr_s[p] = src[e];
  }
}

// ---------------- segment sums (gather form) ----------------
__global__ __launch_bounds__(128) void segsum_h_kernel(const float* __restrict__ h,
                                                       const int* __restrict__ off,
                                                       const int* __restrict__ csr_e,
                                                       float* __restrict__ agg) {
  int n = blockIdx.x;
  int u = threadIdx.x;
  int p0 = off[n], p1 = off[n + 1];
  float acc = 0.f;
  for (int p = p0; p < p1; ++p) {
    int e = csr_e[p];
    acc += h[(size_t)e * UNITS + u];
  }
  agg[(size_t)n * UNITS + u] = acc;
}

__global__ __launch_bounds__(128) void gather_x_kernel(const float* __restrict__ x,
                                                       const int* __restrict__ off,
                                                       const int* __restrict__ csr_s,
                                                       float* __restrict__ agg,
                                                       int out_stride, int out_off) {
  int n = blockIdx.x;
  int u = threadIdx.x;
  int p0 = off[n], p1 = off[n + 1];
  float acc = 0.f;
  for (int p = p0; p < p1; ++p) {
    int sidx = csr_s[p];
    acc += x[(size_t)sidx * 128 + u];
  }
  agg[(size_t)n * out_stride + out_off + u] = acc;
}

// ---------------- shared GEMM tile k-loop ----------------
// tile: 64 rows x 128 units, 256 threads; thread = 4 rows x 8 units.
// msh: staged row operand in LDS, row stride MS (padded). W: global, row-major [K][128].
template<int K, int MS>
__device__ __forceinline__ void tile_kloop(const float* __restrict__ msh,
                                           const float* __restrict__ W,
                                           int rg, int ug, float (&acc)[4][8]) {
  const float4* Wv = (const float4*)W;
  #pragma unroll 2
  for (int k4 = 0; k4 < K / 4; ++k4) {
    float4 mv[4];
    #pragma unroll
    for (int j = 0; j < 4; ++j)
      mv[j] = *(const float4*)(&msh[(4 * rg + j) * MS + 4 * k4]);
    #pragma unroll
    for (int kk = 0; kk < 4; ++kk) {
      float4 w0 = Wv[(size_t)(4 * k4 + kk) * (UNITS / 4) + 2 * ug];
      float4 w1 = Wv[(size_t)(4 * k4 + kk) * (UNITS / 4) + 2 * ug + 1];
      #pragma unroll
      for (int j = 0; j < 4; ++j) {
        float mk = (kk == 0) ? mv[j].x : (kk == 1) ? mv[j].y : (kk == 2) ? mv[j].z : mv[j].w;
        acc[j][0] = fmaf(mk, w0.x, acc[j][0]);
        acc[j][1] = fmaf(mk, w0.y, acc[j][1]);
        acc[j][2] = fmaf(mk, w0.z, acc[j][2]);
        acc[j][3] = fmaf(mk, w0.w, acc[j][3]);
        acc[j][4] = fmaf(mk, w1.x, acc[j][4]);
        acc[j][5] = fmaf(mk, w1.y, acc[j][5]);
        acc[j][6] = fmaf(mk, w1.z, acc[j][6]);
        acc[j][7] = fmaf(mk, w1.w, acc[j][7]);
      }
    }
  }
}

// ---------------- init edge state: h = relu([nf[src] | ef] @ W_init + b) ----------------
#define MS_I (KINIT + 4)   // 148
__global__ __launch_bounds__(256) void init_edge_kernel(const float* __restrict__ nf,
                                                        const float* __restrict__ ef,
                                                        const float* __restrict__ W,
                                                        const float* __restrict__ b,
                                                        const int* __restrict__ src,
                                                        float* __restrict__ h) {
  __shared__ float msh[64 * MS_I];
  int t = threadIdx.x;
  int base = blockIdx.x * 64;
  {
    int i = t >> 2, q = t & 3;
    int e = base + i;
    int s = src[e];
    const float* nrow = nf + (size_t)s * D_NODE;
    const float* erow = ef + (size_t)e * D_EDGE;
    #pragma unroll
    for (int jj = 0; jj < 8; ++jj) {
      int k = q * 4 + jj * 16;
      *(float4*)(&msh[i * MS_I + k]) = *(const float4*)(nrow + k);
    }
    *(float4*)(&msh[i * MS_I + 128 + q * 4]) = *(const float4*)(erow + q * 4);
  }
  __syncthreads();
  int ug = t & 15, rg = t >> 4;
  float acc[4][8];
  #pragma unroll
  for (int j = 0; j < 4; ++j)
    #pragma unroll
    for (int uu = 0; uu < 8; ++uu) acc[j][uu] = 0.f;
  tile_kloop<KINIT, MS_I>(msh, W, rg, ug, acc);
  float4 b0 = *(const float4*)(b + 8 * ug);
  float4 b1 = *(const float4*)(b + 8 * ug + 4);
  #pragma unroll
  for (int j = 0; j < 4; ++j) {
    int e = base + 4 * rg + j;
    float* hr = h + (size_t)e * UNITS + 8 * ug;
    float4 o0, o1;
    o0.x = fmaxf(acc[j][0] + b0.x, 0.f);
    o0.y = fmaxf(acc[j][1] + b0.y, 0.f);
    o0.z = fmaxf(acc[j][2] + b0.z, 0.f);
    o0.w = fmaxf(acc[j][3] + b0.w, 0.f);
    o1.x = fmaxf(acc[j][4] + b1.x, 0.f);
    o1.y = fmaxf(acc[j][5] + b1.y, 0.f);
    o1.z = fmaxf(acc[j][6] + b1.z, 0.f);
    o1.w = fmaxf(acc[j][7] + b1.w, 0.f);
    *(float4*)hr = o0;
    *(float4*)(hr + 4) = o1;
  }
}

// ---------------- edge update (in place, pairs within tile): h = relu(h + (agg[src]-h[rev]) @ W + b) ----------------
#define MS_E (UNITS + 4)   // 132
__global__ __launch_bounds__(256) void edge_update_kernel(const float* __restrict__ agg,
                                                          const int* __restrict__ src,
                                                          const float* __restrict__ W,
                                                          const float* __restrict__ b,
                                                          float* __restrict__ h) {
  __shared__ float msh[64 * MS_E];
  int t = threadIdx.x;
  int base = blockIdx.x * 64;
  {
    int i = t >> 2, q = t & 3;
    int e = base + i;
    int erev = e ^ 1;                 // reverse edge lives in the same tile
    int s = src[e];
    const float* arow = agg + (size_t)s * UNITS;
    const float* hrow = h + (size_t)erev * UNITS;
    #pragma unroll
    for (int jj = 0; jj < 8; ++jj) {
      int k = q * 4 + jj * 16;
      float4 a = *(const float4*)(arow + k);
      float4 hv = *(const float4*)(hrow + k);
      float4 r;
      r.x = a.x - hv.x; r.y = a.y - hv.y; r.z = a.z - hv.z; r.w = a.w - hv.w;
      *(float4*)(&msh[i * MS_E + k]) = r;
    }
  }
  __syncthreads();
  int ug = t & 15, rg = t >> 4;
  float acc[4][8];
  #pragma unroll
  for (int j = 0; j < 4; ++j)
    #pragma unroll
    for (int uu = 0; uu < 8; ++uu) acc[j][uu] = 0.f;
  tile_kloop<UNITS, MS_E>(msh, W, rg, ug, acc);
  float4 b0 = *(const float4*)(b + 8 * ug);
  float4 b1 = *(const float4*)(b + 8 * ug + 4);
  #pragma unroll
  for (int j = 0; j < 4; ++j) {
    int e = base + 4 * rg + j;
    float* hr = h + (size_t)e * UNITS + 8 * ug;
    float4 h0 = *(const float4*)hr;
    float4 h1 = *(const float4*)(hr + 4);
    float4 o0, o1;
    o0.x = fmaxf(acc[j][0] + h0.x + b0.x, 0.f);
    o0.y = fmaxf(acc[j][1] + h0.y + b0.y, 0.f);
    o0.z = fmaxf(acc[j][2] + h0.z + b0.z, 0.f);
    o0.w = fmaxf(acc[j][3] + h0.w + b0.w, 0.f);
    o1.x = fmaxf(acc[j][4] + h1.x + b1.x, 0.f);
    o1.y = fmaxf(acc[j][5] + h1.y + b1.y, 0.f);
    o1.z = fmaxf(acc[j][6] + h1.z + b1.z, 0.f);
    o1.w = fmaxf(acc[j][7] + h1.w + b1.w, 0.f);
    *(float4*)hr = o0;
    *(float4*)(hr + 4) = o1;
  }
}

// ---------------- GIN step 0: K=256 (v = (1+eps)*[nf|readout] + agg256), out = relu(v@W_gin0 + b) ----------------
__global__ __launch_bounds__(256) void gin0_kernel(const float* __restrict__ nf,
                                                   const float* __restrict__ readout,
                                                   const float* __restrict__ agg,   // [N,256]
                                                   const float* __restrict__ W,     // [256,128]
                                                   const float* __restrict__ b,
                                                   const float* __restrict__ eps,
                                                   float* __restrict__ xout) {
  __shared__ float msh[64 * MS_E];
  int t = threadIdx.x;
  int base = blockIdx.x * 64;
  float epsv = 1.f + eps[0];
  int ug = t & 15, rg = t >> 4;
  float acc[4][8];
  #pragma unroll
  for (int j = 0; j < 4; ++j)
    #pragma unroll
    for (int uu = 0; uu < 8; ++uu) acc[j][uu] = 0.f;
  #pragma unroll
  for (int chunk = 0; chunk < 2; ++chunk) {
    {
      int i = t >> 2, q = t & 3;
      int n = base + i;
      int nc = (n < N_NODES) ? n : 0;
      const float* xrow = (chunk == 0) ? (nf + (size_t)nc * 128) : (readout + (size_t)nc * 128);
      const float* arow = agg + (size_t)nc * 256 + chunk * 128;
      #pragma unroll
      for (int jj = 0; jj < 8; ++jj) {
        int k = q * 4 + jj * 16;
        float4 xv = *(const float4*)(xrow + k);
        float4 av = *(const float4*)(arow + k);
        float4 r;
        r.x = fmaf(epsv, xv.x, av.x); r.y = fmaf(epsv, xv.y, av.y);
        r.z = fmaf(epsv, xv.z, av.z); r.w = fmaf(epsv, xv.w, av.w);
        *(float4*)(&msh[i * MS_E + k]) = r;
      }
    }
    __syncthreads();
    tile_kloop<UNITS, MS_E>(msh, W + (size_t)chunk * 128 * UNITS, rg, ug, acc);
    __syncthreads();
  }
  float4 b0 = *(const float4*)(b + 8 * ug);
  float4 b1 = *(const float4*)(b + 8 * ug + 4);
  #pragma unroll
  for (int j = 0; j < 4; ++j) {
    int n = base + 4 * rg + j;
    if (n >= N_NODES) continue;
    float* xr = xout + (size_t)n * UNITS + 8 * ug;
    float4 o0, o1;
    o0.x = fmaxf(acc[j][0] + b0.x, 0.f);
    o0.y = fmaxf(acc[j][1] + b0.y, 0.f);
    o0.z = fmaxf(acc[j][2] + b0.z, 0.f);
    o0.w = fmaxf(acc[j][3] + b0.w, 0.f);
    o1.x = fmaxf(acc[j][4] + b1.x, 0.f);
    o1.y = fmaxf(acc[j][5] + b1.y, 0.f);
    o1.z = fmaxf(acc[j][6] + b1.z, 0.f);
    o1.w = fmaxf(acc[j][7] + b1.w, 0.f);
    *(float4*)xr = o0;
    *(float4*)(xr + 4) = o1;
  }
}

// ---------------- GIN steps 1..3: K=128, in place on x ----------------
__global__ __launch_bounds__(256) void gin_kernel(const float* __restrict__ x,
                                                  const float* __restrict__ agg,   // [N,128]
                                                  const float* __restrict__ W,     // [128,128]
                                                  const float* __restrict__ b,
                                                  const float* __restrict__ eps,
                                                  float* __restrict__ xout) {
  __shared__ float msh[64 * MS_E];
  int t = threadIdx.x;
  int base = blockIdx.x * 64;
  float epsv = 1.f + eps[0];
  {
    int i = t >> 2, q = t & 3;
    int n = base + i;
    int nc = (n < N_NODES) ? n : 0;
    const float* xrow = x + (size_t)nc * UNITS;
    const float* arow = agg + (size_t)nc * UNITS;
    #pragma unroll
    for (int jj = 0; jj < 8; ++jj) {
      int k = q * 4 + jj * 16;
      float4 xv = *(const float4*)(xrow + k);
      float4 av = *(const float4*)(arow + k);
      float4 r;
      r.x = fmaf(epsv, xv.x, av.x); r.y = fmaf(epsv, xv.y, av.y);
      r.z = fmaf(epsv, xv.z, av.z); r.w = fmaf(epsv, xv.w, av.w);
      *(float4*)(&msh[i * MS_E + k]) = r;
    }
  }
  __syncthreads();
  int ug = t & 15, rg = t >> 4;
  float acc[4][8];
  #pragma unroll
  for (int j = 0; j < 4; ++j)
    #pragma unroll
    for (int uu = 0; uu < 8; ++uu) acc[j][uu] = 0.f;
  tile_kloop<UNITS, MS_E>(msh, W, rg, ug, acc);
  float4 b0 = *(const float4*)(b + 8 * ug);
  float4 b1 = *(const float4*)(b + 8 * ug + 4);
  #pragma unroll
  for (int j = 0; j < 4; ++j) {
    int n = base + 4 * rg + j;
    if (n >= N_NODES) continue;
    float* xr = xout + (size_t)n * UNITS + 8 * ug;
    float4 o0, o1;
    o0.x = fmaxf(acc[j][0] + b0.x, 0.f);
    o0.y = fmaxf(acc[j][1] + b0.y, 0.f);
    o0.z = fmaxf(acc[j][2] + b0.z, 0.f);
    o0.w = fmaxf(acc[j][3] + b0.w, 0.f);
    o1.x = fmaxf(acc[j][4] + b1.x, 0.f);
    o1.y = fmaxf(acc[j][5] + b1.y, 0.f);
    o1.z = fmaxf(acc[j][6] + b1.z, 0.f);
    o1.w = fmaxf(acc[j][7] + b1.w, 0.f);
    *(float4*)xr = o0;
    *(float4*)(xr + 4) = o1;
  }
}

extern "C" void kernel_launch(void* const* d_in, const int* in_sizes, int n_in,
                              void* d_out, int out_size, void* d_ws, size_t ws_size,
                              hipStream_t stream) {
  const float* nf     = (const float*)d_in[0];
  const float* ef     = (const float*)d_in[1];
  const float* W_init = (const float*)d_in[2];
  const float* b_init = (const float*)d_in[3];
  const float* W_edge = (const float*)d_in[4];
  const float* b_edge = (const float*)d_in[5];
  const float* W_gin0 = (const float*)d_in[6];
  const float* W_gin  = (const float*)d_in[7];
  const float* b_gin  = (const float*)d_in[8];
  const float* eps    = (const float*)d_in[9];
  const int* esrc     = (const int*)d_in[10];
  const int* edst     = (const int*)d_in[11];
  // d_in[12] = edge_rev, equals e^1 by construction; relied upon implicitly.

  float* xout = (float*)d_out;                          // [N,128]
  float* h    = xout + (size_t)N_NODES * UNITS;         // [E,128]

  float* agg     = (float*)d_ws;                        // [N,256] (edge steps use [:,0:128])
  float* readout = agg + (size_t)N_NODES * 256;         // [N,128]
  int* csr_off   = (int*)(readout + (size_t)N_NODES * 128);  // N+1
  int* cursor    = csr_off + (N_NODES + 1);             // N (doubles as histogram)
  int* csr_e     = cursor + N_NODES;                    // E
  int* csr_s     = csr_e + N_EDGES;                     // E

  // ---- CSR by dst ----
  hipMemsetAsync(cursor, 0, N_NODES * sizeof(int), stream);
  hist_kernel<<<(N_EDGES + 255) / 256, 256, 0, stream>>>(edst, cursor);
  scan_kernel<<<1, 1024, 0, stream>>>(cursor, csr_off);
  hipMemsetAsync(cursor, 0, N_NODES * sizeof(int), stream);
  fill_kernel<<<(N_EDGES + 255) / 256, 256, 0, stream>>>(edst, esrc, csr_off, cursor, csr_e, csr_s);

  // ---- init edge states ----
  init_edge_kernel<<<N_EDGES / 64, 256, 0, stream>>>(nf, ef, W_init, b_init, esrc, h);

  // ---- EdgeConv steps (in place on h) ----
  for (int t = 0; t < 4; ++t) {
    segsum_h_kernel<<<N_NODES, 128, 0, stream>>>(h, csr_off, csr_e, agg);
    edge_update_kernel<<<N_EDGES / 64, 256, 0, stream>>>(
        agg, esrc, W_edge + (size_t)t * UNITS * UNITS, b_edge + (size_t)t * UNITS, h);
  }

  // ---- readout ----
  segsum_h_kernel<<<N_NODES, 128, 0, stream>>>(h, csr_off, csr_e, readout);

  // ---- GIN step 0 (x0 = [nf | readout], never materialized) ----
  gather_x_kernel<<<N_NODES, 128, 0, stream>>>(nf, csr_off, csr_s, agg, 256, 0);
  gather_x_kernel<<<N_NODES, 128, 0, stream>>>(readout, csr_off, csr_s, agg, 256, 128);
  gin0_kernel<<<(N_NODES + 63) / 64, 256, 0, stream>>>(nf, readout, agg, W_gin0, b_gin, eps, xout);

  // ---- GIN steps 1..3 (in place on x) ----
  for (int t = 1; t < 4; ++t) {
    gather_x_kernel<<<N_NODES, 128, 0, stream>>>(xout, csr_off, csr_s, agg, 128, 0);
    gin_kernel<<<(N_NODES + 63) / 64, 256, 0, stream>>>(
        xout, agg, W_gin + (size_t)(t - 1) * UNITS * UNITS, b_gin + (size_t)t * UNITS, eps + t, xout);
  }

  (void)in_sizes; (void)n_in; (void)out_size; (void)ws_size;
}

// Round 2
// 2488.106 us; speedup vs baseline: 1.3742x; 1.3742x over previous
//
#include <hip/hip_runtime.h>

#define N_NODES 100000
#define N_EDGES 600000

typedef __attribute__((ext_vector_type(8))) short short8v;
typedef __attribute__((ext_vector_type(4))) short short4v;
typedef __attribute__((ext_vector_type(4))) float f32x4;
typedef __attribute__((ext_vector_type(8))) __bf16 bf16x8v;

__device__ __forceinline__ short f2bf(float f) {
  unsigned u = __builtin_bit_cast(unsigned, f);
  unsigned r = (u + 0x7fffu + ((u >> 16) & 1u)) >> 16;
  return (short)r;
}

// ---------------- CSR build ----------------
__global__ void hist_kernel(const int* __restrict__ dst, int* __restrict__ cnt) {
  int e = blockIdx.x * 256 + threadIdx.x;
  if (e < N_EDGES) atomicAdd(&cnt[dst[e]], 1);
}

__global__ void scan_kernel(const int* __restrict__ cnt, int* __restrict__ off) {
  __shared__ int sums[1024];
  int tid = threadIdx.x;
  const int n = N_NODES;
  int chunk = (n + 1023) / 1024;
  int s0 = tid * chunk;
  int s1 = min(s0 + chunk, n);
  int s = 0;
  for (int i = s0; i < s1; ++i) s += cnt[i];
  sums[tid] = s;
  __syncthreads();
  for (int d = 1; d < 1024; d <<= 1) {
    int v = (tid >= d) ? sums[tid - d] : 0;
    __syncthreads();
    sums[tid] += v;
    __syncthreads();
  }
  int run = (tid == 0) ? 0 : sums[tid - 1];
  for (int i = s0; i < s1; ++i) { off[i] = run; run += cnt[i]; }
  if (tid == 1023) off[n] = sums[1023];
}

__global__ void fill_kernel(const int* __restrict__ dst, const int* __restrict__ src,
                            const int* __restrict__ off, int* __restrict__ cur,
                            int* __restrict__ csr_e, int* __restrict__ csr_s) {
  int e = blockIdx.x * 256 + threadIdx.x;
  if (e < N_EDGES) {
    int d = dst[e];
    int p = off[d] + atomicAdd(&cur[d], 1);
    csr_e[p] = e;
    csr_s[p] = src[e];
  }
}

// ---------------- segment sums (gather form) ----------------
__global__ __launch_bounds__(128) void segsum_h_kernel(const float* __restrict__ h,
                                                       const int* __restrict__ off,
                                                       const int* __restrict__ csr_e,
                                                       float* __restrict__ agg) {
  int n = blockIdx.x;
  int u = threadIdx.x;
  int p0 = off[n], p1 = off[n + 1];
  float acc = 0.f;
  for (int p = p0; p < p1; ++p) {
    int e = csr_e[p];
    acc += h[(size_t)e * 128 + u];
  }
  agg[(size_t)n * 128 + u] = acc;
}

__global__ __launch_bounds__(128) void gather_x_kernel(const float* __restrict__ x,
                                                       const int* __restrict__ off,
                                                       const int* __restrict__ csr_s,
                                                       float* __restrict__ agg) {
  int n = blockIdx.x;
  int u = threadIdx.x;
  int p0 = off[n], p1 = off[n + 1];
  float acc = 0.f;
  for (int p = p0; p < p1; ++p) {
    int s = csr_s[p];
    acc += x[(size_t)s * 128 + u];
  }
  agg[(size_t)n * 128 + u] = acc;
}

__global__ __launch_bounds__(128) void gather2_kernel(const float* __restrict__ xa,
                                                      const float* __restrict__ xb,
                                                      const int* __restrict__ off,
                                                      const int* __restrict__ csr_s,
                                                      float* __restrict__ aggA,
                                                      float* __restrict__ aggB) {
  int n = blockIdx.x;
  int u = threadIdx.x;
  int p0 = off[n], p1 = off[n + 1];
  float sa = 0.f, sb = 0.f;
  for (int p = p0; p < p1; ++p) {
    int s = csr_s[p];
    sa += xa[(size_t)s * 128 + u];
    sb += xb[(size_t)s * 128 + u];
  }
  aggA[(size_t)n * 128 + u] = sa;
  aggB[(size_t)n * 128 + u] = sb;
}

// ---------------- unified MFMA GEMM ----------------
// Tile: 64 rows x 128 cols, 256 threads (4 waves). Wave w: all 64 rows x cols
// [32w, 32w+32). W fragments live in registers for the whole kernel
// (persistent grid-stride over tiles). A staged in LDS as bf16, row stride
// KSTEPS*32+8 shorts (272B/336B -> <=2-way bank conflicts on ds_read_b128).
// k-mapping within a 32-k step: k = 32s + 8g + j for both A and B fragments
// (any consistent bijection is correct since k is reduced).
#define PREP_INIT 0
#define PREP_EDGE 1
#define PREP_GIN  2
#define EPI_RAW 0
#define EPI_BR  1
#define EPI_ABR 2

template<int KSTEPS, int PREPM, int EPIM>
__global__ __launch_bounds__(256, 3) void mfma_gemm(
    const float* __restrict__ Wf, int KREAL,
    const float* __restrict__ bias,
    const float* __restrict__ P0,      // INIT: nf; EDGE: agg; GIN: x
    const float* __restrict__ P1,      // INIT: ef; EDGE: h (rev-read); GIN: agg
    const int* __restrict__ srcIdx,    // INIT/EDGE: edge_src
    const float* __restrict__ epsp,    // GIN: eps scalar
    const float* addsrc,               // EPI_ABR: residual / partial
    float* Out, int numRows) {
  constexpr int RS = KSTEPS * 32 + 8;
  __shared__ short amem[64 * RS];
  const int t = threadIdx.x;
  const int l = t & 63;
  const int w = t >> 6;
  const int g = l >> 4;
  const int n0 = l & 15;

  // ---- preload W fragments (wave w covers col tiles 2w, 2w+1) ----
  short8v wf[KSTEPS][2];
  #pragma unroll
  for (int s = 0; s < KSTEPS; ++s) {
    #pragma unroll
    for (int ct = 0; ct < 2; ++ct) {
      short8v v;
      #pragma unroll
      for (int j = 0; j < 8; ++j) {
        int k = 32 * s + 8 * g + j;
        float wv = (k < KREAL) ? Wf[(size_t)k * 128 + (2 * w + ct) * 16 + n0] : 0.f;
        v[j] = f2bf(wv);
      }
      wf[s][ct] = v;
    }
  }
  float bb[2] = {0.f, 0.f};
  if constexpr (EPIM != EPI_RAW) {
    #pragma unroll
    for (int ct = 0; ct < 2; ++ct) bb[ct] = bias[(2 * w + ct) * 16 + n0];
  }
  float alpha = 0.f;
  if constexpr (PREPM == PREP_GIN) alpha = 1.f + epsp[0];

  const int numTiles = (numRows + 63) >> 6;
  for (int tile = blockIdx.x; tile < numTiles; tile += gridDim.x) {
    const int base = tile * 64;
    // ---- prep: stage A tile (bf16) ----
    {
      const int i = t >> 2, q = t & 3;
      const int row = base + i;
      if constexpr (PREPM == PREP_INIT) {
        const int sn = srcIdx[row];
        const float* nrow = P0 + (size_t)sn * 128;
        #pragma unroll
        for (int cc = 0; cc < 8; ++cc) {
          int col = q * 32 + cc * 4;
          float4 vv = *(const float4*)(nrow + col);
          short4v o = {f2bf(vv.x), f2bf(vv.y), f2bf(vv.z), f2bf(vv.w)};
          *(short4v*)(&amem[i * RS + col]) = o;
        }
        #pragma unroll
        for (int z = 0; z < 2; ++z) {
          int cc = 2 * q + z;
          int col = 128 + cc * 4;
          short4v o = {0, 0, 0, 0};
          if (col < 144) {
            float4 vv = *(const float4*)(P1 + (size_t)row * 16 + (col - 128));
            o = {f2bf(vv.x), f2bf(vv.y), f2bf(vv.z), f2bf(vv.w)};
          }
          *(short4v*)(&amem[i * RS + col]) = o;
        }
      } else if constexpr (PREPM == PREP_EDGE) {
        const int sn = srcIdx[row];
        const float* arow = P0 + (size_t)sn * 128;
        const float* hrow = P1 + (size_t)(row ^ 1) * 128;
        #pragma unroll
        for (int cc = 0; cc < 8; ++cc) {
          int col = q * 32 + cc * 4;
          float4 av = *(const float4*)(arow + col);
          float4 hv = *(const float4*)(hrow + col);
          short4v o = {f2bf(av.x - hv.x), f2bf(av.y - hv.y),
                       f2bf(av.z - hv.z), f2bf(av.w - hv.w)};
          *(short4v*)(&amem[i * RS + col]) = o;
        }
      } else {
        const int rc = (row < numRows) ? row : (numRows - 1);
        const float* xrow = P0 + (size_t)rc * 128;
        const float* grow = P1 + (size_t)rc * 128;
        #pragma unroll
        for (int cc = 0; cc < 8; ++cc) {
          int col = q * 32 + cc * 4;
          float4 xv = *(const float4*)(xrow + col);
          float4 av = *(const float4*)(grow + col);
          short4v o = {f2bf(fmaf(alpha, xv.x, av.x)), f2bf(fmaf(alpha, xv.y, av.y)),
                       f2bf(fmaf(alpha, xv.z, av.z)), f2bf(fmaf(alpha, xv.w, av.w))};
          *(short4v*)(&amem[i * RS + col]) = o;
        }
      }
    }
    __syncthreads();
    // ---- MFMA main loop ----
    f32x4 acc[4][2];
    #pragma unroll
    for (int rt = 0; rt < 4; ++rt)
      #pragma unroll
      for (int ct = 0; ct < 2; ++ct) acc[rt][ct] = (f32x4){0.f, 0.f, 0.f, 0.f};
    #pragma unroll
    for (int s = 0; s < KSTEPS; ++s) {
      bf16x8v af[4];
      #pragma unroll
      for (int rt = 0; rt < 4; ++rt) {
        short8v araw = *(const short8v*)(&amem[(16 * rt + n0) * RS + s * 32 + g * 8]);
        af[rt] = __builtin_bit_cast(bf16x8v, araw);
      }
      #pragma unroll
      for (int rt = 0; rt < 4; ++rt)
        #pragma unroll
        for (int ct = 0; ct < 2; ++ct)
          acc[rt][ct] = __builtin_amdgcn_mfma_f32_16x16x32_bf16(
              af[rt], __builtin_bit_cast(bf16x8v, wf[s][ct]), acc[rt][ct], 0, 0, 0);
    }
    // ---- epilogue: C/D layout col=lane&15, row=(lane>>4)*4+reg ----
    #pragma unroll
    for (int rt = 0; rt < 4; ++rt) {
      #pragma unroll
      for (int ct = 0; ct < 2; ++ct) {
        #pragma unroll
        for (int r = 0; r < 4; ++r) {
          int row = base + 16 * rt + 4 * g + r;
          if (row < numRows) {
            size_t idx = (size_t)row * 128 + (2 * w + ct) * 16 + n0;
            float o = acc[rt][ct][r];
            if constexpr (EPIM == EPI_ABR) o += addsrc[idx];
            if constexpr (EPIM != EPI_RAW) o = fmaxf(o + bb[ct], 0.f);
            Out[idx] = o;
          }
        }
      }
    }
    __syncthreads();
  }
}

extern "C" void kernel_launch(void* const* d_in, const int* in_sizes, int n_in,
                              void* d_out, int out_size, void* d_ws, size_t ws_size,
                              hipStream_t stream) {
  const float* nf     = (const float*)d_in[0];
  const float* ef     = (const float*)d_in[1];
  const float* W_init = (const float*)d_in[2];
  const float* b_init = (const float*)d_in[3];
  const float* W_edge = (const float*)d_in[4];
  const float* b_edge = (const float*)d_in[5];
  const float* W_gin0 = (const float*)d_in[6];
  const float* W_gin  = (const float*)d_in[7];
  const float* b_gin  = (const float*)d_in[8];
  const float* eps    = (const float*)d_in[9];
  const int* esrc     = (const int*)d_in[10];
  const int* edst     = (const int*)d_in[11];
  // d_in[12] = edge_rev == e^1 by construction.

  float* xout = (float*)d_out;                      // [N,128]
  float* h    = xout + (size_t)N_NODES * 128;       // [E,128]

  float* aggA    = (float*)d_ws;                    // [N,128]
  float* aggB    = aggA + (size_t)N_NODES * 128;    // [N,128]
  float* readout = aggB + (size_t)N_NODES * 128;    // [N,128]
  int* csr_off = (int*)(readout + (size_t)N_NODES * 128);  // N+1
  int* cursor  = csr_off + (N_NODES + 1);           // N (also histogram)
  int* csr_e   = cursor + N_NODES;                  // E
  int* csr_s   = csr_e + N_EDGES;                   // E

  // ---- CSR by dst ----
  hipMemsetAsync(cursor, 0, N_NODES * sizeof(int), stream);
  hist_kernel<<<(N_EDGES + 255) / 256, 256, 0, stream>>>(edst, cursor);
  scan_kernel<<<1, 1024, 0, stream>>>(cursor, csr_off);
  hipMemsetAsync(cursor, 0, N_NODES * sizeof(int), stream);
  fill_kernel<<<(N_EDGES + 255) / 256, 256, 0, stream>>>(edst, esrc, csr_off, cursor, csr_e, csr_s);

  // ---- init edge states: h = relu([nf[src]|ef] @ W_init + b) ----
  mfma_gemm<5, PREP_INIT, EPI_BR><<<1024, 256, 0, stream>>>(
      W_init, 144, b_init, nf, ef, esrc, nullptr, nullptr, h, N_EDGES);

  // ---- EdgeConv steps (in place on h; rev edge lives in same 64-tile) ----
  for (int t = 0; t < 4; ++t) {
    segsum_h_kernel<<<N_NODES, 128, 0, stream>>>(h, csr_off, csr_e, aggA);
    mfma_gemm<4, PREP_EDGE, EPI_ABR><<<1024, 256, 0, stream>>>(
        W_edge + (size_t)t * 128 * 128, 128, b_edge + (size_t)t * 128,
        aggA, h, esrc, nullptr, h, h, N_EDGES);
  }

  // ---- readout ----
  segsum_h_kernel<<<N_NODES, 128, 0, stream>>>(h, csr_off, csr_e, readout);

  // ---- GIN step 0: split K=256 into two K=128 passes ----
  gather2_kernel<<<N_NODES, 128, 0, stream>>>(nf, readout, csr_off, csr_s, aggA, aggB);
  // part A: aggA := ((1+e)*nf + aggA) @ W_gin0[0:128]   (raw, in place)
  mfma_gemm<4, PREP_GIN, EPI_RAW><<<1024, 256, 0, stream>>>(
      W_gin0, 128, nullptr, nf, aggA, nullptr, eps, nullptr, aggA, N_NODES);
  // part B: x = relu(((1+e)*readout + aggB) @ W_gin0[128:256] + aggA + b)
  mfma_gemm<4, PREP_GIN, EPI_ABR><<<1024, 256, 0, stream>>>(
      W_gin0 + (size_t)128 * 128, 128, b_gin, readout, aggB, nullptr, eps, aggA, xout, N_NODES);

  // ---- GIN steps 1..3 (in place on x) ----
  for (int t = 1; t < 4; ++t) {
    gather_x_kernel<<<N_NODES, 128, 0, stream>>>(xout, csr_off, csr_s, aggA);
    mfma_gemm<4, PREP_GIN, EPI_BR><<<1024, 256, 0, stream>>>(
        W_gin + (size_t)(t - 1) * 128 * 128, 128, b_gin + (size_t)t * 128,
        xout, aggA, nullptr, eps + t, nullptr, xout, N_NODES);
  }

  (void)in_sizes; (void)n_in; (void)out_size; (void)ws_size;
}

// Round 3
// 1784.761 us; speedup vs baseline: 1.9157x; 1.3941x over previous
//
#include <hip/hip_runtime.h>

#define N_NODES 100000
#define N_EDGES 600000

typedef unsigned short u16;
typedef __attribute__((ext_vector_type(8))) short short8v;
typedef __attribute__((ext_vector_type(4))) short short4v;
typedef __attribute__((ext_vector_type(4))) float f32x4;
typedef __attribute__((ext_vector_type(8))) __bf16 bf16x8v;

__device__ __forceinline__ u16 f2bf(float f) {
  unsigned u = __builtin_bit_cast(unsigned, f);
  unsigned r = (u + 0x7fffu + ((u >> 16) & 1u)) >> 16;
  return (u16)r;
}
__device__ __forceinline__ float bf2f(u16 v) {
  unsigned u = ((unsigned)v) << 16;
  return __builtin_bit_cast(float, u);
}

// ---------------- CSR build ----------------
__global__ void hist_kernel(const int* __restrict__ dst, int* __restrict__ cnt) {
  int e = blockIdx.x * 256 + threadIdx.x;
  if (e < N_EDGES) atomicAdd(&cnt[dst[e]], 1);
}

__global__ void scan_kernel(const int* __restrict__ cnt, int* __restrict__ off) {
  __shared__ int sums[1024];
  int tid = threadIdx.x;
  const int n = N_NODES;
  int chunk = (n + 1023) / 1024;
  int s0 = tid * chunk;
  int s1 = min(s0 + chunk, n);
  int s = 0;
  for (int i = s0; i < s1; ++i) s += cnt[i];
  sums[tid] = s;
  __syncthreads();
  for (int d = 1; d < 1024; d <<= 1) {
    int v = (tid >= d) ? sums[tid - d] : 0;
    __syncthreads();
    sums[tid] += v;
    __syncthreads();
  }
  int run = (tid == 0) ? 0 : sums[tid - 1];
  for (int i = s0; i < s1; ++i) { off[i] = run; run += cnt[i]; }
  if (tid == 1023) off[n] = sums[1023];
}

__global__ void fill_kernel(const int* __restrict__ dst, const int* __restrict__ src,
                            const int* __restrict__ off, int* __restrict__ cur,
                            int* __restrict__ csr_e, int* __restrict__ csr_s) {
  int e = blockIdx.x * 256 + threadIdx.x;
  if (e < N_EDGES) {
    int d = dst[e];
    int p = off[d] + atomicAdd(&cur[d], 1);
    csr_e[p] = e;
    csr_s[p] = src[e];
  }
}

// ---------------- segment sums ----------------
// bf16 h -> bf16 agg; one wave per node (full 256B row per wave), 4 nodes/block
__global__ __launch_bounds__(256) void segsum_hbf_kernel(const u16* __restrict__ hbf,
                                                         const int* __restrict__ off,
                                                         const int* __restrict__ csr_e,
                                                         u16* __restrict__ aggb) {
  int node = blockIdx.x * 4 + (threadIdx.x >> 6);
  int l = threadIdx.x & 63;
  int p0 = off[node], p1 = off[node + 1];
  float a0 = 0.f, a1 = 0.f;
  for (int p = p0; p < p1; ++p) {
    int e = csr_e[p];
    unsigned u = *(const unsigned*)(hbf + (size_t)e * 128 + 2 * l);
    a0 += __builtin_bit_cast(float, u << 16);
    a1 += __builtin_bit_cast(float, u & 0xffff0000u);
  }
  unsigned o = (unsigned)f2bf(a0) | (((unsigned)f2bf(a1)) << 16);
  *(unsigned*)(aggb + (size_t)node * 128 + 2 * l) = o;
}

// f32 h -> f32 agg (readout over final h in d_out)
__global__ __launch_bounds__(128) void segsum_h_kernel(const float* __restrict__ h,
                                                       const int* __restrict__ off,
                                                       const int* __restrict__ csr_e,
                                                       float* __restrict__ agg) {
  int n = blockIdx.x;
  int u = threadIdx.x;
  int p0 = off[n], p1 = off[n + 1];
  float acc = 0.f;
  for (int p = p0; p < p1; ++p) {
    int e = csr_e[p];
    acc += h[(size_t)e * 128 + u];
  }
  agg[(size_t)n * 128 + u] = acc;
}

__global__ __launch_bounds__(128) void gather_x_kernel(const float* __restrict__ x,
                                                       const int* __restrict__ off,
                                                       const int* __restrict__ csr_s,
                                                       float* __restrict__ agg) {
  int n = blockIdx.x;
  int u = threadIdx.x;
  int p0 = off[n], p1 = off[n + 1];
  float acc = 0.f;
  for (int p = p0; p < p1; ++p) {
    int s = csr_s[p];
    acc += x[(size_t)s * 128 + u];
  }
  agg[(size_t)n * 128 + u] = acc;
}

__global__ __launch_bounds__(128) void gather2_kernel(const float* __restrict__ xa,
                                                      const float* __restrict__ xb,
                                                      const int* __restrict__ off,
                                                      const int* __restrict__ csr_s,
                                                      float* __restrict__ aggA,
                                                      float* __restrict__ aggB) {
  int n = blockIdx.x;
  int u = threadIdx.x;
  int p0 = off[n], p1 = off[n + 1];
  float sa = 0.f, sb = 0.f;
  for (int p = p0; p < p1; ++p) {
    int s = csr_s[p];
    sa += xa[(size_t)s * 128 + u];
    sb += xb[(size_t)s * 128 + u];
  }
  aggA[(size_t)n * 128 + u] = sa;
  aggB[(size_t)n * 128 + u] = sb;
}

// ---------------- unified MFMA GEMM ----------------
// Tile 64 rows x 128 cols, 256 threads (4 waves); wave w -> cols [32w,32w+32).
// W fragments in registers; A staged in LDS bf16 (row stride RS shorts).
// k-mapping k = 32s+8g+j consistent between A and B fragments.
#define PREP_INIT 0
#define PREP_EDGE 1
#define PREP_GIN  2
#define EPI_RAW 0
#define EPI_BR  1
#define EPI_ABR 2

template<int KSTEPS, int PREPM, int EPIM, int OUTBF>
__global__ __launch_bounds__(256, 3) void mfma_gemm(
    const float* __restrict__ Wf, int KREAL,
    const float* __restrict__ bias,
    const void* __restrict__ P0,      // INIT: nf f32; EDGE: aggb u16; GIN: x f32
    const void* __restrict__ P1,      // INIT: ef f32; EDGE: hbf u16 (rev); GIN: agg f32
    const int* __restrict__ srcIdx,   // INIT/EDGE: edge_src
    const float* __restrict__ epsp,   // GIN: eps scalar
    const void* __restrict__ addsrc,  // EPI_ABR: EDGE -> u16 hbf; GIN -> f32
    void* __restrict__ Out, int numRows) {
  constexpr int RS = KSTEPS * 32 + 8;
  __shared__ short amem[64 * RS];
  const int t = threadIdx.x;
  const int l = t & 63;
  const int w = t >> 6;
  const int g = l >> 4;
  const int n0 = l & 15;

  // ---- preload W fragments (wave w covers col tiles 2w, 2w+1) ----
  short8v wf[KSTEPS][2];
  #pragma unroll
  for (int s = 0; s < KSTEPS; ++s) {
    #pragma unroll
    for (int ct = 0; ct < 2; ++ct) {
      short8v v;
      #pragma unroll
      for (int j = 0; j < 8; ++j) {
        int k = 32 * s + 8 * g + j;
        float wv = (k < KREAL) ? Wf[(size_t)k * 128 + (2 * w + ct) * 16 + n0] : 0.f;
        v[j] = (short)f2bf(wv);
      }
      wf[s][ct] = v;
    }
  }
  float bb[2] = {0.f, 0.f};
  if constexpr (EPIM != EPI_RAW) {
    #pragma unroll
    for (int ct = 0; ct < 2; ++ct) bb[ct] = bias[(2 * w + ct) * 16 + n0];
  }
  float alpha = 0.f;
  if constexpr (PREPM == PREP_GIN) alpha = 1.f + epsp[0];

  const int numTiles = (numRows + 63) >> 6;
  for (int tile = blockIdx.x; tile < numTiles; tile += gridDim.x) {
    const int base = tile * 64;
    // ---- prep: stage A tile (bf16) ----
    {
      const int i = t >> 2, q = t & 3;
      const int row = base + i;
      if constexpr (PREPM == PREP_INIT) {
        const int sn = srcIdx[row];
        const float* nrow = (const float*)P0 + (size_t)sn * 128;
        #pragma unroll
        for (int cc = 0; cc < 8; ++cc) {
          int col = q * 32 + cc * 4;
          float4 vv = *(const float4*)(nrow + col);
          short4v o = {(short)f2bf(vv.x), (short)f2bf(vv.y), (short)f2bf(vv.z), (short)f2bf(vv.w)};
          *(short4v*)(&amem[i * RS + col]) = o;
        }
        #pragma unroll
        for (int z = 0; z < 2; ++z) {
          int cc = 2 * q + z;
          int col = 128 + cc * 4;
          short4v o = {0, 0, 0, 0};
          if (col < 144) {
            float4 vv = *(const float4*)((const float*)P1 + (size_t)row * 16 + (col - 128));
            o = {(short)f2bf(vv.x), (short)f2bf(vv.y), (short)f2bf(vv.z), (short)f2bf(vv.w)};
          }
          *(short4v*)(&amem[i * RS + col]) = o;
        }
      } else if constexpr (PREPM == PREP_EDGE) {
        const int sn = srcIdx[row];
        const u16* arow = (const u16*)P0 + (size_t)sn * 128 + q * 32;
        const u16* hrow = (const u16*)P1 + (size_t)(row ^ 1) * 128 + q * 32;
        #pragma unroll
        for (int c = 0; c < 4; ++c) {
          short8v av = *(const short8v*)(arow + 8 * c);
          short8v hv = *(const short8v*)(hrow + 8 * c);
          short8v o;
          #pragma unroll
          for (int j = 0; j < 8; ++j)
            o[j] = (short)f2bf(bf2f((u16)av[j]) - bf2f((u16)hv[j]));
          *(short8v*)(&amem[i * RS + q * 32 + 8 * c]) = o;
        }
      } else {
        const int rc = (row < numRows) ? row : (numRows - 1);
        const float* xrow = (const float*)P0 + (size_t)rc * 128;
        const float* grow = (const float*)P1 + (size_t)rc * 128;
        #pragma unroll
        for (int cc = 0; cc < 8; ++cc) {
          int col = q * 32 + cc * 4;
          float4 xv = *(const float4*)(xrow + col);
          float4 av = *(const float4*)(grow + col);
          short4v o = {(short)f2bf(fmaf(alpha, xv.x, av.x)), (short)f2bf(fmaf(alpha, xv.y, av.y)),
                       (short)f2bf(fmaf(alpha, xv.z, av.z)), (short)f2bf(fmaf(alpha, xv.w, av.w))};
          *(short4v*)(&amem[i * RS + col]) = o;
        }
      }
    }
    __syncthreads();
    // ---- MFMA main loop ----
    f32x4 acc[4][2];
    #pragma unroll
    for (int rt = 0; rt < 4; ++rt)
      #pragma unroll
      for (int ct = 0; ct < 2; ++ct) acc[rt][ct] = (f32x4){0.f, 0.f, 0.f, 0.f};
    #pragma unroll
    for (int s = 0; s < KSTEPS; ++s) {
      bf16x8v af[4];
      #pragma unroll
      for (int rt = 0; rt < 4; ++rt) {
        short8v araw = *(const short8v*)(&amem[(16 * rt + n0) * RS + s * 32 + g * 8]);
        af[rt] = __builtin_bit_cast(bf16x8v, araw);
      }
      #pragma unroll
      for (int rt = 0; rt < 4; ++rt)
        #pragma unroll
        for (int ct = 0; ct < 2; ++ct)
          acc[rt][ct] = __builtin_amdgcn_mfma_f32_16x16x32_bf16(
              af[rt], __builtin_bit_cast(bf16x8v, wf[s][ct]), acc[rt][ct], 0, 0, 0);
    }
    // ---- epilogue: C/D layout col=lane&15, row=(lane>>4)*4+reg ----
    if constexpr (OUTBF) {
      __syncthreads();  // all A reads done; reuse amem for C staging
      #pragma unroll
      for (int rt = 0; rt < 4; ++rt) {
        #pragma unroll
        for (int ct = 0; ct < 2; ++ct) {
          #pragma unroll
          for (int r = 0; r < 4; ++r) {
            int row = base + 16 * rt + 4 * g + r;
            float o = acc[rt][ct][r];
            size_t idx = (size_t)row * 128 + (2 * w + ct) * 16 + n0;
            if constexpr (EPIM == EPI_ABR) o += bf2f(((const u16*)addsrc)[idx]);
            if constexpr (EPIM != EPI_RAW) o = fmaxf(o + bb[ct], 0.f);
            amem[(16 * rt + 4 * g + r) * RS + (2 * w + ct) * 16 + n0] = (short)f2bf(o);
          }
        }
      }
      __syncthreads();
      {
        const int i = t >> 2, q = t & 3;
        const int row = base + i;
        if (row < numRows) {
          u16* orow = (u16*)Out + (size_t)row * 128 + q * 32;
          #pragma unroll
          for (int c = 0; c < 4; ++c)
            *(short8v*)(orow + 8 * c) = *(const short8v*)(&amem[i * RS + q * 32 + 8 * c]);
        }
      }
    } else {
      #pragma unroll
      for (int rt = 0; rt < 4; ++rt) {
        #pragma unroll
        for (int ct = 0; ct < 2; ++ct) {
          #pragma unroll
          for (int r = 0; r < 4; ++r) {
            int row = base + 16 * rt + 4 * g + r;
            if (row < numRows) {
              size_t idx = (size_t)row * 128 + (2 * w + ct) * 16 + n0;
              float o = acc[rt][ct][r];
              if constexpr (EPIM == EPI_ABR) {
                if constexpr (PREPM == PREP_EDGE) o += bf2f(((const u16*)addsrc)[idx]);
                else o += ((const float*)addsrc)[idx];
              }
              if constexpr (EPIM != EPI_RAW) o = fmaxf(o + bb[ct], 0.f);
              ((float*)Out)[idx] = o;
            }
          }
        }
      }
    }
    __syncthreads();
  }
}

extern "C" void kernel_launch(void* const* d_in, const int* in_sizes, int n_in,
                              void* d_out, int out_size, void* d_ws, size_t ws_size,
                              hipStream_t stream) {
  const float* nf     = (const float*)d_in[0];
  const float* ef     = (const float*)d_in[1];
  const float* W_init = (const float*)d_in[2];
  const float* b_init = (const float*)d_in[3];
  const float* W_edge = (const float*)d_in[4];
  const float* b_edge = (const float*)d_in[5];
  const float* W_gin0 = (const float*)d_in[6];
  const float* W_gin  = (const float*)d_in[7];
  const float* b_gin  = (const float*)d_in[8];
  const float* eps    = (const float*)d_in[9];
  const int* esrc     = (const int*)d_in[10];
  const int* edst     = (const int*)d_in[11];
  // d_in[12] = edge_rev == e^1 by construction.

  float* xout  = (float*)d_out;                     // [N,128] f32
  float* h_out = xout + (size_t)N_NODES * 128;      // [E,128] f32 (final h)

  // ws layout (time-multiplexed):
  //  [0, 51.2MB)      aggA f32 [N,128]; edge phase aliases aggbf u16 [N,128]
  //  [51.2, 204.8MB)  hbf u16 [E,128]; after edge phase dead ->
  //                     aggB f32 [N,128] at +0, readout f32 [N,128] at +51.2MB
  //  [204.8MB, ...)   csr arrays
  char* wsb = (char*)d_ws;
  float* aggA  = (float*)wsb;
  u16*   aggbf = (u16*)wsb;
  u16*   hbf   = (u16*)(wsb + (size_t)N_NODES * 128 * 4);
  float* aggB  = (float*)hbf;
  float* readout = (float*)((char*)hbf + (size_t)N_NODES * 128 * 4);
  int* csr_off = (int*)((char*)hbf + (size_t)N_EDGES * 128 * 2);  // N+1
  int* cursor  = csr_off + (N_NODES + 1);
  int* csr_e   = cursor + N_NODES;
  int* csr_s   = csr_e + N_EDGES;

  // ---- CSR by dst ----
  hipMemsetAsync(cursor, 0, N_NODES * sizeof(int), stream);
  hist_kernel<<<(N_EDGES + 255) / 256, 256, 0, stream>>>(edst, cursor);
  scan_kernel<<<1, 1024, 0, stream>>>(cursor, csr_off);
  hipMemsetAsync(cursor, 0, N_NODES * sizeof(int), stream);
  fill_kernel<<<(N_EDGES + 255) / 256, 256, 0, stream>>>(edst, esrc, csr_off, cursor, csr_e, csr_s);

  const int ETILES = N_EDGES / 64;          // 9375
  const int NTILES = (N_NODES + 63) / 64;   // 1563

  // ---- init edge states: hbf = relu([nf[src]|ef] @ W_init + b)  (bf16) ----
  mfma_gemm<5, PREP_INIT, EPI_BR, 1><<<ETILES, 256, 0, stream>>>(
      W_init, 144, b_init, nf, ef, esrc, nullptr, nullptr, hbf, N_EDGES);

  // ---- EdgeConv steps 0..2 (in place on hbf) ----
  for (int t = 0; t < 3; ++t) {
    segsum_hbf_kernel<<<N_NODES / 4, 256, 0, stream>>>(hbf, csr_off, csr_e, aggbf);
    mfma_gemm<4, PREP_EDGE, EPI_ABR, 1><<<ETILES, 256, 0, stream>>>(
        W_edge + (size_t)t * 128 * 128, 128, b_edge + (size_t)t * 128,
        aggbf, hbf, esrc, nullptr, hbf, hbf, N_EDGES);
  }
  // ---- EdgeConv step 3 -> f32 h_out in d_out ----
  segsum_hbf_kernel<<<N_NODES / 4, 256, 0, stream>>>(hbf, csr_off, csr_e, aggbf);
  mfma_gemm<4, PREP_EDGE, EPI_ABR, 0><<<ETILES, 256, 0, stream>>>(
      W_edge + (size_t)3 * 128 * 128, 128, b_edge + (size_t)3 * 128,
      aggbf, hbf, esrc, nullptr, hbf, h_out, N_EDGES);

  // ---- readout (f32 h from d_out; hbf now dead) ----
  segsum_h_kernel<<<N_NODES, 128, 0, stream>>>(h_out, csr_off, csr_e, readout);

  // ---- GIN step 0: split K=256 into two K=128 passes ----
  gather2_kernel<<<N_NODES, 128, 0, stream>>>(nf, readout, csr_off, csr_s, aggA, aggB);
  mfma_gemm<4, PREP_GIN, EPI_RAW, 0><<<NTILES, 256, 0, stream>>>(
      W_gin0, 128, nullptr, nf, aggA, nullptr, eps, nullptr, aggA, N_NODES);
  mfma_gemm<4, PREP_GIN, EPI_ABR, 0><<<NTILES, 256, 0, stream>>>(
      W_gin0 + (size_t)128 * 128, 128, b_gin, readout, aggB, nullptr, eps, aggA, xout, N_NODES);

  // ---- GIN steps 1..3 (in place on x) ----
  for (int t = 1; t < 4; ++t) {
    gather_x_kernel<<<N_NODES, 128, 0, stream>>>(xout, csr_off, csr_s, aggA);
    mfma_gemm<4, PREP_GIN, EPI_BR, 0><<<NTILES, 256, 0, stream>>>(
        W_gin + (size_t)(t - 1) * 128 * 128, 128, b_gin + (size_t)t * 128,
        xout, aggA, nullptr, eps + t, nullptr, xout, N_NODES);
  }

  (void)in_sizes; (void)n_in; (void)out_size; (void)ws_size;
}

// Round 4
// 1642.760 us; speedup vs baseline: 2.0813x; 1.0864x over previous
//
#include <hip/hip_runtime.h>

#define N_NODES 100000
#define N_EDGES 600000

typedef unsigned short u16;
typedef __attribute__((ext_vector_type(8))) short short8v;
typedef __attribute__((ext_vector_type(4))) short short4v;
typedef __attribute__((ext_vector_type(4))) float f32x4;
typedef __attribute__((ext_vector_type(8))) __bf16 bf16x8v;

__device__ __forceinline__ u16 f2bf(float f) {
  unsigned u = __builtin_bit_cast(unsigned, f);
  unsigned r = (u + 0x7fffu + ((u >> 16) & 1u)) >> 16;
  return (u16)r;
}
__device__ __forceinline__ float bf2f(u16 v) {
  unsigned u = ((unsigned)v) << 16;
  return __builtin_bit_cast(float, u);
}

// ---------------- CSR build ----------------
__global__ void hist_kernel(const int* __restrict__ dst, int* __restrict__ cnt) {
  int e = blockIdx.x * 256 + threadIdx.x;
  if (e < N_EDGES) atomicAdd(&cnt[dst[e]], 1);
}

__global__ void scan_kernel(const int* __restrict__ cnt, int* __restrict__ off) {
  __shared__ int sums[1024];
  int tid = threadIdx.x;
  const int n = N_NODES;
  int chunk = (n + 1023) / 1024;
  int s0 = tid * chunk;
  int s1 = min(s0 + chunk, n);
  int s = 0;
  for (int i = s0; i < s1; ++i) s += cnt[i];
  sums[tid] = s;
  __syncthreads();
  for (int d = 1; d < 1024; d <<= 1) {
    int v = (tid >= d) ? sums[tid - d] : 0;
    __syncthreads();
    sums[tid] += v;
    __syncthreads();
  }
  int run = (tid == 0) ? 0 : sums[tid - 1];
  for (int i = s0; i < s1; ++i) { off[i] = run; run += cnt[i]; }
  if (tid == 1023) off[n] = sums[1023];
}

__global__ void fill_kernel(const int* __restrict__ dst, const int* __restrict__ src,
                            const int* __restrict__ off, int* __restrict__ cur,
                            int* __restrict__ csr_e, int* __restrict__ csr_s) {
  int e = blockIdx.x * 256 + threadIdx.x;
  if (e < N_EDGES) {
    int d = dst[e];
    int p = off[d] + atomicAdd(&cur[d], 1);
    csr_e[p] = e;
    csr_s[p] = src[e];
  }
}

// ---------------- segment sum over bf16 h (one wave per node) ----------------
__global__ __launch_bounds__(256) void segsum_hbf_kernel(const u16* __restrict__ hbf,
                                                         const int* __restrict__ off,
                                                         const int* __restrict__ csr_e,
                                                         u16* __restrict__ aggb) {
  int node = blockIdx.x * 4 + (threadIdx.x >> 6);
  int l = threadIdx.x & 63;
  int p0 = off[node], p1 = off[node + 1];
  float a0 = 0.f, a1 = 0.f;
  for (int p = p0; p < p1; ++p) {
    int e = csr_e[p];
    unsigned u = *(const unsigned*)(hbf + (size_t)e * 128 + 2 * l);
    a0 += __builtin_bit_cast(float, u << 16);
    a1 += __builtin_bit_cast(float, u & 0xffff0000u);
  }
  unsigned o = (unsigned)f2bf(a0) | (((unsigned)f2bf(a1)) << 16);
  *(unsigned*)(aggb + (size_t)node * 128 + 2 * l) = o;
}

// ---- fused: readout[n] = sum of final h rows; also expand hbf -> f32 h_out ----
__global__ __launch_bounds__(256) void expand_readout_kernel(const u16* __restrict__ hbf,
                                                             const int* __restrict__ off,
                                                             const int* __restrict__ csr_e,
                                                             float* __restrict__ h_out,
                                                             u16* __restrict__ readout) {
  int node = blockIdx.x * 4 + (threadIdx.x >> 6);
  int l = threadIdx.x & 63;
  int p0 = off[node], p1 = off[node + 1];
  float a0 = 0.f, a1 = 0.f;
  for (int p = p0; p < p1; ++p) {
    int e = csr_e[p];
    unsigned u = *(const unsigned*)(hbf + (size_t)e * 128 + 2 * l);
    float f0 = __builtin_bit_cast(float, u << 16);
    float f1 = __builtin_bit_cast(float, u & 0xffff0000u);
    a0 += f0; a1 += f1;
    float2 w = {f0, f1};
    *(float2*)(h_out + (size_t)e * 128 + 2 * l) = w;
  }
  unsigned o = (unsigned)f2bf(a0) | (((unsigned)f2bf(a1)) << 16);
  *(unsigned*)(readout + (size_t)node * 128 + 2 * l) = o;
}

// ---------------- unified MFMA GEMM ----------------
// Tile 64 rows x 128 cols, 256 threads (4 waves); wave w -> cols [32w,32w+32).
// W fragments in registers; A staged in LDS bf16 (row stride RS shorts).
// k-mapping k = 32s+8g+j consistent between A and B fragments.
// GIN preps fuse the CSR neighbor gather inline (no materialized agg).
#define PREP_INIT 0
#define PREP_EDGE 1
#define PREP_GIN0 2
#define PREP_GINX 3
#define EPI_BR  1
#define EPI_ABR 2

template<int KSTEPS, int PREPM, int EPIM, int OUTBF>
__global__ __launch_bounds__(256, 3) void mfma_gemm(
    const float* __restrict__ Wf, int KREAL,
    const float* __restrict__ bias,
    const void* __restrict__ P0,      // INIT: nf f32; EDGE: aggb u16; GIN0: nf f32; GINX: x u16
    const void* __restrict__ P1,      // INIT: ef f32; EDGE: hbf u16 (rev); GIN0: readout u16
    const int* __restrict__ srcIdx,   // INIT/EDGE: edge_src
    const int* __restrict__ csr_off,  // GIN: gather offsets
    const int* __restrict__ csr_s,    // GIN: gather sources
    const float* __restrict__ epsp,   // GIN: eps scalar
    const void* __restrict__ addsrc,  // EPI_ABR: u16 residual (EDGE)
    void* __restrict__ Out, int numRows) {
  constexpr int RS = KSTEPS * 32 + 8;
  constexpr bool WLATE = (KSTEPS >= 8);
  __shared__ short amem[64 * RS];
  const int t = threadIdx.x;
  const int l = t & 63;
  const int w = t >> 6;
  const int g = l >> 4;
  const int n0 = l & 15;
  const int base = blockIdx.x * 64;

  short8v wf[KSTEPS][2];
  auto load_w = [&]() {
    #pragma unroll
    for (int s = 0; s < KSTEPS; ++s) {
      #pragma unroll
      for (int ct = 0; ct < 2; ++ct) {
        short8v v;
        #pragma unroll
        for (int j = 0; j < 8; ++j) {
          int k = 32 * s + 8 * g + j;
          float wv = (k < KREAL) ? Wf[(size_t)k * 128 + (2 * w + ct) * 16 + n0] : 0.f;
          v[j] = (short)f2bf(wv);
        }
        wf[s][ct] = v;
      }
    }
  };
  if constexpr (!WLATE) load_w();

  float bb[2];
  #pragma unroll
  for (int ct = 0; ct < 2; ++ct) bb[ct] = bias[(2 * w + ct) * 16 + n0];
  float alpha = 0.f;
  if constexpr (PREPM == PREP_GIN0 || PREPM == PREP_GINX) alpha = 1.f + epsp[0];

  // ---- prep: stage A tile (bf16) ----
  if constexpr (PREPM == PREP_INIT) {
    const int i = t >> 2, q = t & 3;
    const int row = base + i;
    const int sn = srcIdx[row];
    const float* nrow = (const float*)P0 + (size_t)sn * 128;
    #pragma unroll
    for (int cc = 0; cc < 8; ++cc) {
      int col = q * 32 + cc * 4;
      float4 vv = *(const float4*)(nrow + col);
      short4v o = {(short)f2bf(vv.x), (short)f2bf(vv.y), (short)f2bf(vv.z), (short)f2bf(vv.w)};
      *(short4v*)(&amem[i * RS + col]) = o;
    }
    #pragma unroll
    for (int z = 0; z < 2; ++z) {
      int col = 128 + (2 * q + z) * 4;
      short4v o = {0, 0, 0, 0};
      if (col < 144) {
        float4 vv = *(const float4*)((const float*)P1 + (size_t)row * 16 + (col - 128));
        o = {(short)f2bf(vv.x), (short)f2bf(vv.y), (short)f2bf(vv.z), (short)f2bf(vv.w)};
      }
      *(short4v*)(&amem[i * RS + col]) = o;
    }
  } else if constexpr (PREPM == PREP_EDGE) {
    const int i = t >> 2, q = t & 3;
    const int row = base + i;
    const int sn = srcIdx[row];
    const u16* arow = (const u16*)P0 + (size_t)sn * 128 + q * 32;
    const u16* hrow = (const u16*)P1 + (size_t)(row ^ 1) * 128 + q * 32;
    #pragma unroll
    for (int c = 0; c < 4; ++c) {
      short8v av = *(const short8v*)(arow + 8 * c);
      short8v hv = *(const short8v*)(hrow + 8 * c);
      short8v o;
      #pragma unroll
      for (int j = 0; j < 8; ++j)
        o[j] = (short)f2bf(bf2f((u16)av[j]) - bf2f((u16)hv[j]));
      *(short8v*)(&amem[i * RS + q * 32 + 8 * c]) = o;
    }
  } else if constexpr (PREPM == PREP_GIN0) {
    const int i2 = t >> 3, q = t & 7;
    #pragma unroll
    for (int half = 0; half < 2; ++half) {
      const int r = i2 + 32 * half;
      const int row = base + r;
      const int n = (row < numRows) ? row : (numRows - 1);
      const int p0 = csr_off[n], p1 = csr_off[n + 1];
      float acc[32];
      if (q < 4) {
        const float* self = (const float*)P0 + (size_t)n * 128 + 32 * q;
        #pragma unroll
        for (int c4 = 0; c4 < 8; ++c4) {
          float4 v = *(const float4*)(self + 4 * c4);
          acc[4 * c4 + 0] = alpha * v.x; acc[4 * c4 + 1] = alpha * v.y;
          acc[4 * c4 + 2] = alpha * v.z; acc[4 * c4 + 3] = alpha * v.w;
        }
        for (int p = p0; p < p1; ++p) {
          const float* nb = (const float*)P0 + (size_t)csr_s[p] * 128 + 32 * q;
          #pragma unroll
          for (int c4 = 0; c4 < 8; ++c4) {
            float4 v = *(const float4*)(nb + 4 * c4);
            acc[4 * c4 + 0] += v.x; acc[4 * c4 + 1] += v.y;
            acc[4 * c4 + 2] += v.z; acc[4 * c4 + 3] += v.w;
          }
        }
      } else {
        const u16* self = (const u16*)P1 + (size_t)n * 128 + 32 * (q - 4);
        #pragma unroll
        for (int c8 = 0; c8 < 4; ++c8) {
          short8v v = *(const short8v*)(self + 8 * c8);
          #pragma unroll
          for (int j = 0; j < 8; ++j) acc[8 * c8 + j] = alpha * bf2f((u16)v[j]);
        }
        for (int p = p0; p < p1; ++p) {
          const u16* nb = (const u16*)P1 + (size_t)csr_s[p] * 128 + 32 * (q - 4);
          #pragma unroll
          for (int c8 = 0; c8 < 4; ++c8) {
            short8v v = *(const short8v*)(nb + 8 * c8);
            #pragma unroll
            for (int j = 0; j < 8; ++j) acc[8 * c8 + j] += bf2f((u16)v[j]);
          }
        }
      }
      #pragma unroll
      for (int c4 = 0; c4 < 8; ++c4) {
        short4v o = {(short)f2bf(acc[4 * c4 + 0]), (short)f2bf(acc[4 * c4 + 1]),
                     (short)f2bf(acc[4 * c4 + 2]), (short)f2bf(acc[4 * c4 + 3])};
        *(short4v*)(&amem[r * RS + 32 * q + 4 * c4]) = o;
      }
    }
  } else {  // PREP_GINX
    const int i = t >> 2, q = t & 3;
    const int row = base + i;
    const int n = (row < numRows) ? row : (numRows - 1);
    const int p0 = csr_off[n], p1 = csr_off[n + 1];
    float acc[32];
    const u16* self = (const u16*)P0 + (size_t)n * 128 + 32 * q;
    #pragma unroll
    for (int c8 = 0; c8 < 4; ++c8) {
      short8v v = *(const short8v*)(self + 8 * c8);
      #pragma unroll
      for (int j = 0; j < 8; ++j) acc[8 * c8 + j] = alpha * bf2f((u16)v[j]);
    }
    for (int p = p0; p < p1; ++p) {
      const u16* nb = (const u16*)P0 + (size_t)csr_s[p] * 128 + 32 * q;
      #pragma unroll
      for (int c8 = 0; c8 < 4; ++c8) {
        short8v v = *(const short8v*)(nb + 8 * c8);
        #pragma unroll
        for (int j = 0; j < 8; ++j) acc[8 * c8 + j] += bf2f((u16)v[j]);
      }
    }
    #pragma unroll
    for (int c4 = 0; c4 < 8; ++c4) {
      short4v o = {(short)f2bf(acc[4 * c4 + 0]), (short)f2bf(acc[4 * c4 + 1]),
                   (short)f2bf(acc[4 * c4 + 2]), (short)f2bf(acc[4 * c4 + 3])};
      *(short4v*)(&amem[i * RS + 32 * q + 4 * c4]) = o;
    }
  }
  __syncthreads();
  if constexpr (WLATE) load_w();

  // ---- MFMA main loop ----
  f32x4 acc[4][2];
  #pragma unroll
  for (int rt = 0; rt < 4; ++rt)
    #pragma unroll
    for (int ct = 0; ct < 2; ++ct) acc[rt][ct] = (f32x4){0.f, 0.f, 0.f, 0.f};
  #pragma unroll
  for (int s = 0; s < KSTEPS; ++s) {
    bf16x8v af[4];
    #pragma unroll
    for (int rt = 0; rt < 4; ++rt) {
      short8v araw = *(const short8v*)(&amem[(16 * rt + n0) * RS + s * 32 + g * 8]);
      af[rt] = __builtin_bit_cast(bf16x8v, araw);
    }
    #pragma unroll
    for (int rt = 0; rt < 4; ++rt)
      #pragma unroll
      for (int ct = 0; ct < 2; ++ct)
        acc[rt][ct] = __builtin_amdgcn_mfma_f32_16x16x32_bf16(
            af[rt], __builtin_bit_cast(bf16x8v, wf[s][ct]), acc[rt][ct], 0, 0, 0);
  }

  // ---- epilogue: C/D layout col=lane&15, row=(lane>>4)*4+reg ----
  if constexpr (OUTBF) {
    __syncthreads();  // reuse amem for C staging
    #pragma unroll
    for (int rt = 0; rt < 4; ++rt) {
      #pragma unroll
      for (int ct = 0; ct < 2; ++ct) {
        #pragma unroll
        for (int r = 0; r < 4; ++r) {
          int row = base + 16 * rt + 4 * g + r;
          float o = acc[rt][ct][r];
          size_t idx = (size_t)row * 128 + (2 * w + ct) * 16 + n0;
          if constexpr (EPIM == EPI_ABR) o += bf2f(((const u16*)addsrc)[idx]);
          o = fmaxf(o + bb[ct], 0.f);
          amem[(16 * rt + 4 * g + r) * RS + (2 * w + ct) * 16 + n0] = (short)f2bf(o);
        }
      }
    }
    __syncthreads();
    {
      const int i = t >> 2, q = t & 3;
      const int row = base + i;
      if (row < numRows) {
        u16* orow = (u16*)Out + (size_t)row * 128 + q * 32;
        #pragma unroll
        for (int c = 0; c < 4; ++c)
          *(short8v*)(orow + 8 * c) = *(const short8v*)(&amem[i * RS + q * 32 + 8 * c]);
      }
    }
  } else {
    #pragma unroll
    for (int rt = 0; rt < 4; ++rt) {
      #pragma unroll
      for (int ct = 0; ct < 2; ++ct) {
        #pragma unroll
        for (int r = 0; r < 4; ++r) {
          int row = base + 16 * rt + 4 * g + r;
          if (row < numRows) {
            size_t idx = (size_t)row * 128 + (2 * w + ct) * 16 + n0;
            float o = acc[rt][ct][r];
            if constexpr (EPIM == EPI_ABR) o += bf2f(((const u16*)addsrc)[idx]);
            o = fmaxf(o + bb[ct], 0.f);
            ((float*)Out)[idx] = o;
          }
        }
      }
    }
  }
}

extern "C" void kernel_launch(void* const* d_in, const int* in_sizes, int n_in,
                              void* d_out, int out_size, void* d_ws, size_t ws_size,
                              hipStream_t stream) {
  const float* nf     = (const float*)d_in[0];
  const float* ef     = (const float*)d_in[1];
  const float* W_init = (const float*)d_in[2];
  const float* b_init = (const float*)d_in[3];
  const float* W_edge = (const float*)d_in[4];
  const float* b_edge = (const float*)d_in[5];
  const float* W_gin0 = (const float*)d_in[6];
  const float* W_gin  = (const float*)d_in[7];
  const float* b_gin  = (const float*)d_in[8];
  const float* eps    = (const float*)d_in[9];
  const int* esrc     = (const int*)d_in[10];
  const int* edst     = (const int*)d_in[11];
  // d_in[12] = edge_rev == e^1 by construction.

  float* xout  = (float*)d_out;                     // [N,128] f32
  float* h_out = xout + (size_t)N_NODES * 128;      // [E,128] f32 (final h)

  const size_t NB = (size_t)N_NODES * 128 * 2;      // bf16 node-feature block
  const size_t EB = (size_t)N_EDGES * 128 * 2;      // bf16 edge-state block
  char* wsb = (char*)d_ws;
  u16* aggbf   = (u16*)wsb;
  u16* hbf     = (u16*)(wsb + NB);
  u16* readout = (u16*)(wsb + NB + EB);
  u16* xbf0    = (u16*)(wsb + 2 * NB + EB);
  u16* xbf1    = (u16*)(wsb + 3 * NB + EB);
  int* csr_off = (int*)(wsb + 4 * NB + EB);         // N+1
  int* cursor  = csr_off + (N_NODES + 1);           // N (also histogram)
  int* csr_e   = cursor + N_NODES;                  // E
  int* csr_s   = csr_e + N_EDGES;                   // E

  // ---- CSR by dst ----
  hipMemsetAsync(cursor, 0, N_NODES * sizeof(int), stream);
  hist_kernel<<<(N_EDGES + 255) / 256, 256, 0, stream>>>(edst, cursor);
  scan_kernel<<<1, 1024, 0, stream>>>(cursor, csr_off);
  hipMemsetAsync(cursor, 0, N_NODES * sizeof(int), stream);
  fill_kernel<<<(N_EDGES + 255) / 256, 256, 0, stream>>>(edst, esrc, csr_off, cursor, csr_e, csr_s);

  const int ETILES = N_EDGES / 64;          // 9375
  const int NTILES = (N_NODES + 63) / 64;   // 1563

  // ---- init edge states: hbf = relu([nf[src]|ef] @ W_init + b) ----
  mfma_gemm<5, PREP_INIT, EPI_BR, 1><<<ETILES, 256, 0, stream>>>(
      W_init, 144, b_init, nf, ef, esrc, nullptr, nullptr, nullptr, nullptr, hbf, N_EDGES);

  // ---- EdgeConv steps 0..3 (in place on hbf) ----
  for (int t = 0; t < 4; ++t) {
    segsum_hbf_kernel<<<N_NODES / 4, 256, 0, stream>>>(hbf, csr_off, csr_e, aggbf);
    mfma_gemm<4, PREP_EDGE, EPI_ABR, 1><<<ETILES, 256, 0, stream>>>(
        W_edge + (size_t)t * 128 * 128, 128, b_edge + (size_t)t * 128,
        aggbf, hbf, esrc, nullptr, nullptr, nullptr, hbf, hbf, N_EDGES);
  }

  // ---- fused: h_out (f32) expansion + readout (bf16) ----
  expand_readout_kernel<<<N_NODES / 4, 256, 0, stream>>>(hbf, csr_off, csr_e, h_out, readout);

  // ---- GIN step 0: fused K=256 GEMM with inline gathers ----
  mfma_gemm<8, PREP_GIN0, EPI_BR, 1><<<NTILES, 256, 0, stream>>>(
      W_gin0, 256, b_gin, nf, readout, nullptr, csr_off, csr_s, eps, nullptr, xbf0, N_NODES);

  // ---- GIN steps 1..3 (double-buffered bf16 x; inline gathers) ----
  mfma_gemm<4, PREP_GINX, EPI_BR, 1><<<NTILES, 256, 0, stream>>>(
      W_gin, 128, b_gin + 128, xbf0, nullptr, nullptr, csr_off, csr_s, eps + 1, nullptr, xbf1, N_NODES);
  mfma_gemm<4, PREP_GINX, EPI_BR, 1><<<NTILES, 256, 0, stream>>>(
      W_gin + (size_t)128 * 128, 128, b_gin + 256, xbf1, nullptr, nullptr, csr_off, csr_s, eps + 2, nullptr, xbf0, N_NODES);
  mfma_gemm<4, PREP_GINX, EPI_BR, 0><<<NTILES, 256, 0, stream>>>(
      W_gin + (size_t)2 * 128 * 128, 128, b_gin + 384, xbf0, nullptr, nullptr, csr_off, csr_s, eps + 3, nullptr, xout, N_NODES);

  (void)in_sizes; (void)n_in; (void)out_size; (void)ws_size;
}

// Round 5
// 1477.139 us; speedup vs baseline: 2.3147x; 1.1121x over previous
//
#include <hip/hip_runtime.h>

#define N_NODES 100000
#define N_EDGES 600000

typedef unsigned short u16;
typedef __attribute__((ext_vector_type(8))) short short8v;
typedef __attribute__((ext_vector_type(4))) short short4v;
typedef __attribute__((ext_vector_type(4))) float f32x4;
typedef __attribute__((ext_vector_type(8))) __bf16 bf16x8v;

__device__ __forceinline__ u16 f2bf(float f) {
  unsigned u = __builtin_bit_cast(unsigned, f);
  unsigned r = (u + 0x7fffu + ((u >> 16) & 1u)) >> 16;
  return (u16)r;
}
__device__ __forceinline__ float bf2f(u16 v) {
  unsigned u = ((unsigned)v) << 16;
  return __builtin_bit_cast(float, u);
}
__device__ __forceinline__ short8v shfl_xor4_v(short8v v) {
  int4 iv = __builtin_bit_cast(int4, v);
  iv.x = __shfl_xor(iv.x, 4, 64);
  iv.y = __shfl_xor(iv.y, 4, 64);
  iv.z = __shfl_xor(iv.z, 4, 64);
  iv.w = __shfl_xor(iv.w, 4, 64);
  return __builtin_bit_cast(short8v, iv);
}

// ---------------- nf -> bf16 ----------------
__global__ __launch_bounds__(256) void convert_nf_kernel(const float* __restrict__ nf,
                                                         u16* __restrict__ nfbf) {
  size_t idx = ((size_t)blockIdx.x * 256 + threadIdx.x) * 8;
  if (idx >= (size_t)N_NODES * 128) return;
  float4 a = *(const float4*)(nf + idx);
  float4 b = *(const float4*)(nf + idx + 4);
  short8v o = {(short)f2bf(a.x), (short)f2bf(a.y), (short)f2bf(a.z), (short)f2bf(a.w),
               (short)f2bf(b.x), (short)f2bf(b.y), (short)f2bf(b.z), (short)f2bf(b.w)};
  *(short8v*)(nfbf + idx) = o;
}

// ---------------- CSR build ----------------
__global__ void hist_kernel(const int* __restrict__ dst, int* __restrict__ cnt) {
  int e = blockIdx.x * 256 + threadIdx.x;
  if (e < N_EDGES) atomicAdd(&cnt[dst[e]], 1);
}

// scan also zeroes cnt (so it can be reused as the fill cursor without a memset)
__global__ void scan_kernel(int* __restrict__ cnt, int* __restrict__ off) {
  __shared__ int sums[1024];
  int tid = threadIdx.x;
  const int n = N_NODES;
  int chunk = (n + 1023) / 1024;
  int s0 = tid * chunk;
  int s1 = min(s0 + chunk, n);
  int s = 0;
  for (int i = s0; i < s1; ++i) s += cnt[i];
  sums[tid] = s;
  __syncthreads();
  for (int d = 1; d < 1024; d <<= 1) {
    int v = (tid >= d) ? sums[tid - d] : 0;
    __syncthreads();
    sums[tid] += v;
    __syncthreads();
  }
  int run = (tid == 0) ? 0 : sums[tid - 1];
  for (int i = s0; i < s1; ++i) {
    off[i] = run;
    int c = cnt[i];
    cnt[i] = 0;
    run += c;
  }
  if (tid == 1023) off[n] = sums[1023];
}

__global__ void fill_kernel(const int* __restrict__ dst, const int* __restrict__ src,
                            const int* __restrict__ off, int* __restrict__ cur,
                            int* __restrict__ csr_e, int* __restrict__ csr_s) {
  int e = blockIdx.x * 256 + threadIdx.x;
  if (e < N_EDGES) {
    int d = dst[e];
    int p = off[d] + atomicAdd(&cur[d], 1);
    csr_e[p] = e;
    csr_s[p] = src[e];
  }
}

// ---------------- segment sum over bf16 h (one wave per node, shfl-bcast edges) ----
__global__ __launch_bounds__(256) void segsum_hbf_kernel(const u16* __restrict__ hbf,
                                                         const int* __restrict__ off,
                                                         const int* __restrict__ csr_e,
                                                         u16* __restrict__ aggb) {
  int node = blockIdx.x * 4 + (threadIdx.x >> 6);
  int l = threadIdx.x & 63;
  int p0 = off[node], p1 = off[node + 1];
  int deg = p1 - p0;
  int e_l = (l < deg) ? csr_e[p0 + min(l, deg - 1)] : 0;
  float a0 = 0.f, a1 = 0.f;
  int jmax = min(deg, 64);
  for (int j = 0; j < jmax; ++j) {
    int e = __shfl(e_l, j, 64);
    unsigned u = *(const unsigned*)(hbf + (size_t)e * 128 + 2 * l);
    a0 += __builtin_bit_cast(float, u << 16);
    a1 += __builtin_bit_cast(float, u & 0xffff0000u);
  }
  for (int p = p0 + 64; p < p1; ++p) {  // deg > 64: essentially never
    int e = csr_e[p];
    unsigned u = *(const unsigned*)(hbf + (size_t)e * 128 + 2 * l);
    a0 += __builtin_bit_cast(float, u << 16);
    a1 += __builtin_bit_cast(float, u & 0xffff0000u);
  }
  unsigned o = (unsigned)f2bf(a0) | (((unsigned)f2bf(a1)) << 16);
  *(unsigned*)(aggb + (size_t)node * 128 + 2 * l) = o;
}

// ---- fused: readout[n] = sum of final h rows; also expand hbf -> f32 h_out ----
__global__ __launch_bounds__(256) void expand_readout_kernel(const u16* __restrict__ hbf,
                                                             const int* __restrict__ off,
                                                             const int* __restrict__ csr_e,
                                                             float* __restrict__ h_out,
                                                             u16* __restrict__ readout) {
  int node = blockIdx.x * 4 + (threadIdx.x >> 6);
  int l = threadIdx.x & 63;
  int p0 = off[node], p1 = off[node + 1];
  int deg = p1 - p0;
  int e_l = (l < deg) ? csr_e[p0 + min(l, deg - 1)] : 0;
  float a0 = 0.f, a1 = 0.f;
  int jmax = min(deg, 64);
  for (int j = 0; j < jmax; ++j) {
    int e = __shfl(e_l, j, 64);
    unsigned u = *(const unsigned*)(hbf + (size_t)e * 128 + 2 * l);
    float f0 = __builtin_bit_cast(float, u << 16);
    float f1 = __builtin_bit_cast(float, u & 0xffff0000u);
    a0 += f0; a1 += f1;
    float2 w = {f0, f1};
    *(float2*)(h_out + (size_t)e * 128 + 2 * l) = w;
  }
  for (int p = p0 + 64; p < p1; ++p) {
    int e = csr_e[p];
    unsigned u = *(const unsigned*)(hbf + (size_t)e * 128 + 2 * l);
    float f0 = __builtin_bit_cast(float, u << 16);
    float f1 = __builtin_bit_cast(float, u & 0xffff0000u);
    a0 += f0; a1 += f1;
    float2 w = {f0, f1};
    *(float2*)(h_out + (size_t)e * 128 + 2 * l) = w;
  }
  unsigned o = (unsigned)f2bf(a0) | (((unsigned)f2bf(a1)) << 16);
  *(unsigned*)(readout + (size_t)node * 128 + 2 * l) = o;
}

// ---------------- unified MFMA GEMM ----------------
// Tile 64 rows x 128 cols, 256 threads (4 waves); wave w -> cols [32w,32w+32).
// W fragments in registers; A staged in LDS bf16 (row stride RS shorts).
// k-mapping k = 32s+8g+j consistent between A and B fragments.
// EDGE: h tile read ONCE (regs); rev via shfl_xor(4); residual routed via LDS.
// GIN: CSR neighbor gather fused into prep.
#define PREP_INIT 0
#define PREP_EDGE 1
#define PREP_GIN0 2
#define PREP_GINX 3
#define EPI_BR  1
#define EPI_ABR 2   // add LDS-staged residual (EDGE)

template<int KSTEPS, int PREPM, int EPIM, int OUTBF>
__global__ __launch_bounds__(256, 3) void mfma_gemm(
    const float* __restrict__ Wf, int KREAL,
    const float* __restrict__ bias,
    const void* __restrict__ P0,      // INIT: nfbf u16; EDGE: aggb u16; GIN0: nfbf u16; GINX: x u16
    const void* __restrict__ P1,      // INIT: ef f32; EDGE: hbf u16; GIN0: readout u16
    const int* __restrict__ srcIdx,   // INIT/EDGE: edge_src
    const int* __restrict__ csr_off,  // GIN: gather offsets
    const int* __restrict__ csr_s,    // GIN: gather sources
    const float* __restrict__ epsp,   // GIN: eps scalar
    void* __restrict__ Out, int numRows) {
  constexpr int RS = KSTEPS * 32 + 8;
  constexpr bool WLATE = (KSTEPS >= 8);
  __shared__ short amem[64 * RS];
  const int t = threadIdx.x;
  const int l = t & 63;
  const int w = t >> 6;
  const int g = l >> 4;
  const int n0 = l & 15;
  const int base = blockIdx.x * 64;

  short8v wf[KSTEPS][2];
  auto load_w = [&]() {
    #pragma unroll
    for (int s = 0; s < KSTEPS; ++s) {
      #pragma unroll
      for (int ct = 0; ct < 2; ++ct) {
        short8v v;
        #pragma unroll
        for (int j = 0; j < 8; ++j) {
          int k = 32 * s + 8 * g + j;
          float wv = (k < KREAL) ? Wf[(size_t)k * 128 + (2 * w + ct) * 16 + n0] : 0.f;
          v[j] = (short)f2bf(wv);
        }
        wf[s][ct] = v;
      }
    }
  };
  if constexpr (!WLATE) load_w();

  float bb[2];
  #pragma unroll
  for (int ct = 0; ct < 2; ++ct) bb[ct] = bias[(2 * w + ct) * 16 + n0];
  float alpha = 0.f;
  if constexpr (PREPM == PREP_GIN0 || PREPM == PREP_GINX) alpha = 1.f + epsp[0];

  short8v hself[4];  // EDGE residual tile, regs (thread (i,q): row i, cols 32q..32q+31)

  // ---- prep: stage A tile (bf16) ----
  if constexpr (PREPM == PREP_INIT) {
    const int i = t >> 2, q = t & 3;
    const int row = base + i;
    const int sn = srcIdx[row];
    const u16* nrow = (const u16*)P0 + (size_t)sn * 128 + q * 32;
    #pragma unroll
    for (int c = 0; c < 4; ++c)
      *(short8v*)(&amem[i * RS + q * 32 + 8 * c]) = *(const short8v*)(nrow + 8 * c);
    #pragma unroll
    for (int z = 0; z < 2; ++z) {
      int col = 128 + (2 * q + z) * 4;
      short4v o = {0, 0, 0, 0};
      if (col < 144) {
        float4 vv = *(const float4*)((const float*)P1 + (size_t)row * 16 + (col - 128));
        o = {(short)f2bf(vv.x), (short)f2bf(vv.y), (short)f2bf(vv.z), (short)f2bf(vv.w)};
      }
      *(short4v*)(&amem[i * RS + col]) = o;
    }
  } else if constexpr (PREPM == PREP_EDGE) {
    const int i = t >> 2, q = t & 3;
    const int row = base + i;
    const int sn = srcIdx[row];
    const u16* arow = (const u16*)P0 + (size_t)sn * 128 + q * 32;
    const u16* hrow = (const u16*)P1 + (size_t)row * 128 + q * 32;
    short8v av[4];
    #pragma unroll
    for (int c = 0; c < 4; ++c) av[c] = *(const short8v*)(arow + 8 * c);
    #pragma unroll
    for (int c = 0; c < 4; ++c) hself[c] = *(const short8v*)(hrow + 8 * c);
    #pragma unroll
    for (int c = 0; c < 4; ++c) {
      short8v hrev = shfl_xor4_v(hself[c]);  // thread t^4 holds row i^1
      short8v o;
      #pragma unroll
      for (int j = 0; j < 8; ++j)
        o[j] = (short)f2bf(bf2f((u16)av[c][j]) - bf2f((u16)hrev[j]));
      *(short8v*)(&amem[i * RS + q * 32 + 8 * c]) = o;
    }
  } else if constexpr (PREPM == PREP_GIN0) {
    const int i2 = t >> 3, q = t & 7;
    #pragma unroll
    for (int half = 0; half < 2; ++half) {
      const int r = i2 + 32 * half;
      const int row = base + r;
      const int n = (row < numRows) ? row : (numRows - 1);
      const int p0 = csr_off[n], p1 = csr_off[n + 1];
      const u16* basep = (q < 4) ? (const u16*)P0 : (const u16*)P1;
      const int coff = (q < 4) ? 32 * q : 32 * (q - 4);
      float acc[32];
      const u16* self = basep + (size_t)n * 128 + coff;
      #pragma unroll
      for (int c8 = 0; c8 < 4; ++c8) {
        short8v v = *(const short8v*)(self + 8 * c8);
        #pragma unroll
        for (int j = 0; j < 8; ++j) acc[8 * c8 + j] = alpha * bf2f((u16)v[j]);
      }
      for (int p = p0; p < p1; ++p) {
        const u16* nb = basep + (size_t)csr_s[p] * 128 + coff;
        #pragma unroll
        for (int c8 = 0; c8 < 4; ++c8) {
          short8v v = *(const short8v*)(nb + 8 * c8);
          #pragma unroll
          for (int j = 0; j < 8; ++j) acc[8 * c8 + j] += bf2f((u16)v[j]);
        }
      }
      #pragma unroll
      for (int c4 = 0; c4 < 8; ++c4) {
        short4v o = {(short)f2bf(acc[4 * c4 + 0]), (short)f2bf(acc[4 * c4 + 1]),
                     (short)f2bf(acc[4 * c4 + 2]), (short)f2bf(acc[4 * c4 + 3])};
        *(short4v*)(&amem[r * RS + 32 * q + (q < 4 ? 0 : 128 - 32 * 4) + 4 * c4 - (q < 4 ? 0 : 0)]) = o;
      }
    }
  } else {  // PREP_GINX
    const int i = t >> 2, q = t & 3;
    const int row = base + i;
    const int n = (row < numRows) ? row : (numRows - 1);
    const int p0 = csr_off[n], p1 = csr_off[n + 1];
    float acc[32];
    const u16* self = (const u16*)P0 + (size_t)n * 128 + 32 * q;
    #pragma unroll
    for (int c8 = 0; c8 < 4; ++c8) {
      short8v v = *(const short8v*)(self + 8 * c8);
      #pragma unroll
      for (int j = 0; j < 8; ++j) acc[8 * c8 + j] = alpha * bf2f((u16)v[j]);
    }
    for (int p = p0; p < p1; ++p) {
      const u16* nb = (const u16*)P0 + (size_t)csr_s[p] * 128 + 32 * q;
      #pragma unroll
      for (int c8 = 0; c8 < 4; ++c8) {
        short8v v = *(const short8v*)(nb + 8 * c8);
        #pragma unroll
        for (int j = 0; j < 8; ++j) acc[8 * c8 + j] += bf2f((u16)v[j]);
      }
    }
    #pragma unroll
    for (int c4 = 0; c4 < 8; ++c4) {
      short4v o = {(short)f2bf(acc[4 * c4 + 0]), (short)f2bf(acc[4 * c4 + 1]),
                   (short)f2bf(acc[4 * c4 + 2]), (short)f2bf(acc[4 * c4 + 3])};
      *(short4v*)(&amem[i * RS + 32 * q + 4 * c4]) = o;
    }
  }
  __syncthreads();
  if constexpr (WLATE) load_w();

  // ---- MFMA main loop ----
  f32x4 acc[4][2];
  #pragma unroll
  for (int rt = 0; rt < 4; ++rt)
    #pragma unroll
    for (int ct = 0; ct < 2; ++ct) acc[rt][ct] = (f32x4){0.f, 0.f, 0.f, 0.f};
  #pragma unroll
  for (int s = 0; s < KSTEPS; ++s) {
    bf16x8v af[4];
    #pragma unroll
    for (int rt = 0; rt < 4; ++rt) {
      short8v araw = *(const short8v*)(&amem[(16 * rt + n0) * RS + s * 32 + g * 8]);
      af[rt] = __builtin_bit_cast(bf16x8v, araw);
    }
    #pragma unroll
    for (int rt = 0; rt < 4; ++rt)
      #pragma unroll
      for (int ct = 0; ct < 2; ++ct)
        acc[rt][ct] = __builtin_amdgcn_mfma_f32_16x16x32_bf16(
            af[rt], __builtin_bit_cast(bf16x8v, wf[s][ct]), acc[rt][ct], 0, 0, 0);
  }

  // ---- EDGE residual: route reg-held h tile through LDS to C positions ----
  if constexpr (EPIM == EPI_ABR) {
    __syncthreads();  // all A reads done
    {
      const int i = t >> 2, q = t & 3;
      #pragma unroll
      for (int c = 0; c < 4; ++c)
        *(short8v*)(&amem[i * RS + q * 32 + 8 * c]) = hself[c];
    }
    __syncthreads();
  }

  // ---- epilogue: C/D layout col=lane&15, row=(lane>>4)*4+reg ----
  if constexpr (OUTBF) {
    if constexpr (EPIM != EPI_ABR) __syncthreads();  // reuse amem for C staging
    #pragma unroll
    for (int rt = 0; rt < 4; ++rt) {
      #pragma unroll
      for (int ct = 0; ct < 2; ++ct) {
        #pragma unroll
        for (int r = 0; r < 4; ++r) {
          int lrow = 16 * rt + 4 * g + r;
          int lcol = (2 * w + ct) * 16 + n0;
          float o = acc[rt][ct][r];
          if constexpr (EPIM == EPI_ABR) o += bf2f((u16)amem[lrow * RS + lcol]);
          o = fmaxf(o + bb[ct], 0.f);
          amem[lrow * RS + lcol] = (short)f2bf(o);
        }
      }
    }
    __syncthreads();
    {
      const int i = t >> 2, q = t & 3;
      const int row = base + i;
      if (row < numRows) {
        u16* orow = (u16*)Out + (size_t)row * 128 + q * 32;
        #pragma unroll
        for (int c = 0; c < 4; ++c)
          *(short8v*)(orow + 8 * c) = *(const short8v*)(&amem[i * RS + q * 32 + 8 * c]);
      }
    }
  } else {
    #pragma unroll
    for (int rt = 0; rt < 4; ++rt) {
      #pragma unroll
      for (int ct = 0; ct < 2; ++ct) {
        #pragma unroll
        for (int r = 0; r < 4; ++r) {
          int row = base + 16 * rt + 4 * g + r;
          if (row < numRows) {
            int lrow = 16 * rt + 4 * g + r;
            int lcol = (2 * w + ct) * 16 + n0;
            float o = acc[rt][ct][r];
            if constexpr (EPIM == EPI_ABR) o += bf2f((u16)amem[lrow * RS + lcol]);
            o = fmaxf(o + bb[ct], 0.f);
            ((float*)Out)[(size_t)row * 128 + lcol] = o;
          }
        }
      }
    }
  }
}

extern "C" void kernel_launch(void* const* d_in, const int* in_sizes, int n_in,
                              void* d_out, int out_size, void* d_ws, size_t ws_size,
                              hipStream_t stream) {
  const float* nf     = (const float*)d_in[0];
  const float* ef     = (const float*)d_in[1];
  const float* W_init = (const float*)d_in[2];
  const float* b_init = (const float*)d_in[3];
  const float* W_edge = (const float*)d_in[4];
  const float* b_edge = (const float*)d_in[5];
  const float* W_gin0 = (const float*)d_in[6];
  const float* W_gin  = (const float*)d_in[7];
  const float* b_gin  = (const float*)d_in[8];
  const float* eps    = (const float*)d_in[9];
  const int* esrc     = (const int*)d_in[10];
  const int* edst     = (const int*)d_in[11];
  // d_in[12] = edge_rev == e^1 by construction.

  float* xout  = (float*)d_out;                     // [N,128] f32
  float* h_out = xout + (size_t)N_NODES * 128;      // [E,128] f32 (final h)

  const size_t NB = (size_t)N_NODES * 128 * 2;      // bf16 node block (25.6MB)
  const size_t EB = (size_t)N_EDGES * 128 * 2;      // bf16 edge block (153.6MB)
  char* wsb = (char*)d_ws;
  u16* aggbf   = (u16*)wsb;                         // edge phase; later aliased by xbf1
  u16* xbf1    = (u16*)wsb;
  u16* hbf     = (u16*)(wsb + NB);
  u16* readout = (u16*)(wsb + NB + EB);
  u16* xbf0    = (u16*)(wsb + 2 * NB + EB);
  u16* nfbf    = (u16*)(wsb + 3 * NB + EB);
  int* csr_off = (int*)(wsb + 4 * NB + EB);         // N+1
  int* cursor  = csr_off + (N_NODES + 1);           // N (histogram, zeroed by scan)
  int* csr_e   = cursor + N_NODES;                  // E
  int* csr_s   = csr_e + N_EDGES;                   // E

  // ---- nf -> bf16 ----
  convert_nf_kernel<<<(N_NODES * 128 / 8 + 255) / 256, 256, 0, stream>>>(nf, nfbf);

  // ---- CSR by dst ----
  hipMemsetAsync(cursor, 0, N_NODES * sizeof(int), stream);
  hist_kernel<<<(N_EDGES + 255) / 256, 256, 0, stream>>>(edst, cursor);
  scan_kernel<<<1, 1024, 0, stream>>>(cursor, csr_off);   // also zeroes cursor
  fill_kernel<<<(N_EDGES + 255) / 256, 256, 0, stream>>>(edst, esrc, csr_off, cursor, csr_e, csr_s);

  const int ETILES = N_EDGES / 64;          // 9375
  const int NTILES = (N_NODES + 63) / 64;   // 1563

  // ---- init edge states: hbf = relu([nfbf[src]|ef] @ W_init + b) ----
  mfma_gemm<5, PREP_INIT, EPI_BR, 1><<<ETILES, 256, 0, stream>>>(
      W_init, 144, b_init, nfbf, ef, esrc, nullptr, nullptr, nullptr, hbf, N_EDGES);

  // ---- EdgeConv steps 0..3 (in place on hbf) ----
  for (int t = 0; t < 4; ++t) {
    segsum_hbf_kernel<<<N_NODES / 4, 256, 0, stream>>>(hbf, csr_off, csr_e, aggbf);
    mfma_gemm<4, PREP_EDGE, EPI_ABR, 1><<<ETILES, 256, 0, stream>>>(
        W_edge + (size_t)t * 128 * 128, 128, b_edge + (size_t)t * 128,
        aggbf, hbf, esrc, nullptr, nullptr, nullptr, hbf, N_EDGES);
  }

  // ---- fused: h_out (f32) expansion + readout (bf16) ----
  expand_readout_kernel<<<N_NODES / 4, 256, 0, stream>>>(hbf, csr_off, csr_e, h_out, readout);

  // ---- GIN step 0: fused K=256 GEMM with inline gathers ----
  mfma_gemm<8, PREP_GIN0, EPI_BR, 1><<<NTILES, 256, 0, stream>>>(
      W_gin0, 256, b_gin, nfbf, readout, nullptr, csr_off, csr_s, eps, xbf0, N_NODES);

  // ---- GIN steps 1..3 (xbf1 aliases dead aggbf) ----
  mfma_gemm<4, PREP_GINX, EPI_BR, 1><<<NTILES, 256, 0, stream>>>(
      W_gin, 128, b_gin + 128, xbf0, nullptr, nullptr, csr_off, csr_s, eps + 1, xbf1, N_NODES);
  mfma_gemm<4, PREP_GINX, EPI_BR, 1><<<NTILES, 256, 0, stream>>>(
      W_gin + (size_t)128 * 128, 128, b_gin + 256, xbf1, nullptr, nullptr, csr_off, csr_s, eps + 2, xbf0, N_NODES);
  mfma_gemm<4, PREP_GINX, EPI_BR, 0><<<NTILES, 256, 0, stream>>>(
      W_gin + (size_t)2 * 128 * 128, 128, b_gin + 384, xbf0, nullptr, nullptr, csr_off, csr_s, eps + 3, xout, N_NODES);

  (void)in_sizes; (void)n_in; (void)out_size; (void)ws_size;
}

// Round 6
// 1261.592 us; speedup vs baseline: 2.7102x; 1.1709x over previous
//
#include <hip/hip_runtime.h>

#define N_NODES 100000
#define N_EDGES 600000
#define SCAN_NB ((N_NODES + 255) / 256)   // 391

typedef unsigned short u16;
typedef __attribute__((ext_vector_type(8))) short short8v;
typedef __attribute__((ext_vector_type(4))) short short4v;
typedef __attribute__((ext_vector_type(4))) float f32x4;
typedef __attribute__((ext_vector_type(8))) __bf16 bf16x8v;

__device__ __forceinline__ u16 f2bf(float f) {
  unsigned u = __builtin_bit_cast(unsigned, f);
  unsigned r = (u + 0x7fffu + ((u >> 16) & 1u)) >> 16;
  return (u16)r;
}
__device__ __forceinline__ float bf2f(u16 v) {
  unsigned u = ((unsigned)v) << 16;
  return __builtin_bit_cast(float, u);
}
__device__ __forceinline__ short8v shfl_xor4_v(short8v v) {
  int4 iv = __builtin_bit_cast(int4, v);
  iv.x = __shfl_xor(iv.x, 4, 64);
  iv.y = __shfl_xor(iv.y, 4, 64);
  iv.z = __shfl_xor(iv.z, 4, 64);
  iv.w = __shfl_xor(iv.w, 4, 64);
  return __builtin_bit_cast(short8v, iv);
}

// ---------------- nf -> bf16 ----------------
__global__ __launch_bounds__(256) void convert_nf_kernel(const float* __restrict__ nf,
                                                         u16* __restrict__ nfbf) {
  size_t idx = ((size_t)blockIdx.x * 256 + threadIdx.x) * 8;
  if (idx >= (size_t)N_NODES * 128) return;
  float4 a = *(const float4*)(nf + idx);
  float4 b = *(const float4*)(nf + idx + 4);
  short8v o = {(short)f2bf(a.x), (short)f2bf(a.y), (short)f2bf(a.z), (short)f2bf(a.w),
               (short)f2bf(b.x), (short)f2bf(b.y), (short)f2bf(b.z), (short)f2bf(b.w)};
  *(short8v*)(nfbf + idx) = o;
}

// ---------------- CSR build ----------------
__global__ void hist_kernel(const int* __restrict__ dst, int* __restrict__ cnt) {
  int e = blockIdx.x * 256 + threadIdx.x;
  if (e < N_EDGES) atomicAdd(&cnt[dst[e]], 1);
}

// phase 1: block-local exclusive scan; zero cnt (reused as fill cursor)
__global__ __launch_bounds__(256) void scan1_kernel(int* __restrict__ cnt,
                                                    int* __restrict__ off,
                                                    int* __restrict__ blk) {
  __shared__ int s[256];
  int i = blockIdx.x * 256 + threadIdx.x;
  int v = (i < N_NODES) ? cnt[i] : 0;
  if (i < N_NODES) cnt[i] = 0;
  s[threadIdx.x] = v;
  __syncthreads();
  for (int d = 1; d < 256; d <<= 1) {
    int t = (threadIdx.x >= d) ? s[threadIdx.x - d] : 0;
    __syncthreads();
    s[threadIdx.x] += t;
    __syncthreads();
  }
  if (i < N_NODES) off[i] = s[threadIdx.x] - v;   // exclusive within block
  if (threadIdx.x == 255) blk[blockIdx.x] = s[255];
}

// phase 2: exclusive scan of the block totals (SCAN_NB=391 <= 512)
__global__ __launch_bounds__(512) void scan2_kernel(int* __restrict__ blk) {
  __shared__ int s[512];
  int v = (threadIdx.x < SCAN_NB) ? blk[threadIdx.x] : 0;
  s[threadIdx.x] = v;
  __syncthreads();
  for (int d = 1; d < 512; d <<= 1) {
    int t = (threadIdx.x >= d) ? s[threadIdx.x - d] : 0;
    __syncthreads();
    s[threadIdx.x] += t;
    __syncthreads();
  }
  if (threadIdx.x < SCAN_NB) blk[threadIdx.x] = s[threadIdx.x] - v;
}

// phase 3: add block offsets; set off[N]
__global__ __launch_bounds__(256) void scan3_kernel(int* __restrict__ off,
                                                    const int* __restrict__ blk) {
  int i = blockIdx.x * 256 + threadIdx.x;
  if (i < N_NODES) off[i] += blk[blockIdx.x];
  if (i == 0) off[N_NODES] = N_EDGES;
}

__global__ void fill_kernel(const int* __restrict__ dst, const int* __restrict__ src,
                            const int* __restrict__ off, int* __restrict__ cur,
                            int* __restrict__ csr_e, int* __restrict__ csr_s) {
  int e = blockIdx.x * 256 + threadIdx.x;
  if (e < N_EDGES) {
    int d = dst[e];
    int p = off[d] + atomicAdd(&cur[d], 1);
    csr_e[p] = e;
    csr_s[p] = src[e];
  }
}

// ---------------- segment sum over bf16 h (one wave per node, shfl-bcast edges) ----
__global__ __launch_bounds__(256) void segsum_hbf_kernel(const u16* __restrict__ hbf,
                                                         const int* __restrict__ off,
                                                         const int* __restrict__ csr_e,
                                                         u16* __restrict__ aggb) {
  int node = blockIdx.x * 4 + (threadIdx.x >> 6);
  int l = threadIdx.x & 63;
  int p0 = off[node], p1 = off[node + 1];
  int deg = p1 - p0;
  int e_l = (l < deg) ? csr_e[p0 + min(l, deg - 1)] : 0;
  float a0 = 0.f, a1 = 0.f;
  int jmax = min(deg, 64);
  for (int j = 0; j < jmax; ++j) {
    int e = __shfl(e_l, j, 64);
    unsigned u = *(const unsigned*)(hbf + (size_t)e * 128 + 2 * l);
    a0 += __builtin_bit_cast(float, u << 16);
    a1 += __builtin_bit_cast(float, u & 0xffff0000u);
  }
  for (int p = p0 + 64; p < p1; ++p) {  // deg > 64: essentially never
    int e = csr_e[p];
    unsigned u = *(const unsigned*)(hbf + (size_t)e * 128 + 2 * l);
    a0 += __builtin_bit_cast(float, u << 16);
    a1 += __builtin_bit_cast(float, u & 0xffff0000u);
  }
  unsigned o = (unsigned)f2bf(a0) | (((unsigned)f2bf(a1)) << 16);
  *(unsigned*)(aggb + (size_t)node * 128 + 2 * l) = o;
}

// ---- fused: readout[n] = sum of final h rows; also expand hbf -> f32 h_out ----
__global__ __launch_bounds__(256) void expand_readout_kernel(const u16* __restrict__ hbf,
                                                             const int* __restrict__ off,
                                                             const int* __restrict__ csr_e,
                                                             float* __restrict__ h_out,
                                                             u16* __restrict__ readout) {
  int node = blockIdx.x * 4 + (threadIdx.x >> 6);
  int l = threadIdx.x & 63;
  int p0 = off[node], p1 = off[node + 1];
  int deg = p1 - p0;
  int e_l = (l < deg) ? csr_e[p0 + min(l, deg - 1)] : 0;
  float a0 = 0.f, a1 = 0.f;
  int jmax = min(deg, 64);
  for (int j = 0; j < jmax; ++j) {
    int e = __shfl(e_l, j, 64);
    unsigned u = *(const unsigned*)(hbf + (size_t)e * 128 + 2 * l);
    float f0 = __builtin_bit_cast(float, u << 16);
    float f1 = __builtin_bit_cast(float, u & 0xffff0000u);
    a0 += f0; a1 += f1;
    float2 w = {f0, f1};
    *(float2*)(h_out + (size_t)e * 128 + 2 * l) = w;
  }
  for (int p = p0 + 64; p < p1; ++p) {
    int e = csr_e[p];
    unsigned u = *(const unsigned*)(hbf + (size_t)e * 128 + 2 * l);
    float f0 = __builtin_bit_cast(float, u << 16);
    float f1 = __builtin_bit_cast(float, u & 0xffff0000u);
    a0 += f0; a1 += f1;
    float2 w = {f0, f1};
    *(float2*)(h_out + (size_t)e * 128 + 2 * l) = w;
  }
  unsigned o = (unsigned)f2bf(a0) | (((unsigned)f2bf(a1)) << 16);
  *(unsigned*)(readout + (size_t)node * 128 + 2 * l) = o;
}

// ---------------- unified MFMA GEMM ----------------
// Tile 64 rows x 128 cols, 256 threads (4 waves); wave w -> cols [32w,32w+32).
// W fragments in registers; A staged in LDS bf16 (row stride RS shorts).
// k-mapping k = 32s+8g+j consistent between A and B fragments.
// EDGE: h tile read ONCE (regs); rev via shfl_xor(4); residual routed via LDS.
// GIN: CSR neighbor gather fused into prep.
#define PREP_INIT 0
#define PREP_EDGE 1
#define PREP_GIN0 2
#define PREP_GINX 3
#define EPI_BR  1
#define EPI_ABR 2   // add LDS-staged residual (EDGE)

template<int KSTEPS, int PREPM, int EPIM, int OUTBF>
__global__ __launch_bounds__(256, 3) void mfma_gemm(
    const float* __restrict__ Wf, int KREAL,
    const float* __restrict__ bias,
    const void* __restrict__ P0,      // INIT: nfbf u16; EDGE: aggb u16; GIN0: nfbf u16; GINX: x u16
    const void* __restrict__ P1,      // INIT: ef f32; EDGE: hbf u16; GIN0: readout u16
    const int* __restrict__ srcIdx,   // INIT/EDGE: edge_src
    const int* __restrict__ csr_off,  // GIN: gather offsets
    const int* __restrict__ csr_s,    // GIN: gather sources
    const float* __restrict__ epsp,   // GIN: eps scalar
    void* __restrict__ Out, int numRows) {
  constexpr int RS = KSTEPS * 32 + 8;
  constexpr bool WLATE = (KSTEPS >= 8);
  __shared__ short amem[64 * RS];
  const int t = threadIdx.x;
  const int l = t & 63;
  const int w = t >> 6;
  const int g = l >> 4;
  const int n0 = l & 15;
  const int base = blockIdx.x * 64;

  short8v wf[KSTEPS][2];
  auto load_w = [&]() {
    #pragma unroll
    for (int s = 0; s < KSTEPS; ++s) {
      #pragma unroll
      for (int ct = 0; ct < 2; ++ct) {
        short8v v;
        #pragma unroll
        for (int j = 0; j < 8; ++j) {
          int k = 32 * s + 8 * g + j;
          float wv = (k < KREAL) ? Wf[(size_t)k * 128 + (2 * w + ct) * 16 + n0] : 0.f;
          v[j] = (short)f2bf(wv);
        }
        wf[s][ct] = v;
      }
    }
  };
  if constexpr (!WLATE) load_w();

  float bb[2];
  #pragma unroll
  for (int ct = 0; ct < 2; ++ct) bb[ct] = bias[(2 * w + ct) * 16 + n0];
  float alpha = 0.f;
  if constexpr (PREPM == PREP_GIN0 || PREPM == PREP_GINX) alpha = 1.f + epsp[0];

  short8v hself[4];  // EDGE residual tile, regs (thread (i,q): row i, cols 32q..32q+31)

  // ---- prep: stage A tile (bf16) ----
  if constexpr (PREPM == PREP_INIT) {
    const int i = t >> 2, q = t & 3;
    const int row = base + i;
    const int sn = srcIdx[row];
    const u16* nrow = (const u16*)P0 + (size_t)sn * 128 + q * 32;
    #pragma unroll
    for (int c = 0; c < 4; ++c)
      *(short8v*)(&amem[i * RS + q * 32 + 8 * c]) = *(const short8v*)(nrow + 8 * c);
    #pragma unroll
    for (int z = 0; z < 2; ++z) {
      int col = 128 + (2 * q + z) * 4;
      short4v o = {0, 0, 0, 0};
      if (col < 144) {
        float4 vv = *(const float4*)((const float*)P1 + (size_t)row * 16 + (col - 128));
        o = {(short)f2bf(vv.x), (short)f2bf(vv.y), (short)f2bf(vv.z), (short)f2bf(vv.w)};
      }
      *(short4v*)(&amem[i * RS + col]) = o;
    }
  } else if constexpr (PREPM == PREP_EDGE) {
    const int i = t >> 2, q = t & 3;
    const int row = base + i;
    const int sn = srcIdx[row];
    const u16* arow = (const u16*)P0 + (size_t)sn * 128 + q * 32;
    const u16* hrow = (const u16*)P1 + (size_t)row * 128 + q * 32;
    short8v av[4];
    #pragma unroll
    for (int c = 0; c < 4; ++c) av[c] = *(const short8v*)(arow + 8 * c);
    #pragma unroll
    for (int c = 0; c < 4; ++c) hself[c] = *(const short8v*)(hrow + 8 * c);
    #pragma unroll
    for (int c = 0; c < 4; ++c) {
      short8v hrev = shfl_xor4_v(hself[c]);  // thread t^4 holds row i^1
      short8v o;
      #pragma unroll
      for (int j = 0; j < 8; ++j)
        o[j] = (short)f2bf(bf2f((u16)av[c][j]) - bf2f((u16)hrev[j]));
      *(short8v*)(&amem[i * RS + q * 32 + 8 * c]) = o;
    }
  } else if constexpr (PREPM == PREP_GIN0) {
    const int i2 = t >> 3, q = t & 7;
    #pragma unroll
    for (int half = 0; half < 2; ++half) {
      const int r = i2 + 32 * half;
      const int row = base + r;
      const int n = (row < numRows) ? row : (numRows - 1);
      const int p0 = csr_off[n], p1 = csr_off[n + 1];
      const u16* basep = (q < 4) ? (const u16*)P0 : (const u16*)P1;
      const int coff = (q < 4) ? 32 * q : 32 * (q - 4);
      float acc[32];
      const u16* self = basep + (size_t)n * 128 + coff;
      #pragma unroll
      for (int c8 = 0; c8 < 4; ++c8) {
        short8v v = *(const short8v*)(self + 8 * c8);
        #pragma unroll
        for (int j = 0; j < 8; ++j) acc[8 * c8 + j] = alpha * bf2f((u16)v[j]);
      }
      for (int p = p0; p < p1; ++p) {
        const u16* nb = basep + (size_t)csr_s[p] * 128 + coff;
        #pragma unroll
        for (int c8 = 0; c8 < 4; ++c8) {
          short8v v = *(const short8v*)(nb + 8 * c8);
          #pragma unroll
          for (int j = 0; j < 8; ++j) acc[8 * c8 + j] += bf2f((u16)v[j]);
        }
      }
      #pragma unroll
      for (int c4 = 0; c4 < 8; ++c4) {
        short4v o = {(short)f2bf(acc[4 * c4 + 0]), (short)f2bf(acc[4 * c4 + 1]),
                     (short)f2bf(acc[4 * c4 + 2]), (short)f2bf(acc[4 * c4 + 3])};
        *(short4v*)(&amem[r * RS + 32 * q + 4 * c4]) = o;
      }
    }
  } else {  // PREP_GINX
    const int i = t >> 2, q = t & 3;
    const int row = base + i;
    const int n = (row < numRows) ? row : (numRows - 1);
    const int p0 = csr_off[n], p1 = csr_off[n + 1];
    float acc[32];
    const u16* self = (const u16*)P0 + (size_t)n * 128 + 32 * q;
    #pragma unroll
    for (int c8 = 0; c8 < 4; ++c8) {
      short8v v = *(const short8v*)(self + 8 * c8);
      #pragma unroll
      for (int j = 0; j < 8; ++j) acc[8 * c8 + j] = alpha * bf2f((u16)v[j]);
    }
    for (int p = p0; p < p1; ++p) {
      const u16* nb = (const u16*)P0 + (size_t)csr_s[p] * 128 + 32 * q;
      #pragma unroll
      for (int c8 = 0; c8 < 4; ++c8) {
        short8v v = *(const short8v*)(nb + 8 * c8);
        #pragma unroll
        for (int j = 0; j < 8; ++j) acc[8 * c8 + j] += bf2f((u16)v[j]);
      }
    }
    #pragma unroll
    for (int c4 = 0; c4 < 8; ++c4) {
      short4v o = {(short)f2bf(acc[4 * c4 + 0]), (short)f2bf(acc[4 * c4 + 1]),
                   (short)f2bf(acc[4 * c4 + 2]), (short)f2bf(acc[4 * c4 + 3])};
      *(short4v*)(&amem[i * RS + 32 * q + 4 * c4]) = o;
    }
  }
  __syncthreads();
  if constexpr (WLATE) load_w();

  // ---- MFMA main loop ----
  f32x4 acc[4][2];
  #pragma unroll
  for (int rt = 0; rt < 4; ++rt)
    #pragma unroll
    for (int ct = 0; ct < 2; ++ct) acc[rt][ct] = (f32x4){0.f, 0.f, 0.f, 0.f};
  #pragma unroll
  for (int s = 0; s < KSTEPS; ++s) {
    bf16x8v af[4];
    #pragma unroll
    for (int rt = 0; rt < 4; ++rt) {
      short8v araw = *(const short8v*)(&amem[(16 * rt + n0) * RS + s * 32 + g * 8]);
      af[rt] = __builtin_bit_cast(bf16x8v, araw);
    }
    #pragma unroll
    for (int rt = 0; rt < 4; ++rt)
      #pragma unroll
      for (int ct = 0; ct < 2; ++ct)
        acc[rt][ct] = __builtin_amdgcn_mfma_f32_16x16x32_bf16(
            af[rt], __builtin_bit_cast(bf16x8v, wf[s][ct]), acc[rt][ct], 0, 0, 0);
  }

  // ---- EDGE residual: route reg-held h tile through LDS to C positions ----
  if constexpr (EPIM == EPI_ABR) {
    __syncthreads();  // all A reads done
    {
      const int i = t >> 2, q = t & 3;
      #pragma unroll
      for (int c = 0; c < 4; ++c)
        *(short8v*)(&amem[i * RS + q * 32 + 8 * c]) = hself[c];
    }
    __syncthreads();
  }

  // ---- epilogue: C/D layout col=lane&15, row=(lane>>4)*4+reg ----
  if constexpr (OUTBF) {
    if constexpr (EPIM != EPI_ABR) __syncthreads();  // reuse amem for C staging
    #pragma unroll
    for (int rt = 0; rt < 4; ++rt) {
      #pragma unroll
      for (int ct = 0; ct < 2; ++ct) {
        #pragma unroll
        for (int r = 0; r < 4; ++r) {
          int lrow = 16 * rt + 4 * g + r;
          int lcol = (2 * w + ct) * 16 + n0;
          float o = acc[rt][ct][r];
          if constexpr (EPIM == EPI_ABR) o += bf2f((u16)amem[lrow * RS + lcol]);
          o = fmaxf(o + bb[ct], 0.f);
          amem[lrow * RS + lcol] = (short)f2bf(o);
        }
      }
    }
    __syncthreads();
    {
      const int i = t >> 2, q = t & 3;
      const int row = base + i;
      if (row < numRows) {
        u16* orow = (u16*)Out + (size_t)row * 128 + q * 32;
        #pragma unroll
        for (int c = 0; c < 4; ++c)
          *(short8v*)(orow + 8 * c) = *(const short8v*)(&amem[i * RS + q * 32 + 8 * c]);
      }
    }
  } else {
    #pragma unroll
    for (int rt = 0; rt < 4; ++rt) {
      #pragma unroll
      for (int ct = 0; ct < 2; ++ct) {
        #pragma unroll
        for (int r = 0; r < 4; ++r) {
          int row = base + 16 * rt + 4 * g + r;
          if (row < numRows) {
            int lrow = 16 * rt + 4 * g + r;
            int lcol = (2 * w + ct) * 16 + n0;
            float o = acc[rt][ct][r];
            if constexpr (EPIM == EPI_ABR) o += bf2f((u16)amem[lrow * RS + lcol]);
            o = fmaxf(o + bb[ct], 0.f);
            ((float*)Out)[(size_t)row * 128 + lcol] = o;
          }
        }
      }
    }
  }
}

extern "C" void kernel_launch(void* const* d_in, const int* in_sizes, int n_in,
                              void* d_out, int out_size, void* d_ws, size_t ws_size,
                              hipStream_t stream) {
  const float* nf     = (const float*)d_in[0];
  const float* ef     = (const float*)d_in[1];
  const float* W_init = (const float*)d_in[2];
  const float* b_init = (const float*)d_in[3];
  const float* W_edge = (const float*)d_in[4];
  const float* b_edge = (const float*)d_in[5];
  const float* W_gin0 = (const float*)d_in[6];
  const float* W_gin  = (const float*)d_in[7];
  const float* b_gin  = (const float*)d_in[8];
  const float* eps    = (const float*)d_in[9];
  const int* esrc     = (const int*)d_in[10];
  const int* edst     = (const int*)d_in[11];
  // d_in[12] = edge_rev == e^1 by construction.

  float* xout  = (float*)d_out;                     // [N,128] f32
  float* h_out = xout + (size_t)N_NODES * 128;      // [E,128] f32 (final h)

  const size_t NB = (size_t)N_NODES * 128 * 2;      // bf16 node block (25.6MB)
  const size_t EB = (size_t)N_EDGES * 128 * 2;      // bf16 edge block (153.6MB)
  char* wsb = (char*)d_ws;
  u16* aggbf   = (u16*)wsb;                         // edge phase; later aliased by xbf1
  u16* xbf1    = (u16*)wsb;
  u16* hbf     = (u16*)(wsb + NB);
  u16* readout = (u16*)(wsb + NB + EB);
  u16* xbf0    = (u16*)(wsb + 2 * NB + EB);
  u16* nfbf    = (u16*)(wsb + 3 * NB + EB);
  int* csr_off = (int*)(wsb + 4 * NB + EB);         // N+1
  int* cursor  = csr_off + (N_NODES + 1);           // N (histogram, zeroed by scan1)
  int* csr_e   = cursor + N_NODES;                  // E
  int* csr_s   = csr_e + N_EDGES;                   // E
  int* blk     = csr_s + N_EDGES;                   // SCAN_NB

  // ---- nf -> bf16 ----
  convert_nf_kernel<<<(N_NODES * 128 / 8 + 255) / 256, 256, 0, stream>>>(nf, nfbf);

  // ---- CSR by dst (3-phase parallel scan) ----
  hipMemsetAsync(cursor, 0, N_NODES * sizeof(int), stream);
  hist_kernel<<<(N_EDGES + 255) / 256, 256, 0, stream>>>(edst, cursor);
  scan1_kernel<<<SCAN_NB, 256, 0, stream>>>(cursor, csr_off, blk);
  scan2_kernel<<<1, 512, 0, stream>>>(blk);
  scan3_kernel<<<SCAN_NB, 256, 0, stream>>>(csr_off, blk);
  fill_kernel<<<(N_EDGES + 255) / 256, 256, 0, stream>>>(edst, esrc, csr_off, cursor, csr_e, csr_s);

  const int ETILES = N_EDGES / 64;          // 9375
  const int NTILES = (N_NODES + 63) / 64;   // 1563

  // ---- init edge states: hbf = relu([nfbf[src]|ef] @ W_init + b) ----
  mfma_gemm<5, PREP_INIT, EPI_BR, 1><<<ETILES, 256, 0, stream>>>(
      W_init, 144, b_init, nfbf, ef, esrc, nullptr, nullptr, nullptr, hbf, N_EDGES);

  // ---- EdgeConv steps 0..3 (in place on hbf) ----
  for (int t = 0; t < 4; ++t) {
    segsum_hbf_kernel<<<N_NODES / 4, 256, 0, stream>>>(hbf, csr_off, csr_e, aggbf);
    mfma_gemm<4, PREP_EDGE, EPI_ABR, 1><<<ETILES, 256, 0, stream>>>(
        W_edge + (size_t)t * 128 * 128, 128, b_edge + (size_t)t * 128,
        aggbf, hbf, esrc, nullptr, nullptr, nullptr, hbf, N_EDGES);
  }

  // ---- fused: h_out (f32) expansion + readout (bf16) ----
  expand_readout_kernel<<<N_NODES / 4, 256, 0, stream>>>(hbf, csr_off, csr_e, h_out, readout);

  // ---- GIN step 0: fused K=256 GEMM with inline gathers ----
  mfma_gemm<8, PREP_GIN0, EPI_BR, 1><<<NTILES, 256, 0, stream>>>(
      W_gin0, 256, b_gin, nfbf, readout, nullptr, csr_off, csr_s, eps, xbf0, N_NODES);

  // ---- GIN steps 1..3 (xbf1 aliases dead aggbf) ----
  mfma_gemm<4, PREP_GINX, EPI_BR, 1><<<NTILES, 256, 0, stream>>>(
      W_gin, 128, b_gin + 128, xbf0, nullptr, nullptr, csr_off, csr_s, eps + 1, xbf1, N_NODES);
  mfma_gemm<4, PREP_GINX, EPI_BR, 1><<<NTILES, 256, 0, stream>>>(
      W_gin + (size_t)128 * 128, 128, b_gin + 256, xbf1, nullptr, nullptr, csr_off, csr_s, eps + 2, xbf0, N_NODES);
  mfma_gemm<4, PREP_GINX, EPI_BR, 0><<<NTILES, 256, 0, stream>>>(
      W_gin + (size_t)2 * 128 * 128, 128, b_gin + 384, xbf0, nullptr, nullptr, csr_off, csr_s, eps + 3, xout, N_NODES);

  (void)in_sizes; (void)n_in; (void)out_size; (void)ws_size;
}

// Round 7
// 1178.023 us; speedup vs baseline: 2.9024x; 1.0709x over previous
//
#include <hip/hip_runtime.h>

#define N_NODES 100000
#define N_EDGES 600000
#define SCAN_NB ((N_NODES + 255) / 256)   // 391

typedef unsigned short u16;
typedef __attribute__((ext_vector_type(8))) short short8v;
typedef __attribute__((ext_vector_type(4))) short short4v;
typedef __attribute__((ext_vector_type(4))) float f32x4;
typedef __attribute__((ext_vector_type(8))) __bf16 bf16x8v;

__device__ __forceinline__ u16 f2bf(float f) {
  unsigned u = __builtin_bit_cast(unsigned, f);
  unsigned r = (u + 0x7fffu + ((u >> 16) & 1u)) >> 16;
  return (u16)r;
}
__device__ __forceinline__ float bf2f(u16 v) {
  unsigned u = ((unsigned)v) << 16;
  return __builtin_bit_cast(float, u);
}
__device__ __forceinline__ short8v shfl_xor4_v(short8v v) {
  int4 iv = __builtin_bit_cast(int4, v);
  iv.x = __shfl_xor(iv.x, 4, 64);
  iv.y = __shfl_xor(iv.y, 4, 64);
  iv.z = __shfl_xor(iv.z, 4, 64);
  iv.w = __shfl_xor(iv.w, 4, 64);
  return __builtin_bit_cast(short8v, iv);
}

// ---------------- nf -> bf16 ----------------
__global__ __launch_bounds__(256) void convert_nf_kernel(const float* __restrict__ nf,
                                                         u16* __restrict__ nfbf) {
  size_t idx = ((size_t)blockIdx.x * 256 + threadIdx.x) * 8;
  if (idx >= (size_t)N_NODES * 128) return;
  float4 a = *(const float4*)(nf + idx);
  float4 b = *(const float4*)(nf + idx + 4);
  short8v o = {(short)f2bf(a.x), (short)f2bf(a.y), (short)f2bf(a.z), (short)f2bf(a.w),
               (short)f2bf(b.x), (short)f2bf(b.y), (short)f2bf(b.z), (short)f2bf(b.w)};
  *(short8v*)(nfbf + idx) = o;
}

// ---------------- CSR build ----------------
__global__ void hist_kernel(const int* __restrict__ dst, int* __restrict__ cnt) {
  int e = blockIdx.x * 256 + threadIdx.x;
  if (e < N_EDGES) atomicAdd(&cnt[dst[e]], 1);
}

// phase 1: block-local exclusive scan; zero cnt (reused as fill cursor)
__global__ __launch_bounds__(256) void scan1_kernel(int* __restrict__ cnt,
                                                    int* __restrict__ off,
                                                    int* __restrict__ blk) {
  __shared__ int s[256];
  int i = blockIdx.x * 256 + threadIdx.x;
  int v = (i < N_NODES) ? cnt[i] : 0;
  if (i < N_NODES) cnt[i] = 0;
  s[threadIdx.x] = v;
  __syncthreads();
  for (int d = 1; d < 256; d <<= 1) {
    int t = (threadIdx.x >= d) ? s[threadIdx.x - d] : 0;
    __syncthreads();
    s[threadIdx.x] += t;
    __syncthreads();
  }
  if (i < N_NODES) off[i] = s[threadIdx.x] - v;   // exclusive within block
  if (threadIdx.x == 255) blk[blockIdx.x] = s[255];
}

// phase 2: exclusive scan of the block totals (SCAN_NB=391 <= 512)
__global__ __launch_bounds__(512) void scan2_kernel(int* __restrict__ blk) {
  __shared__ int s[512];
  int v = (threadIdx.x < SCAN_NB) ? blk[threadIdx.x] : 0;
  s[threadIdx.x] = v;
  __syncthreads();
  for (int d = 1; d < 512; d <<= 1) {
    int t = (threadIdx.x >= d) ? s[threadIdx.x - d] : 0;
    __syncthreads();
    s[threadIdx.x] += t;
    __syncthreads();
  }
  if (threadIdx.x < SCAN_NB) blk[threadIdx.x] = s[threadIdx.x] - v;
}

// phase 3: add block offsets; set off[N]
__global__ __launch_bounds__(256) void scan3_kernel(int* __restrict__ off,
                                                    const int* __restrict__ blk) {
  int i = blockIdx.x * 256 + threadIdx.x;
  if (i < N_NODES) off[i] += blk[blockIdx.x];
  if (i == 0) off[N_NODES] = N_EDGES;
}

__global__ void fill_kernel(const int* __restrict__ dst, const int* __restrict__ src,
                            const int* __restrict__ off, int* __restrict__ cur,
                            int* __restrict__ csr_e, int* __restrict__ csr_s) {
  int e = blockIdx.x * 256 + threadIdx.x;
  if (e < N_EDGES) {
    int d = dst[e];
    int p = off[d] + atomicAdd(&cur[d], 1);
    csr_e[p] = e;
    csr_s[p] = src[e];
  }
}

// ---------------- segment sum over bf16 h (one wave per node, shfl-bcast edges) ----
__global__ __launch_bounds__(256) void segsum_hbf_kernel(const u16* __restrict__ hbf,
                                                         const int* __restrict__ off,
                                                         const int* __restrict__ csr_e,
                                                         u16* __restrict__ aggb) {
  int node = blockIdx.x * 4 + (threadIdx.x >> 6);
  int l = threadIdx.x & 63;
  int p0 = off[node], p1 = off[node + 1];
  int deg = p1 - p0;
  int e_l = (l < deg) ? csr_e[p0 + min(l, deg - 1)] : 0;
  float a0 = 0.f, a1 = 0.f;
  int jmax = min(deg, 64);
  for (int j = 0; j < jmax; ++j) {
    int e = __shfl(e_l, j, 64);
    unsigned u = *(const unsigned*)(hbf + (size_t)e * 128 + 2 * l);
    a0 += __builtin_bit_cast(float, u << 16);
    a1 += __builtin_bit_cast(float, u & 0xffff0000u);
  }
  for (int p = p0 + 64; p < p1; ++p) {  // deg > 64: essentially never
    int e = csr_e[p];
    unsigned u = *(const unsigned*)(hbf + (size_t)e * 128 + 2 * l);
    a0 += __builtin_bit_cast(float, u << 16);
    a1 += __builtin_bit_cast(float, u & 0xffff0000u);
  }
  unsigned o = (unsigned)f2bf(a0) | (((unsigned)f2bf(a1)) << 16);
  *(unsigned*)(aggb + (size_t)node * 128 + 2 * l) = o;
}

// ---- readout segsum over final hbf (nontemporal loads: hbf is dead after) ----
__global__ __launch_bounds__(256) void segsum_readout_kernel(const u16* __restrict__ hbf,
                                                             const int* __restrict__ off,
                                                             const int* __restrict__ csr_e,
                                                             u16* __restrict__ readout) {
  int node = blockIdx.x * 4 + (threadIdx.x >> 6);
  int l = threadIdx.x & 63;
  int p0 = off[node], p1 = off[node + 1];
  int deg = p1 - p0;
  int e_l = (l < deg) ? csr_e[p0 + min(l, deg - 1)] : 0;
  float a0 = 0.f, a1 = 0.f;
  int jmax = min(deg, 64);
  for (int j = 0; j < jmax; ++j) {
    int e = __shfl(e_l, j, 64);
    unsigned u = __builtin_nontemporal_load((const unsigned*)(hbf + (size_t)e * 128 + 2 * l));
    a0 += __builtin_bit_cast(float, u << 16);
    a1 += __builtin_bit_cast(float, u & 0xffff0000u);
  }
  for (int p = p0 + 64; p < p1; ++p) {
    int e = csr_e[p];
    unsigned u = __builtin_nontemporal_load((const unsigned*)(hbf + (size_t)e * 128 + 2 * l));
    a0 += __builtin_bit_cast(float, u << 16);
    a1 += __builtin_bit_cast(float, u & 0xffff0000u);
  }
  unsigned o = (unsigned)f2bf(a0) | (((unsigned)f2bf(a1)) << 16);
  *(unsigned*)(readout + (size_t)node * 128 + 2 * l) = o;
}

// ---------------- unified MFMA GEMM ----------------
// Tile 64 rows x 128 cols, 256 threads (4 waves); wave w -> cols [32w,32w+32).
// W fragments in registers; A staged in LDS bf16 (row stride RS shorts).
// k-mapping k = 32s+8g+j consistent between A and B fragments.
// EDGE: h tile read ONCE (regs); rev via shfl_xor(4); residual routed via LDS.
// GIN: CSR neighbor gather fused into prep.
// OUTBF: 0 = f32 out (nontemporal), 1 = bf16 out (LDS-staged),
//        2 = bf16 out + f32 nontemporal dual-write (last edge step).
#define PREP_INIT 0
#define PREP_EDGE 1
#define PREP_GIN0 2
#define PREP_GINX 3
#define EPI_BR  1
#define EPI_ABR 2   // add LDS-staged residual (EDGE)

template<int KSTEPS, int PREPM, int EPIM, int OUTBF>
__global__ __launch_bounds__(256, 3) void mfma_gemm(
    const float* __restrict__ Wf, int KREAL,
    const float* __restrict__ bias,
    const void* __restrict__ P0,      // INIT: nfbf u16; EDGE: aggb u16; GIN0: nfbf u16; GINX: x u16
    const void* __restrict__ P1,      // INIT: ef f32; EDGE: hbf u16; GIN0: readout u16
    const int* __restrict__ srcIdx,   // INIT/EDGE: edge_src
    const int* __restrict__ csr_off,  // GIN: gather offsets
    const int* __restrict__ csr_s,    // GIN: gather sources
    const float* __restrict__ epsp,   // GIN: eps scalar
    float* __restrict__ OutF32,       // OUTBF==2: f32 dual output (h_out)
    void* __restrict__ Out, int numRows) {
  constexpr int RS = KSTEPS * 32 + 8;
  constexpr bool WLATE = (KSTEPS >= 8);
  __shared__ short amem[64 * RS];
  const int t = threadIdx.x;
  const int l = t & 63;
  const int w = t >> 6;
  const int g = l >> 4;
  const int n0 = l & 15;
  const int base = blockIdx.x * 64;

  short8v wf[KSTEPS][2];
  auto load_w = [&]() {
    #pragma unroll
    for (int s = 0; s < KSTEPS; ++s) {
      #pragma unroll
      for (int ct = 0; ct < 2; ++ct) {
        short8v v;
        #pragma unroll
        for (int j = 0; j < 8; ++j) {
          int k = 32 * s + 8 * g + j;
          float wv = (k < KREAL) ? Wf[(size_t)k * 128 + (2 * w + ct) * 16 + n0] : 0.f;
          v[j] = (short)f2bf(wv);
        }
        wf[s][ct] = v;
      }
    }
  };
  if constexpr (!WLATE) load_w();

  float bb[2];
  #pragma unroll
  for (int ct = 0; ct < 2; ++ct) bb[ct] = bias[(2 * w + ct) * 16 + n0];
  float alpha = 0.f;
  if constexpr (PREPM == PREP_GIN0 || PREPM == PREP_GINX) alpha = 1.f + epsp[0];

  short8v hself[4];  // EDGE residual tile, regs (thread (i,q): row i, cols 32q..32q+31)

  // ---- prep: stage A tile (bf16) ----
  if constexpr (PREPM == PREP_INIT) {
    const int i = t >> 2, q = t & 3;
    const int row = base + i;
    const int sn = srcIdx[row];
    const u16* nrow = (const u16*)P0 + (size_t)sn * 128 + q * 32;
    #pragma unroll
    for (int c = 0; c < 4; ++c)
      *(short8v*)(&amem[i * RS + q * 32 + 8 * c]) = *(const short8v*)(nrow + 8 * c);
    #pragma unroll
    for (int z = 0; z < 2; ++z) {
      int col = 128 + (2 * q + z) * 4;
      short4v o = {0, 0, 0, 0};
      if (col < 144) {
        float4 vv = *(const float4*)((const float*)P1 + (size_t)row * 16 + (col - 128));
        o = {(short)f2bf(vv.x), (short)f2bf(vv.y), (short)f2bf(vv.z), (short)f2bf(vv.w)};
      }
      *(short4v*)(&amem[i * RS + col]) = o;
    }
  } else if constexpr (PREPM == PREP_EDGE) {
    const int i = t >> 2, q = t & 3;
    const int row = base + i;
    const int sn = srcIdx[row];
    const u16* arow = (const u16*)P0 + (size_t)sn * 128 + q * 32;
    const u16* hrow = (const u16*)P1 + (size_t)row * 128 + q * 32;
    short8v av[4];
    #pragma unroll
    for (int c = 0; c < 4; ++c) av[c] = *(const short8v*)(arow + 8 * c);
    #pragma unroll
    for (int c = 0; c < 4; ++c) hself[c] = *(const short8v*)(hrow + 8 * c);
    #pragma unroll
    for (int c = 0; c < 4; ++c) {
      short8v hrev = shfl_xor4_v(hself[c]);  // thread t^4 holds row i^1
      short8v o;
      #pragma unroll
      for (int j = 0; j < 8; ++j)
        o[j] = (short)f2bf(bf2f((u16)av[c][j]) - bf2f((u16)hrev[j]));
      *(short8v*)(&amem[i * RS + q * 32 + 8 * c]) = o;
    }
  } else if constexpr (PREPM == PREP_GIN0) {
    const int i2 = t >> 3, q = t & 7;
    #pragma unroll
    for (int half = 0; half < 2; ++half) {
      const int r = i2 + 32 * half;
      const int row = base + r;
      const int n = (row < numRows) ? row : (numRows - 1);
      const int p0 = csr_off[n], p1 = csr_off[n + 1];
      const u16* basep = (q < 4) ? (const u16*)P0 : (const u16*)P1;
      const int coff = (q < 4) ? 32 * q : 32 * (q - 4);
      float acc[32];
      const u16* self = basep + (size_t)n * 128 + coff;
      #pragma unroll
      for (int c8 = 0; c8 < 4; ++c8) {
        short8v v = *(const short8v*)(self + 8 * c8);
        #pragma unroll
        for (int j = 0; j < 8; ++j) acc[8 * c8 + j] = alpha * bf2f((u16)v[j]);
      }
      for (int p = p0; p < p1; ++p) {
        const u16* nb = basep + (size_t)csr_s[p] * 128 + coff;
        #pragma unroll
        for (int c8 = 0; c8 < 4; ++c8) {
          short8v v = *(const short8v*)(nb + 8 * c8);
          #pragma unroll
          for (int j = 0; j < 8; ++j) acc[8 * c8 + j] += bf2f((u16)v[j]);
        }
      }
      #pragma unroll
      for (int c4 = 0; c4 < 8; ++c4) {
        short4v o = {(short)f2bf(acc[4 * c4 + 0]), (short)f2bf(acc[4 * c4 + 1]),
                     (short)f2bf(acc[4 * c4 + 2]), (short)f2bf(acc[4 * c4 + 3])};
        *(short4v*)(&amem[r * RS + 32 * q + 4 * c4]) = o;
      }
    }
  } else {  // PREP_GINX
    const int i = t >> 2, q = t & 3;
    const int row = base + i;
    const int n = (row < numRows) ? row : (numRows - 1);
    const int p0 = csr_off[n], p1 = csr_off[n + 1];
    float acc[32];
    const u16* self = (const u16*)P0 + (size_t)n * 128 + 32 * q;
    #pragma unroll
    for (int c8 = 0; c8 < 4; ++c8) {
      short8v v = *(const short8v*)(self + 8 * c8);
      #pragma unroll
      for (int j = 0; j < 8; ++j) acc[8 * c8 + j] = alpha * bf2f((u16)v[j]);
    }
    for (int p = p0; p < p1; ++p) {
      const u16* nb = (const u16*)P0 + (size_t)csr_s[p] * 128 + 32 * q;
      #pragma unroll
      for (int c8 = 0; c8 < 4; ++c8) {
        short8v v = *(const short8v*)(nb + 8 * c8);
        #pragma unroll
        for (int j = 0; j < 8; ++j) acc[8 * c8 + j] += bf2f((u16)v[j]);
      }
    }
    #pragma unroll
    for (int c4 = 0; c4 < 8; ++c4) {
      short4v o = {(short)f2bf(acc[4 * c4 + 0]), (short)f2bf(acc[4 * c4 + 1]),
                   (short)f2bf(acc[4 * c4 + 2]), (short)f2bf(acc[4 * c4 + 3])};
      *(short4v*)(&amem[i * RS + 32 * q + 4 * c4]) = o;
    }
  }
  __syncthreads();
  if constexpr (WLATE) load_w();

  // ---- MFMA main loop ----
  f32x4 acc[4][2];
  #pragma unroll
  for (int rt = 0; rt < 4; ++rt)
    #pragma unroll
    for (int ct = 0; ct < 2; ++ct) acc[rt][ct] = (f32x4){0.f, 0.f, 0.f, 0.f};
  #pragma unroll
  for (int s = 0; s < KSTEPS; ++s) {
    bf16x8v af[4];
    #pragma unroll
    for (int rt = 0; rt < 4; ++rt) {
      short8v araw = *(const short8v*)(&amem[(16 * rt + n0) * RS + s * 32 + g * 8]);
      af[rt] = __builtin_bit_cast(bf16x8v, araw);
    }
    #pragma unroll
    for (int rt = 0; rt < 4; ++rt)
      #pragma unroll
      for (int ct = 0; ct < 2; ++ct)
        acc[rt][ct] = __builtin_amdgcn_mfma_f32_16x16x32_bf16(
            af[rt], __builtin_bit_cast(bf16x8v, wf[s][ct]), acc[rt][ct], 0, 0, 0);
  }

  // ---- EDGE residual: route reg-held h tile through LDS to C positions ----
  if constexpr (EPIM == EPI_ABR) {
    __syncthreads();  // all A reads done
    {
      const int i = t >> 2, q = t & 3;
      #pragma unroll
      for (int c = 0; c < 4; ++c)
        *(short8v*)(&amem[i * RS + q * 32 + 8 * c]) = hself[c];
    }
    __syncthreads();
  }

  // ---- epilogue: C/D layout col=lane&15, row=(lane>>4)*4+reg ----
  if constexpr (OUTBF) {
    if constexpr (EPIM != EPI_ABR) __syncthreads();  // reuse amem for C staging
    #pragma unroll
    for (int rt = 0; rt < 4; ++rt) {
      #pragma unroll
      for (int ct = 0; ct < 2; ++ct) {
        #pragma unroll
        for (int r = 0; r < 4; ++r) {
          int lrow = 16 * rt + 4 * g + r;
          int lcol = (2 * w + ct) * 16 + n0;
          float o = acc[rt][ct][r];
          if constexpr (EPIM == EPI_ABR) o += bf2f((u16)amem[lrow * RS + lcol]);
          o = fmaxf(o + bb[ct], 0.f);
          if constexpr (OUTBF == 2)  // dual f32 (pre-round, nontemporal)
            __builtin_nontemporal_store(o, &OutF32[(size_t)(base + lrow) * 128 + lcol]);
          amem[lrow * RS + lcol] = (short)f2bf(o);
        }
      }
    }
    __syncthreads();
    {
      const int i = t >> 2, q = t & 3;
      const int row = base + i;
      if (row < numRows) {
        u16* orow = (u16*)Out + (size_t)row * 128 + q * 32;
        #pragma unroll
        for (int c = 0; c < 4; ++c)
          *(short8v*)(orow + 8 * c) = *(const short8v*)(&amem[i * RS + q * 32 + 8 * c]);
      }
    }
  } else {
    #pragma unroll
    for (int rt = 0; rt < 4; ++rt) {
      #pragma unroll
      for (int ct = 0; ct < 2; ++ct) {
        #pragma unroll
        for (int r = 0; r < 4; ++r) {
          int row = base + 16 * rt + 4 * g + r;
          if (row < numRows) {
            int lrow = 16 * rt + 4 * g + r;
            int lcol = (2 * w + ct) * 16 + n0;
            float o = acc[rt][ct][r];
            if constexpr (EPIM == EPI_ABR) o += bf2f((u16)amem[lrow * RS + lcol]);
            o = fmaxf(o + bb[ct], 0.f);
            __builtin_nontemporal_store(o, &((float*)Out)[(size_t)row * 128 + lcol]);
          }
        }
      }
    }
  }
}

extern "C" void kernel_launch(void* const* d_in, const int* in_sizes, int n_in,
                              void* d_out, int out_size, void* d_ws, size_t ws_size,
                              hipStream_t stream) {
  const float* nf     = (const float*)d_in[0];
  const float* ef     = (const float*)d_in[1];
  const float* W_init = (const float*)d_in[2];
  const float* b_init = (const float*)d_in[3];
  const float* W_edge = (const float*)d_in[4];
  const float* b_edge = (const float*)d_in[5];
  const float* W_gin0 = (const float*)d_in[6];
  const float* W_gin  = (const float*)d_in[7];
  const float* b_gin  = (const float*)d_in[8];
  const float* eps    = (const float*)d_in[9];
  const int* esrc     = (const int*)d_in[10];
  const int* edst     = (const int*)d_in[11];
  // d_in[12] = edge_rev == e^1 by construction.

  float* xout  = (float*)d_out;                     // [N,128] f32
  float* h_out = xout + (size_t)N_NODES * 128;      // [E,128] f32 (final h)

  const size_t NB = (size_t)N_NODES * 128 * 2;      // bf16 node block (25.6MB)
  const size_t EB = (size_t)N_EDGES * 128 * 2;      // bf16 edge block (153.6MB)
  char* wsb = (char*)d_ws;
  u16* aggbf   = (u16*)wsb;                         // edge phase; later aliased by xbf1
  u16* xbf1    = (u16*)wsb;
  u16* hbf     = (u16*)(wsb + NB);
  u16* readout = (u16*)(wsb + NB + EB);
  u16* xbf0    = (u16*)(wsb + 2 * NB + EB);
  u16* nfbf    = (u16*)(wsb + 3 * NB + EB);
  int* csr_off = (int*)(wsb + 4 * NB + EB);         // N+1
  int* cursor  = csr_off + (N_NODES + 1);           // N (histogram, zeroed by scan1)
  int* csr_e   = cursor + N_NODES;                  // E
  int* csr_s   = csr_e + N_EDGES;                   // E
  int* blk     = csr_s + N_EDGES;                   // SCAN_NB

  // ---- nf -> bf16 ----
  convert_nf_kernel<<<(N_NODES * 128 / 8 + 255) / 256, 256, 0, stream>>>(nf, nfbf);

  // ---- CSR by dst (3-phase parallel scan) ----
  hipMemsetAsync(cursor, 0, N_NODES * sizeof(int), stream);
  hist_kernel<<<(N_EDGES + 255) / 256, 256, 0, stream>>>(edst, cursor);
  scan1_kernel<<<SCAN_NB, 256, 0, stream>>>(cursor, csr_off, blk);
  scan2_kernel<<<1, 512, 0, stream>>>(blk);
  scan3_kernel<<<SCAN_NB, 256, 0, stream>>>(csr_off, blk);
  fill_kernel<<<(N_EDGES + 255) / 256, 256, 0, stream>>>(edst, esrc, csr_off, cursor, csr_e, csr_s);

  const int ETILES = N_EDGES / 64;          // 9375
  const int NTILES = (N_NODES + 63) / 64;   // 1563

  // ---- init edge states: hbf = relu([nfbf[src]|ef] @ W_init + b) ----
  mfma_gemm<5, PREP_INIT, EPI_BR, 1><<<ETILES, 256, 0, stream>>>(
      W_init, 144, b_init, nfbf, ef, esrc, nullptr, nullptr, nullptr, nullptr, hbf, N_EDGES);

  // ---- EdgeConv steps 0..2 (in place on hbf) ----
  for (int t = 0; t < 3; ++t) {
    segsum_hbf_kernel<<<N_NODES / 4, 256, 0, stream>>>(hbf, csr_off, csr_e, aggbf);
    mfma_gemm<4, PREP_EDGE, EPI_ABR, 1><<<ETILES, 256, 0, stream>>>(
        W_edge + (size_t)t * 128 * 128, 128, b_edge + (size_t)t * 128,
        aggbf, hbf, esrc, nullptr, nullptr, nullptr, nullptr, hbf, N_EDGES);
  }
  // ---- EdgeConv step 3: dual-write bf16 hbf + f32 h_out (nontemporal) ----
  segsum_hbf_kernel<<<N_NODES / 4, 256, 0, stream>>>(hbf, csr_off, csr_e, aggbf);
  mfma_gemm<4, PREP_EDGE, EPI_ABR, 2><<<ETILES, 256, 0, stream>>>(
      W_edge + (size_t)3 * 128 * 128, 128, b_edge + (size_t)3 * 128,
      aggbf, hbf, esrc, nullptr, nullptr, nullptr, h_out, hbf, N_EDGES);

  // ---- readout from final hbf (nontemporal loads; hbf dead after) ----
  segsum_readout_kernel<<<N_NODES / 4, 256, 0, stream>>>(hbf, csr_off, csr_e, readout);

  // ---- GIN step 0: fused K=256 GEMM with inline gathers ----
  mfma_gemm<8, PREP_GIN0, EPI_BR, 1><<<NTILES, 256, 0, stream>>>(
      W_gin0, 256, b_gin, nfbf, readout, nullptr, csr_off, csr_s, eps, nullptr, xbf0, N_NODES);

  // ---- GIN steps 1..3 (xbf1 aliases dead aggbf) ----
  mfma_gemm<4, PREP_GINX, EPI_BR, 1><<<NTILES, 256, 0, stream>>>(
      W_gin, 128, b_gin + 128, xbf0, nullptr, nullptr, csr_off, csr_s, eps + 1, nullptr, xbf1, N_NODES);
  mfma_gemm<4, PREP_GINX, EPI_BR, 1><<<NTILES, 256, 0, stream>>>(
      W_gin + (size_t)128 * 128, 128, b_gin + 256, xbf1, nullptr, nullptr, csr_off, csr_s, eps + 2, nullptr, xbf0, N_NODES);
  mfma_gemm<4, PREP_GINX, EPI_BR, 0><<<NTILES, 256, 0, stream>>>(
      W_gin + (size_t)2 * 128 * 128, 128, b_gin + 384, xbf0, nullptr, nullptr, csr_off, csr_s, eps + 3, nullptr, xout, N_NODES);

  (void)in_sizes; (void)n_in; (void)out_size; (void)ws_size;
}

// Round 9
// 1111.374 us; speedup vs baseline: 3.0765x; 1.0600x over previous
//
#include <hip/hip_runtime.h>

#define N_NODES 100000
#define N_EDGES 600000
#define SCAN_NB ((N_NODES + 255) / 256)   // 391

// transposed bf16 weight blob offsets (u16 units)
#define WOFF_I  0                         // [128][160]  (K=144 padded to 160)
#define WOFF_E  20480                     // 4 x [128][128]
#define WOFF_G0 86016                     // [128][256]
#define WOFF_G  118784                    // 3 x [128][128]
#define WTOTAL  167936

typedef unsigned short u16;
typedef __attribute__((ext_vector_type(8))) short short8v;
typedef __attribute__((ext_vector_type(4))) short short4v;
typedef __attribute__((ext_vector_type(4))) float f32x4;
typedef __attribute__((ext_vector_type(8))) __bf16 bf16x8v;

__device__ __forceinline__ u16 f2bf(float f) {
  unsigned u = __builtin_bit_cast(unsigned, f);
  unsigned r = (u + 0x7fffu + ((u >> 16) & 1u)) >> 16;
  return (u16)r;
}
__device__ __forceinline__ float bf2f(u16 v) {
  unsigned u = ((unsigned)v) << 16;
  return __builtin_bit_cast(float, u);
}
__device__ __forceinline__ short8v shfl_xor4_v(short8v v) {
  int4 iv = __builtin_bit_cast(int4, v);
  iv.x = __shfl_xor(iv.x, 4, 64);
  iv.y = __shfl_xor(iv.y, 4, 64);
  iv.z = __shfl_xor(iv.z, 4, 64);
  iv.w = __shfl_xor(iv.w, 4, 64);
  return __builtin_bit_cast(short8v, iv);
}

// ---------------- nf -> bf16 (into nfro[N,256] low half) ----------------
__global__ __launch_bounds__(256) void convert_nf_kernel(const float* __restrict__ nf,
                                                         u16* __restrict__ nfro) {
  size_t idx = ((size_t)blockIdx.x * 256 + threadIdx.x) * 8;
  if (idx >= (size_t)N_NODES * 128) return;
  float4 a = *(const float4*)(nf + idx);
  float4 b = *(const float4*)(nf + idx + 4);
  short8v o = {(short)f2bf(a.x), (short)f2bf(a.y), (short)f2bf(a.z), (short)f2bf(a.w),
               (short)f2bf(b.x), (short)f2bf(b.y), (short)f2bf(b.z), (short)f2bf(b.w)};
  size_t row = idx >> 7, col = idx & 127;
  *(short8v*)(nfro + row * 256 + col) = o;
}

// ---------------- weights -> transposed bf16 blob ----------------
__global__ __launch_bounds__(256) void convert_w_kernel(const float* __restrict__ Wi,
                                                        const float* __restrict__ We,
                                                        const float* __restrict__ Wg0,
                                                        const float* __restrict__ Wg,
                                                        u16* __restrict__ out) {
  int e = blockIdx.x * 256 + threadIdx.x;
  if (e >= WTOTAL) return;
  float v;
  if (e < WOFF_E) {                       // init: [128][160], K=144
    int col = e / 160, k = e % 160;
    v = (k < 144) ? Wi[(size_t)k * 128 + col] : 0.f;
  } else if (e < WOFF_G0) {               // edge: 4 x [128][128]
    int r = e - WOFF_E;
    int m = r / 16384; r %= 16384;
    int col = r / 128, k = r % 128;
    v = We[(size_t)m * 16384 + (size_t)k * 128 + col];
  } else if (e < WOFF_G) {                // gin0: [128][256]
    int r = e - WOFF_G0;
    int col = r / 256, k = r % 256;
    v = Wg0[(size_t)k * 128 + col];
  } else {                                // gin: 3 x [128][128]
    int r = e - WOFF_G;
    int m = r / 16384; r %= 16384;
    int col = r / 128, k = r % 128;
    v = Wg[(size_t)m * 16384 + (size_t)k * 128 + col];
  }
  out[e] = f2bf(v);
}

// ---------------- CSR build ----------------
__global__ void hist_kernel(const int* __restrict__ dst, int* __restrict__ cnt) {
  int e = blockIdx.x * 256 + threadIdx.x;
  if (e < N_EDGES) atomicAdd(&cnt[dst[e]], 1);
}

__global__ __launch_bounds__(256) void scan1_kernel(int* __restrict__ cnt,
                                                    int* __restrict__ off,
                                                    int* __restrict__ blk) {
  __shared__ int s[256];
  int i = blockIdx.x * 256 + threadIdx.x;
  int v = (i < N_NODES) ? cnt[i] : 0;
  if (i < N_NODES) cnt[i] = 0;
  s[threadIdx.x] = v;
  __syncthreads();
  for (int d = 1; d < 256; d <<= 1) {
    int t = (threadIdx.x >= d) ? s[threadIdx.x - d] : 0;
    __syncthreads();
    s[threadIdx.x] += t;
    __syncthreads();
  }
  if (i < N_NODES) off[i] = s[threadIdx.x] - v;
  if (threadIdx.x == 255) blk[blockIdx.x] = s[255];
}

__global__ __launch_bounds__(512) void scan2_kernel(int* __restrict__ blk) {
  __shared__ int s[512];
  int v = (threadIdx.x < SCAN_NB) ? blk[threadIdx.x] : 0;
  s[threadIdx.x] = v;
  __syncthreads();
  for (int d = 1; d < 512; d <<= 1) {
    int t = (threadIdx.x >= d) ? s[threadIdx.x - d] : 0;
    __syncthreads();
    s[threadIdx.x] += t;
    __syncthreads();
  }
  if (threadIdx.x < SCAN_NB) blk[threadIdx.x] = s[threadIdx.x] - v;
}

__global__ __launch_bounds__(256) void scan3_kernel(int* __restrict__ off,
                                                    const int* __restrict__ blk) {
  int i = blockIdx.x * 256 + threadIdx.x;
  if (i < N_NODES) off[i] += blk[blockIdx.x];
  if (i == 0) off[N_NODES] = N_EDGES;
}

__global__ void fill_kernel(const int* __restrict__ dst, const int* __restrict__ src,
                            const int* __restrict__ off, int* __restrict__ cur,
                            int* __restrict__ csr_e, int* __restrict__ csr_s) {
  int e = blockIdx.x * 256 + threadIdx.x;
  if (e < N_EDGES) {
    int d = dst[e];
    int p = off[d] + atomicAdd(&cur[d], 1);
    csr_e[p] = e;
    csr_s[p] = src[e];
  }
}

// ---------------- segment sum over bf16 h (one wave per node, shfl-bcast edges) ----
__global__ __launch_bounds__(256) void segsum_hbf_kernel(const u16* __restrict__ hbf,
                                                         const int* __restrict__ off,
                                                         const int* __restrict__ csr_e,
                                                         u16* __restrict__ aggb) {
  int node = blockIdx.x * 4 + (threadIdx.x >> 6);
  int l = threadIdx.x & 63;
  int p0 = off[node], p1 = off[node + 1];
  int deg = p1 - p0;
  int e_l = (l < deg) ? csr_e[p0 + min(l, deg - 1)] : 0;
  float a0 = 0.f, a1 = 0.f;
  int jmax = min(deg, 64);
  for (int j = 0; j < jmax; ++j) {
    int e = __shfl(e_l, j, 64);
    unsigned u = *(const unsigned*)(hbf + (size_t)e * 128 + 2 * l);
    a0 += __builtin_bit_cast(float, u << 16);
    a1 += __builtin_bit_cast(float, u & 0xffff0000u);
  }
  for (int p = p0 + 64; p < p1; ++p) {
    int e = csr_e[p];
    unsigned u = *(const unsigned*)(hbf + (size_t)e * 128 + 2 * l);
    a0 += __builtin_bit_cast(float, u << 16);
    a1 += __builtin_bit_cast(float, u & 0xffff0000u);
  }
  unsigned o = (unsigned)f2bf(a0) | (((unsigned)f2bf(a1)) << 16);
  *(unsigned*)(aggb + (size_t)node * 128 + 2 * l) = o;
}

// ---- readout segsum over final hbf -> nfro[:,128:256] (NT loads, hbf dead after) ----
__global__ __launch_bounds__(256) void segsum_readout_kernel(const u16* __restrict__ hbf,
                                                             const int* __restrict__ off,
                                                             const int* __restrict__ csr_e,
                                                             u16* __restrict__ ro) {
  int node = blockIdx.x * 4 + (threadIdx.x >> 6);
  int l = threadIdx.x & 63;
  int p0 = off[node], p1 = off[node + 1];
  int deg = p1 - p0;
  int e_l = (l < deg) ? csr_e[p0 + min(l, deg - 1)] : 0;
  float a0 = 0.f, a1 = 0.f;
  int jmax = min(deg, 64);
  for (int j = 0; j < jmax; ++j) {
    int e = __shfl(e_l, j, 64);
    unsigned u = __builtin_nontemporal_load((const unsigned*)(hbf + (size_t)e * 128 + 2 * l));
    a0 += __builtin_bit_cast(float, u << 16);
    a1 += __builtin_bit_cast(float, u & 0xffff0000u);
  }
  for (int p = p0 + 64; p < p1; ++p) {
    int e = csr_e[p];
    unsigned u = __builtin_nontemporal_load((const unsigned*)(hbf + (size_t)e * 128 + 2 * l));
    a0 += __builtin_bit_cast(float, u << 16);
    a1 += __builtin_bit_cast(float, u & 0xffff0000u);
  }
  unsigned o = (unsigned)f2bf(a0) | (((unsigned)f2bf(a1)) << 16);
  *(unsigned*)(ro + (size_t)node * 256 + 2 * l) = o;   // high half of nfro row
}

// ---------------- unified MFMA GEMM ----------------
// Tile 64 rows x 128 cols, 256 threads (4 waves); wave w -> cols [32w,32w+32).
// Wt: TRANSPOSED bf16 weights [128 cols][KSTEPS*32] -> one short8v per fragment.
// TPB tiles per block, W fragments reused across tiles.
// EDGE: h tile read ONCE (regs); rev via shfl_xor(4); residual routed via LDS.
// GIN: CSR neighbor gather fused into prep (nfro concat layout for GIN0).
#define PREP_INIT 0
#define PREP_EDGE 1
#define PREP_GIN0 2
#define PREP_GINX 3
#define EPI_BR  1
#define EPI_ABR 2

template<int KSTEPS, int PREPM, int EPIM, int OUTBF, int TPB>
__global__ __launch_bounds__(256, 3) void mfma_gemm(
    const u16* __restrict__ Wt,
    const float* __restrict__ bias,
    const void* __restrict__ P0,      // INIT/GIN0: nfro u16; EDGE: aggb u16; GINX: x u16
    const void* __restrict__ P1,      // INIT: ef f32; EDGE: hbf u16
    const int* __restrict__ srcIdx,   // INIT/EDGE: edge_src
    const int* __restrict__ csr_off,  // GIN: gather offsets
    const int* __restrict__ csr_s,    // GIN: gather sources
    const float* __restrict__ epsp,   // GIN: eps scalar
    float* __restrict__ OutF32,       // OUTBF==2: f32 dual output (h_out)
    void* __restrict__ Out, int numRows) {
  constexpr int RS = KSTEPS * 32 + 8;
  constexpr bool WLATE = (KSTEPS >= 8);
  __shared__ short amem[64 * RS];
  const int t = threadIdx.x;
  const int l = t & 63;
  const int w = t >> 6;
  const int g = l >> 4;
  const int n0 = l & 15;

  short8v wf[KSTEPS][2];
  auto load_w = [&]() {
    #pragma unroll
    for (int s = 0; s < KSTEPS; ++s)
      #pragma unroll
      for (int ct = 0; ct < 2; ++ct)
        wf[s][ct] = *(const short8v*)(Wt + (size_t)((2 * w + ct) * 16 + n0) * (KSTEPS * 32) + 32 * s + 8 * g);
  };
  if constexpr (!WLATE) load_w();

  float bb[2];
  #pragma unroll
  for (int ct = 0; ct < 2; ++ct) bb[ct] = bias[(2 * w + ct) * 16 + n0];
  float alpha = 0.f;
  if constexpr (PREPM == PREP_GIN0 || PREPM == PREP_GINX) alpha = 1.f + epsp[0];

  for (int it = 0; it < TPB; ++it) {
    const int base = (blockIdx.x * TPB + it) * 64;
    short8v hself[4];

    // ---- prep: stage A tile (bf16) ----
    if constexpr (PREPM == PREP_INIT) {
      const int i = t >> 2, q = t & 3;
      const int row = base + i;
      const int sn = srcIdx[row];
      const u16* nrow = (const u16*)P0 + (size_t)sn * 256 + q * 32;
      #pragma unroll
      for (int c = 0; c < 4; ++c)
        *(short8v*)(&amem[i * RS + q * 32 + 8 * c]) = *(const short8v*)(nrow + 8 * c);
      #pragma unroll
      for (int z = 0; z < 2; ++z) {
        int col = 128 + (2 * q + z) * 4;
        short4v o = {0, 0, 0, 0};
        if (col < 144) {
          f32x4 vv = __builtin_nontemporal_load(
              (const f32x4*)((const float*)P1 + (size_t)row * 16 + (col - 128)));
          o = {(short)f2bf(vv.x), (short)f2bf(vv.y), (short)f2bf(vv.z), (short)f2bf(vv.w)};
        }
        *(short4v*)(&amem[i * RS + col]) = o;
      }
    } else if constexpr (PREPM == PREP_EDGE) {
      const int i = t >> 2, q = t & 3;
      const int row = base + i;
      const int sn = srcIdx[row];
      const u16* arow = (const u16*)P0 + (size_t)sn * 128 + q * 32;
      const u16* hrow = (const u16*)P1 + (size_t)row * 128 + q * 32;
      short8v av[4];
      #pragma unroll
      for (int c = 0; c < 4; ++c) av[c] = *(const short8v*)(arow + 8 * c);
      #pragma unroll
      for (int c = 0; c < 4; ++c) hself[c] = *(const short8v*)(hrow + 8 * c);
      #pragma unroll
      for (int c = 0; c < 4; ++c) {
        short8v hrev = shfl_xor4_v(hself[c]);
        short8v o;
        #pragma unroll
        for (int j = 0; j < 8; ++j)
          o[j] = (short)f2bf(bf2f((u16)av[c][j]) - bf2f((u16)hrev[j]));
        *(short8v*)(&amem[i * RS + q * 32 + 8 * c]) = o;
      }
    } else if constexpr (PREPM == PREP_GIN0) {
      const int i2 = t >> 3, q = t & 7;
      #pragma unroll
      for (int half = 0; half < 2; ++half) {
        const int r = i2 + 32 * half;
        const int row = base + r;
        const int n = (row < numRows) ? row : (numRows - 1);
        const int p0 = csr_off[n], p1 = csr_off[n + 1];
        float acc[32];
        const u16* self = (const u16*)P0 + (size_t)n * 256 + 32 * q;
        #pragma unroll
        for (int c8 = 0; c8 < 4; ++c8) {
          short8v v = *(const short8v*)(self + 8 * c8);
          #pragma unroll
          for (int j = 0; j < 8; ++j) acc[8 * c8 + j] = alpha * bf2f((u16)v[j]);
        }
        for (int p = p0; p < p1; ++p) {
          const u16* nb = (const u16*)P0 + (size_t)csr_s[p] * 256 + 32 * q;
          #pragma unroll
          for (int c8 = 0; c8 < 4; ++c8) {
            short8v v = *(const short8v*)(nb + 8 * c8);
            #pragma unroll
            for (int j = 0; j < 8; ++j) acc[8 * c8 + j] += bf2f((u16)v[j]);
          }
        }
        #pragma unroll
        for (int c4 = 0; c4 < 8; ++c4) {
          short4v o = {(short)f2bf(acc[4 * c4 + 0]), (short)f2bf(acc[4 * c4 + 1]),
                       (short)f2bf(acc[4 * c4 + 2]), (short)f2bf(acc[4 * c4 + 3])};
          *(short4v*)(&amem[r * RS + 32 * q + 4 * c4]) = o;
        }
      }
    } else {  // PREP_GINX
      const int i = t >> 2, q = t & 3;
      const int row = base + i;
      const int n = (row < numRows) ? row : (numRows - 1);
      const int p0 = csr_off[n], p1 = csr_off[n + 1];
      float acc[32];
      const u16* self = (const u16*)P0 + (size_t)n * 128 + 32 * q;
      #pragma unroll
      for (int c8 = 0; c8 < 4; ++c8) {
        short8v v = *(const short8v*)(self + 8 * c8);
        #pragma unroll
        for (int j = 0; j < 8; ++j) acc[8 * c8 + j] = alpha * bf2f((u16)v[j]);
      }
      for (int p = p0; p < p1; ++p) {
        const u16* nb = (const u16*)P0 + (size_t)csr_s[p] * 128 + 32 * q;
        #pragma unroll
        for (int c8 = 0; c8 < 4; ++c8) {
          short8v v = *(const short8v*)(nb + 8 * c8);
          #pragma unroll
          for (int j = 0; j < 8; ++j) acc[8 * c8 + j] += bf2f((u16)v[j]);
        }
      }
      #pragma unroll
      for (int c4 = 0; c4 < 8; ++c4) {
        short4v o = {(short)f2bf(acc[4 * c4 + 0]), (short)f2bf(acc[4 * c4 + 1]),
                     (short)f2bf(acc[4 * c4 + 2]), (short)f2bf(acc[4 * c4 + 3])};
        *(short4v*)(&amem[i * RS + 32 * q + 4 * c4]) = o;
      }
    }
    __syncthreads();
    if constexpr (WLATE) load_w();

    // ---- MFMA main loop ----
    f32x4 acc[4][2];
    #pragma unroll
    for (int rt = 0; rt < 4; ++rt)
      #pragma unroll
      for (int ct = 0; ct < 2; ++ct) acc[rt][ct] = (f32x4){0.f, 0.f, 0.f, 0.f};
    #pragma unroll
    for (int s = 0; s < KSTEPS; ++s) {
      bf16x8v af[4];
      #pragma unroll
      for (int rt = 0; rt < 4; ++rt) {
        short8v araw = *(const short8v*)(&amem[(16 * rt + n0) * RS + s * 32 + g * 8]);
        af[rt] = __builtin_bit_cast(bf16x8v, araw);
      }
      #pragma unroll
      for (int rt = 0; rt < 4; ++rt)
        #pragma unroll
        for (int ct = 0; ct < 2; ++ct)
          acc[rt][ct] = __builtin_amdgcn_mfma_f32_16x16x32_bf16(
              af[rt], __builtin_bit_cast(bf16x8v, wf[s][ct]), acc[rt][ct], 0, 0, 0);
    }

    // ---- EDGE residual: route reg-held h tile through LDS to C positions ----
    if constexpr (EPIM == EPI_ABR) {
      __syncthreads();
      {
        const int i = t >> 2, q = t & 3;
        #pragma unroll
        for (int c = 0; c < 4; ++c)
          *(short8v*)(&amem[i * RS + q * 32 + 8 * c]) = hself[c];
      }
      __syncthreads();
    }

    // ---- epilogue: C/D layout col=lane&15, row=(lane>>4)*4+reg ----
    if constexpr (OUTBF) {
      if constexpr (EPIM != EPI_ABR) __syncthreads();
      #pragma unroll
      for (int rt = 0; rt < 4; ++rt) {
        #pragma unroll
        for (int ct = 0; ct < 2; ++ct) {
          #pragma unroll
          for (int r = 0; r < 4; ++r) {
            int lrow = 16 * rt + 4 * g + r;
            int lcol = (2 * w + ct) * 16 + n0;
            float o = acc[rt][ct][r];
            if constexpr (EPIM == EPI_ABR) o += bf2f((u16)amem[lrow * RS + lcol]);
            o = fmaxf(o + bb[ct], 0.f);
            if constexpr (OUTBF == 2)
              __builtin_nontemporal_store(o, &OutF32[(size_t)(base + lrow) * 128 + lcol]);
            amem[lrow * RS + lcol] = (short)f2bf(o);
          }
        }
      }
      __syncthreads();
      {
        const int i = t >> 2, q = t & 3;
        const int row = base + i;
        if (row < numRows) {
          u16* orow = (u16*)Out + (size_t)row * 128 + q * 32;
          #pragma unroll
          for (int c = 0; c < 4; ++c)
            *(short8v*)(orow + 8 * c) = *(const short8v*)(&amem[i * RS + q * 32 + 8 * c]);
        }
      }
    } else {
      #pragma unroll
      for (int rt = 0; rt < 4; ++rt) {
        #pragma unroll
        for (int ct = 0; ct < 2; ++ct) {
          #pragma unroll
          for (int r = 0; r < 4; ++r) {
            int row = base + 16 * rt + 4 * g + r;
            if (row < numRows) {
              int lcol = (2 * w + ct) * 16 + n0;
              float o = acc[rt][ct][r];
              o = fmaxf(o + bb[ct], 0.f);
              __builtin_nontemporal_store(o, &((float*)Out)[(size_t)row * 128 + lcol]);
            }
          }
        }
      }
    }
    __syncthreads();  // amem reuse across tile iterations
  }
}

extern "C" void kernel_launch(void* const* d_in, const int* in_sizes, int n_in,
                              void* d_out, int out_size, void* d_ws, size_t ws_size,
                              hipStream_t stream) {
  const float* nf     = (const float*)d_in[0];
  const float* ef     = (const float*)d_in[1];
  const float* W_init = (const float*)d_in[2];
  const float* b_init = (const float*)d_in[3];
  const float* W_edge = (const float*)d_in[4];
  const float* b_edge = (const float*)d_in[5];
  const float* W_gin0 = (const float*)d_in[6];
  const float* W_gin  = (const float*)d_in[7];
  const float* b_gin  = (const float*)d_in[8];
  const float* eps    = (const float*)d_in[9];
  const int* esrc     = (const int*)d_in[10];
  const int* edst     = (const int*)d_in[11];
  // d_in[12] = edge_rev == e^1 by construction.

  float* xout  = (float*)d_out;                     // [N,128] f32
  float* h_out = xout + (size_t)N_NODES * 128;      // [E,128] f32 (final h)

  const size_t NB = (size_t)N_NODES * 128 * 2;      // bf16 node block (25.6MB)
  const size_t EB = (size_t)N_EDGES * 128 * 2;      // bf16 edge block (153.6MB)
  char* wsb = (char*)d_ws;
  u16* aggbf   = (u16*)wsb;                         // edge phase; later aliased by xbf1
  u16* xbf1    = (u16*)wsb;
  u16* hbf     = (u16*)(wsb + NB);
  u16* nfro    = (u16*)(wsb + NB + EB);             // [N,256] concat (nf | readout)
  u16* xbf0    = (u16*)(wsb + 3 * NB + EB);
  int* csr_off = (int*)(wsb + 4 * NB + EB);         // N+1
  int* cursor  = csr_off + (N_NODES + 1);           // N (histogram, zeroed by scan1)
  int* csr_e   = cursor + N_NODES;                  // E
  int* csr_s   = csr_e + N_EDGES;                   // E
  int* blk     = csr_s + N_EDGES;                   // SCAN_NB
  u16* wblob   = (u16*)(blk + SCAN_NB + 1);         // transposed bf16 weights

  // ---- conversions ----
  convert_nf_kernel<<<(N_NODES * 128 / 8 + 255) / 256, 256, 0, stream>>>(nf, nfro);
  convert_w_kernel<<<(WTOTAL + 255) / 256, 256, 0, stream>>>(W_init, W_edge, W_gin0, W_gin, wblob);

  // ---- CSR by dst (3-phase parallel scan) ----
  hipMemsetAsync(cursor, 0, N_NODES * sizeof(int), stream);
  hist_kernel<<<(N_EDGES + 255) / 256, 256, 0, stream>>>(edst, cursor);
  scan1_kernel<<<SCAN_NB, 256, 0, stream>>>(cursor, csr_off, blk);
  scan2_kernel<<<1, 512, 0, stream>>>(blk);
  scan3_kernel<<<SCAN_NB, 256, 0, stream>>>(csr_off, blk);
  fill_kernel<<<(N_EDGES + 255) / 256, 256, 0, stream>>>(edst, esrc, csr_off, cursor, csr_e, csr_s);

  const u16* wt_init = wblob + WOFF_I;
  const u16* wt_edge = wblob + WOFF_E;
  const u16* wt_gin0 = wblob + WOFF_G0;
  const u16* wt_gin  = wblob + WOFF_G;

  // ---- init edge states: hbf = relu([nf[src]|ef] @ W_init + b) ----
  mfma_gemm<5, PREP_INIT, EPI_BR, 1, 5><<<1875, 256, 0, stream>>>(
      wt_init, b_init, nfro, ef, esrc, nullptr, nullptr, nullptr, nullptr, hbf, N_EDGES);

  // ---- EdgeConv steps 0..2 (in place on hbf) ----
  for (int t = 0; t < 3; ++t) {
    segsum_hbf_kernel<<<N_NODES / 4, 256, 0, stream>>>(hbf, csr_off, csr_e, aggbf);
    mfma_gemm<4, PREP_EDGE, EPI_ABR, 1, 5><<<1875, 256, 0, stream>>>(
        wt_edge + (size_t)t * 16384, b_edge + (size_t)t * 128,
        aggbf, hbf, esrc, nullptr, nullptr, nullptr, nullptr, hbf, N_EDGES);
  }
  // ---- EdgeConv step 3: dual-write bf16 hbf + f32 h_out (nontemporal) ----
  segsum_hbf_kernel<<<N_NODES / 4, 256, 0, stream>>>(hbf, csr_off, csr_e, aggbf);
  mfma_gemm<4, PREP_EDGE, EPI_ABR, 2, 5><<<1875, 256, 0, stream>>>(
      wt_edge + (size_t)3 * 16384, b_edge + (size_t)3 * 128,
      aggbf, hbf, esrc, nullptr, nullptr, nullptr, h_out, hbf, N_EDGES);

  // ---- readout from final hbf into nfro high half ----
  segsum_readout_kernel<<<N_NODES / 4, 256, 0, stream>>>(hbf, csr_off, csr_e, nfro + 128);

  // ---- GIN step 0: fused K=256 GEMM with inline gathers over nfro ----
  mfma_gemm<8, PREP_GIN0, EPI_BR, 1, 3><<<521, 256, 0, stream>>>(
      wt_gin0, b_gin, nfro, nullptr, nullptr, csr_off, csr_s, eps, nullptr, xbf0, N_NODES);

  // ---- GIN steps 1..3 (xbf1 aliases dead aggbf) ----
  mfma_gemm<4, PREP_GINX, EPI_BR, 1, 3><<<521, 256, 0, stream>>>(
      wt_gin, b_gin + 128, xbf0, nullptr, nullptr, csr_off, csr_s, eps + 1, nullptr, xbf1, N_NODES);
  mfma_gemm<4, PREP_GINX, EPI_BR, 1, 3><<<521, 256, 0, stream>>>(
      wt_gin + 16384, b_gin + 256, xbf1, nullptr, nullptr, csr_off, csr_s, eps + 2, nullptr, xbf0, N_NODES);
  mfma_gemm<4, PREP_GINX, EPI_BR, 0, 3><<<521, 256, 0, stream>>>(
      wt_gin + 2 * 16384, b_gin + 384, xbf0, nullptr, nullptr, csr_off, csr_s, eps + 3, nullptr, xout, N_NODES);

  (void)in_sizes; (void)n_in; (void)out_size; (void)ws_size;
}

// Round 10
// 1030.693 us; speedup vs baseline: 3.3173x; 1.0783x over previous
//
#include <hip/hip_runtime.h>

#define N_NODES 100000
#define N_EDGES 600000
#define SCAN_NB ((N_NODES + 255) / 256)   // 391

// transposed bf16 weight blob offsets (u16 units)
#define WOFF_I  0                         // [128][160]  (K=144 padded to 160)
#define WOFF_E  20480                     // 4 x [128][128]
#define WOFF_G0 86016                     // [128][256]
#define WOFF_G  118784                    // 3 x [128][128]
#define WTOTAL  167936
#define NFCONV_THREADS (N_NODES * 128 / 8)   // 1.6M

typedef unsigned short u16;
typedef __attribute__((ext_vector_type(8))) short short8v;
typedef __attribute__((ext_vector_type(4))) short short4v;
typedef __attribute__((ext_vector_type(4))) float f32x4;
typedef __attribute__((ext_vector_type(2))) unsigned u32x2;
typedef __attribute__((ext_vector_type(8))) __bf16 bf16x8v;

__device__ __forceinline__ u16 f2bf(float f) {
  unsigned u = __builtin_bit_cast(unsigned, f);
  unsigned r = (u + 0x7fffu + ((u >> 16) & 1u)) >> 16;
  return (u16)r;
}
__device__ __forceinline__ float bf2f(u16 v) {
  unsigned u = ((unsigned)v) << 16;
  return __builtin_bit_cast(float, u);
}
__device__ __forceinline__ float bflo(unsigned u) {
  return __builtin_bit_cast(float, u << 16);
}
__device__ __forceinline__ float bfhi(unsigned u) {
  return __builtin_bit_cast(float, u & 0xffff0000u);
}
__device__ __forceinline__ short8v shfl_xor4_v(short8v v) {
  int4 iv = __builtin_bit_cast(int4, v);
  iv.x = __shfl_xor(iv.x, 4, 64);
  iv.y = __shfl_xor(iv.y, 4, 64);
  iv.z = __shfl_xor(iv.z, 4, 64);
  iv.w = __shfl_xor(iv.w, 4, 64);
  return __builtin_bit_cast(short8v, iv);
}

// ---------------- fused conversions: nf -> nfro low half; weights -> blob ----------------
__global__ __launch_bounds__(256) void convert_all_kernel(const float* __restrict__ nf,
                                                          u16* __restrict__ nfro,
                                                          const float* __restrict__ Wi,
                                                          const float* __restrict__ We,
                                                          const float* __restrict__ Wg0,
                                                          const float* __restrict__ Wg,
                                                          u16* __restrict__ wout) {
  int tid = blockIdx.x * 256 + threadIdx.x;
  if (tid < NFCONV_THREADS) {
    size_t idx = (size_t)tid * 8;
    float4 a = *(const float4*)(nf + idx);
    float4 b = *(const float4*)(nf + idx + 4);
    short8v o = {(short)f2bf(a.x), (short)f2bf(a.y), (short)f2bf(a.z), (short)f2bf(a.w),
                 (short)f2bf(b.x), (short)f2bf(b.y), (short)f2bf(b.z), (short)f2bf(b.w)};
    size_t row = idx >> 7, col = idx & 127;
    *(short8v*)(nfro + row * 256 + col) = o;
    return;
  }
  int e = tid - NFCONV_THREADS;
  if (e >= WTOTAL) return;
  float v;
  if (e < WOFF_E) {                       // init: [128][160], K=144
    int col = e / 160, k = e % 160;
    v = (k < 144) ? Wi[(size_t)k * 128 + col] : 0.f;
  } else if (e < WOFF_G0) {               // edge: 4 x [128][128]
    int r = e - WOFF_E;
    int m = r / 16384; r %= 16384;
    int col = r / 128, k = r % 128;
    v = We[(size_t)m * 16384 + (size_t)k * 128 + col];
  } else if (e < WOFF_G) {                // gin0: [128][256]
    int r = e - WOFF_G0;
    int col = r / 256, k = r % 256;
    v = Wg0[(size_t)k * 128 + col];
  } else {                                // gin: 3 x [128][128]
    int r = e - WOFF_G;
    int m = r / 16384; r %= 16384;
    int col = r / 128, k = r % 128;
    v = Wg[(size_t)m * 16384 + (size_t)k * 128 + col];
  }
  wout[e] = f2bf(v);
}

// ---------------- CSR build ----------------
__global__ void hist_kernel(const int* __restrict__ dst, int* __restrict__ cnt) {
  int e = blockIdx.x * 256 + threadIdx.x;
  if (e < N_EDGES) atomicAdd(&cnt[dst[e]], 1);
}

__global__ __launch_bounds__(256) void scan1_kernel(int* __restrict__ cnt,
                                                    int* __restrict__ off,
                                                    int* __restrict__ blk) {
  __shared__ int s[256];
  int i = blockIdx.x * 256 + threadIdx.x;
  int v = (i < N_NODES) ? cnt[i] : 0;
  if (i < N_NODES) cnt[i] = 0;
  s[threadIdx.x] = v;
  __syncthreads();
  for (int d = 1; d < 256; d <<= 1) {
    int t = (threadIdx.x >= d) ? s[threadIdx.x - d] : 0;
    __syncthreads();
    s[threadIdx.x] += t;
    __syncthreads();
  }
  if (i < N_NODES) off[i] = s[threadIdx.x] - v;
  if (threadIdx.x == 255) blk[blockIdx.x] = s[255];
}

__global__ __launch_bounds__(512) void scan2_kernel(int* __restrict__ blk) {
  __shared__ int s[512];
  int v = (threadIdx.x < SCAN_NB) ? blk[threadIdx.x] : 0;
  s[threadIdx.x] = v;
  __syncthreads();
  for (int d = 1; d < 512; d <<= 1) {
    int t = (threadIdx.x >= d) ? s[threadIdx.x - d] : 0;
    __syncthreads();
    s[threadIdx.x] += t;
    __syncthreads();
  }
  if (threadIdx.x < SCAN_NB) blk[threadIdx.x] = s[threadIdx.x] - v;
}

__global__ __launch_bounds__(256) void scan3_kernel(int* __restrict__ off,
                                                    const int* __restrict__ blk) {
  int i = blockIdx.x * 256 + threadIdx.x;
  if (i < N_NODES) off[i] += blk[blockIdx.x];
  if (i == 0) off[N_NODES] = N_EDGES;
}

__global__ void fill_kernel(const int* __restrict__ dst, const int* __restrict__ src,
                            const int* __restrict__ off, int* __restrict__ cur,
                            int* __restrict__ csr_e, int* __restrict__ csr_s) {
  int e = blockIdx.x * 256 + threadIdx.x;
  if (e < N_EDGES) {
    int d = dst[e];
    int p = off[d] + atomicAdd(&cur[d], 1);
    csr_e[p] = e;
    csr_s[p] = src[e];
  }
}

// ---- segment sum over bf16 h: 2 nodes/wave (32-lane groups, 8B/lane) ----
__global__ __launch_bounds__(256) void segsum_hbf_kernel(const u16* __restrict__ hbf,
                                                         const int* __restrict__ off,
                                                         const int* __restrict__ csr_e,
                                                         u16* __restrict__ aggb) {
  int node = blockIdx.x * 8 + (threadIdx.x >> 5);
  int hl = threadIdx.x & 31;
  int p0 = off[node], p1 = off[node + 1];
  int deg = p1 - p0;
  int e_l = (hl < deg) ? csr_e[p0 + hl] : 0;
  float a0 = 0.f, a1 = 0.f, a2 = 0.f, a3 = 0.f;
  int jmax = min(deg, 32);
  for (int j = 0; j < jmax; ++j) {
    int e = __shfl(e_l, j, 32);
    u32x2 u = *(const u32x2*)(hbf + (size_t)e * 128 + 4 * hl);
    a0 += bflo(u.x); a1 += bfhi(u.x); a2 += bflo(u.y); a3 += bfhi(u.y);
  }
  for (int p = p0 + 32; p < p1; ++p) {
    int e = csr_e[p];
    u32x2 u = *(const u32x2*)(hbf + (size_t)e * 128 + 4 * hl);
    a0 += bflo(u.x); a1 += bfhi(u.x); a2 += bflo(u.y); a3 += bfhi(u.y);
  }
  u32x2 o = {(unsigned)f2bf(a0) | (((unsigned)f2bf(a1)) << 16),
             (unsigned)f2bf(a2) | (((unsigned)f2bf(a3)) << 16)};
  *(u32x2*)(aggb + (size_t)node * 128 + 4 * hl) = o;
}

// ---- readout segsum over final hbf -> nfro[:,128:256] (NT loads; hbf dead after) ----
__global__ __launch_bounds__(256) void segsum_readout_kernel(const u16* __restrict__ hbf,
                                                             const int* __restrict__ off,
                                                             const int* __restrict__ csr_e,
                                                             u16* __restrict__ ro) {
  int node = blockIdx.x * 8 + (threadIdx.x >> 5);
  int hl = threadIdx.x & 31;
  int p0 = off[node], p1 = off[node + 1];
  int deg = p1 - p0;
  int e_l = (hl < deg) ? csr_e[p0 + hl] : 0;
  float a0 = 0.f, a1 = 0.f, a2 = 0.f, a3 = 0.f;
  int jmax = min(deg, 32);
  for (int j = 0; j < jmax; ++j) {
    int e = __shfl(e_l, j, 32);
    u32x2 u = __builtin_nontemporal_load((const u32x2*)(hbf + (size_t)e * 128 + 4 * hl));
    a0 += bflo(u.x); a1 += bfhi(u.x); a2 += bflo(u.y); a3 += bfhi(u.y);
  }
  for (int p = p0 + 32; p < p1; ++p) {
    int e = csr_e[p];
    u32x2 u = __builtin_nontemporal_load((const u32x2*)(hbf + (size_t)e * 128 + 4 * hl));
    a0 += bflo(u.x); a1 += bfhi(u.x); a2 += bflo(u.y); a3 += bfhi(u.y);
  }
  u32x2 o = {(unsigned)f2bf(a0) | (((unsigned)f2bf(a1)) << 16),
             (unsigned)f2bf(a2) | (((unsigned)f2bf(a3)) << 16)};
  *(u32x2*)(ro + (size_t)node * 256 + 4 * hl) = o;
}

// ---------------- unified MFMA GEMM ----------------
// Tile 64 rows x 128 cols, 256 threads (4 waves); wave w -> cols [32w,32w+32).
// Wt: TRANSPOSED bf16 weights [128 cols][KSTEPS*32] -> one short8v per fragment.
// TPB tiles per block, W fragments reused across tiles.
// EDGE: h tile read ONCE (regs); rev via shfl_xor(4); residual routed via LDS.
// GIN: CSR neighbor gather fused into prep (nfro concat layout for GIN0).
#define PREP_INIT 0
#define PREP_EDGE 1
#define PREP_GIN0 2
#define PREP_GINX 3
#define EPI_BR  1
#define EPI_ABR 2

template<int KSTEPS, int PREPM, int EPIM, int OUTBF, int TPB>
__global__ __launch_bounds__(256, (KSTEPS <= 5) ? 4 : 3) void mfma_gemm(
    const u16* __restrict__ Wt,
    const float* __restrict__ bias,
    const void* __restrict__ P0,      // INIT/GIN0: nfro u16; EDGE: aggb u16; GINX: x u16
    const void* __restrict__ P1,      // INIT: ef f32; EDGE: hbf u16
    const int* __restrict__ srcIdx,   // INIT/EDGE: edge_src
    const int* __restrict__ csr_off,  // GIN: gather offsets
    const int* __restrict__ csr_s,    // GIN: gather sources
    const float* __restrict__ epsp,   // GIN: eps scalar
    float* __restrict__ OutF32,       // OUTBF==2: f32 dual output (h_out)
    void* __restrict__ Out, int numRows) {
  constexpr int RS = KSTEPS * 32 + 8;
  constexpr bool WLATE = (KSTEPS >= 8);
  __shared__ short amem[64 * RS];
  const int t = threadIdx.x;
  const int l = t & 63;
  const int w = t >> 6;
  const int g = l >> 4;
  const int n0 = l & 15;

  short8v wf[KSTEPS][2];
  auto load_w = [&]() {
    #pragma unroll
    for (int s = 0; s < KSTEPS; ++s)
      #pragma unroll
      for (int ct = 0; ct < 2; ++ct)
        wf[s][ct] = *(const short8v*)(Wt + (size_t)((2 * w + ct) * 16 + n0) * (KSTEPS * 32) + 32 * s + 8 * g);
  };
  if constexpr (!WLATE) load_w();

  float bb[2];
  #pragma unroll
  for (int ct = 0; ct < 2; ++ct) bb[ct] = bias[(2 * w + ct) * 16 + n0];
  float alpha = 0.f;
  if constexpr (PREPM == PREP_GIN0 || PREPM == PREP_GINX) alpha = 1.f + epsp[0];

  for (int it = 0; it < TPB; ++it) {
    const int base = (blockIdx.x * TPB + it) * 64;
    short8v hself[4];

    // ---- prep: stage A tile (bf16) ----
    if constexpr (PREPM == PREP_INIT) {
      const int i = t >> 2, q = t & 3;
      const int row = base + i;
      const int sn = srcIdx[row];
      const u16* nrow = (const u16*)P0 + (size_t)sn * 256 + q * 32;
      #pragma unroll
      for (int c = 0; c < 4; ++c)
        *(short8v*)(&amem[i * RS + q * 32 + 8 * c]) = *(const short8v*)(nrow + 8 * c);
      #pragma unroll
      for (int z = 0; z < 2; ++z) {
        int col = 128 + (2 * q + z) * 4;
        short4v o = {0, 0, 0, 0};
        if (col < 144) {
          f32x4 vv = __builtin_nontemporal_load(
              (const f32x4*)((const float*)P1 + (size_t)row * 16 + (col - 128)));
          o = {(short)f2bf(vv.x), (short)f2bf(vv.y), (short)f2bf(vv.z), (short)f2bf(vv.w)};
        }
        *(short4v*)(&amem[i * RS + col]) = o;
      }
    } else if constexpr (PREPM == PREP_EDGE) {
      const int i = t >> 2, q = t & 3;
      const int row = base + i;
      const int sn = srcIdx[row];
      const u16* arow = (const u16*)P0 + (size_t)sn * 128 + q * 32;
      const u16* hrow = (const u16*)P1 + (size_t)row * 128 + q * 32;
      short8v av[4];
      #pragma unroll
      for (int c = 0; c < 4; ++c) av[c] = *(const short8v*)(arow + 8 * c);
      #pragma unroll
      for (int c = 0; c < 4; ++c) hself[c] = *(const short8v*)(hrow + 8 * c);
      #pragma unroll
      for (int c = 0; c < 4; ++c) {
        short8v hrev = shfl_xor4_v(hself[c]);
        short8v o;
        #pragma unroll
        for (int j = 0; j < 8; ++j)
          o[j] = (short)f2bf(bf2f((u16)av[c][j]) - bf2f((u16)hrev[j]));
        *(short8v*)(&amem[i * RS + q * 32 + 8 * c]) = o;
      }
    } else if constexpr (PREPM == PREP_GIN0) {
      const int i2 = t >> 3, q = t & 7;
      #pragma unroll
      for (int half = 0; half < 2; ++half) {
        const int r = i2 + 32 * half;
        const int row = base + r;
        const int n = (row < numRows) ? row : (numRows - 1);
        const int p0 = csr_off[n], p1 = csr_off[n + 1];
        float acc[32];
        const u16* self = (const u16*)P0 + (size_t)n * 256 + 32 * q;
        #pragma unroll
        for (int c8 = 0; c8 < 4; ++c8) {
          short8v v = *(const short8v*)(self + 8 * c8);
          #pragma unroll
          for (int j = 0; j < 8; ++j) acc[8 * c8 + j] = alpha * bf2f((u16)v[j]);
        }
        for (int p = p0; p < p1; ++p) {
          const u16* nb = (const u16*)P0 + (size_t)csr_s[p] * 256 + 32 * q;
          #pragma unroll
          for (int c8 = 0; c8 < 4; ++c8) {
            short8v v = *(const short8v*)(nb + 8 * c8);
            #pragma unroll
            for (int j = 0; j < 8; ++j) acc[8 * c8 + j] += bf2f((u16)v[j]);
          }
        }
        #pragma unroll
        for (int c4 = 0; c4 < 8; ++c4) {
          short4v o = {(short)f2bf(acc[4 * c4 + 0]), (short)f2bf(acc[4 * c4 + 1]),
                       (short)f2bf(acc[4 * c4 + 2]), (short)f2bf(acc[4 * c4 + 3])};
          *(short4v*)(&amem[r * RS + 32 * q + 4 * c4]) = o;
        }
      }
    } else {  // PREP_GINX
      const int i = t >> 2, q = t & 3;
      const int row = base + i;
      const int n = (row < numRows) ? row : (numRows - 1);
      const int p0 = csr_off[n], p1 = csr_off[n + 1];
      float acc[32];
      const u16* self = (const u16*)P0 + (size_t)n * 128 + 32 * q;
      #pragma unroll
      for (int c8 = 0; c8 < 4; ++c8) {
        short8v v = *(const short8v*)(self + 8 * c8);
        #pragma unroll
        for (int j = 0; j < 8; ++j) acc[8 * c8 + j] = alpha * bf2f((u16)v[j]);
      }
      for (int p = p0; p < p1; ++p) {
        const u16* nb = (const u16*)P0 + (size_t)csr_s[p] * 128 + 32 * q;
        #pragma unroll
        for (int c8 = 0; c8 < 4; ++c8) {
          short8v v = *(const short8v*)(nb + 8 * c8);
          #pragma unroll
          for (int j = 0; j < 8; ++j) acc[8 * c8 + j] += bf2f((u16)v[j]);
        }
      }
      #pragma unroll
      for (int c4 = 0; c4 < 8; ++c4) {
        short4v o = {(short)f2bf(acc[4 * c4 + 0]), (short)f2bf(acc[4 * c4 + 1]),
                     (short)f2bf(acc[4 * c4 + 2]), (short)f2bf(acc[4 * c4 + 3])};
        *(short4v*)(&amem[i * RS + 32 * q + 4 * c4]) = o;
      }
    }
    __syncthreads();
    if constexpr (WLATE) load_w();

    // ---- MFMA main loop ----
    f32x4 acc[4][2];
    #pragma unroll
    for (int rt = 0; rt < 4; ++rt)
      #pragma unroll
      for (int ct = 0; ct < 2; ++ct) acc[rt][ct] = (f32x4){0.f, 0.f, 0.f, 0.f};
    #pragma unroll
    for (int s = 0; s < KSTEPS; ++s) {
      bf16x8v af[4];
      #pragma unroll
      for (int rt = 0; rt < 4; ++rt) {
        short8v araw = *(const short8v*)(&amem[(16 * rt + n0) * RS + s * 32 + g * 8]);
        af[rt] = __builtin_bit_cast(bf16x8v, araw);
      }
      #pragma unroll
      for (int rt = 0; rt < 4; ++rt)
        #pragma unroll
        for (int ct = 0; ct < 2; ++ct)
          acc[rt][ct] = __builtin_amdgcn_mfma_f32_16x16x32_bf16(
              af[rt], __builtin_bit_cast(bf16x8v, wf[s][ct]), acc[rt][ct], 0, 0, 0);
    }

    // ---- EDGE residual: route reg-held h tile through LDS to C positions ----
    if constexpr (EPIM == EPI_ABR) {
      __syncthreads();
      {
        const int i = t >> 2, q = t & 3;
        #pragma unroll
        for (int c = 0; c < 4; ++c)
          *(short8v*)(&amem[i * RS + q * 32 + 8 * c]) = hself[c];
      }
      __syncthreads();
    }

    // ---- epilogue: C/D layout col=lane&15, row=(lane>>4)*4+reg ----
    if constexpr (OUTBF) {
      if constexpr (EPIM != EPI_ABR) __syncthreads();
      #pragma unroll
      for (int rt = 0; rt < 4; ++rt) {
        #pragma unroll
        for (int ct = 0; ct < 2; ++ct) {
          #pragma unroll
          for (int r = 0; r < 4; ++r) {
            int lrow = 16 * rt + 4 * g + r;
            int lcol = (2 * w + ct) * 16 + n0;
            float o = acc[rt][ct][r];
            if constexpr (EPIM == EPI_ABR) o += bf2f((u16)amem[lrow * RS + lcol]);
            o = fmaxf(o + bb[ct], 0.f);
            if constexpr (OUTBF == 2)
              __builtin_nontemporal_store(o, &OutF32[(size_t)(base + lrow) * 128 + lcol]);
            amem[lrow * RS + lcol] = (short)f2bf(o);
          }
        }
      }
      __syncthreads();
      {
        const int i = t >> 2, q = t & 3;
        const int row = base + i;
        if (row < numRows) {
          u16* orow = (u16*)Out + (size_t)row * 128 + q * 32;
          #pragma unroll
          for (int c = 0; c < 4; ++c)
            *(short8v*)(orow + 8 * c) = *(const short8v*)(&amem[i * RS + q * 32 + 8 * c]);
        }
      }
    } else {
      #pragma unroll
      for (int rt = 0; rt < 4; ++rt) {
        #pragma unroll
        for (int ct = 0; ct < 2; ++ct) {
          #pragma unroll
          for (int r = 0; r < 4; ++r) {
            int row = base + 16 * rt + 4 * g + r;
            if (row < numRows) {
              int lcol = (2 * w + ct) * 16 + n0;
              float o = acc[rt][ct][r];
              o = fmaxf(o + bb[ct], 0.f);
              __builtin_nontemporal_store(o, &((float*)Out)[(size_t)row * 128 + lcol]);
            }
          }
        }
      }
    }
    __syncthreads();  // amem reuse across tile iterations
  }
}

extern "C" void kernel_launch(void* const* d_in, const int* in_sizes, int n_in,
                              void* d_out, int out_size, void* d_ws, size_t ws_size,
                              hipStream_t stream) {
  const float* nf     = (const float*)d_in[0];
  const float* ef     = (const float*)d_in[1];
  const float* W_init = (const float*)d_in[2];
  const float* b_init = (const float*)d_in[3];
  const float* W_edge = (const float*)d_in[4];
  const float* b_edge = (const float*)d_in[5];
  const float* W_gin0 = (const float*)d_in[6];
  const float* W_gin  = (const float*)d_in[7];
  const float* b_gin  = (const float*)d_in[8];
  const float* eps    = (const float*)d_in[9];
  const int* esrc     = (const int*)d_in[10];
  const int* edst     = (const int*)d_in[11];
  // d_in[12] = edge_rev == e^1 by construction.

  float* xout  = (float*)d_out;                     // [N,128] f32
  float* h_out = xout + (size_t)N_NODES * 128;      // [E,128] f32 (final h)

  const size_t NB = (size_t)N_NODES * 128 * 2;      // bf16 node block (25.6MB)
  const size_t EB = (size_t)N_EDGES * 128 * 2;      // bf16 edge block (153.6MB)
  char* wsb = (char*)d_ws;
  u16* aggbf   = (u16*)wsb;                         // edge phase; later aliased by xbf1
  u16* xbf1    = (u16*)wsb;
  u16* hbf     = (u16*)(wsb + NB);
  u16* nfro    = (u16*)(wsb + NB + EB);             // [N,256] concat (nf | readout)
  u16* xbf0    = (u16*)(wsb + 3 * NB + EB);
  int* csr_off = (int*)(wsb + 4 * NB + EB);         // N+1
  int* cursor  = csr_off + (N_NODES + 1);           // N (histogram, zeroed by scan1)
  int* csr_e   = cursor + N_NODES;                  // E
  int* csr_s   = csr_e + N_EDGES;                   // E
  int* blk     = csr_s + N_EDGES;                   // SCAN_NB
  u16* wblob   = (u16*)(blk + SCAN_NB + 1);         // transposed bf16 weights

  // ---- conversions (fused) ----
  convert_all_kernel<<<(NFCONV_THREADS + WTOTAL + 255) / 256, 256, 0, stream>>>(
      nf, nfro, W_init, W_edge, W_gin0, W_gin, wblob);

  // ---- CSR by dst (3-phase parallel scan) ----
  hipMemsetAsync(cursor, 0, N_NODES * sizeof(int), stream);
  hist_kernel<<<(N_EDGES + 255) / 256, 256, 0, stream>>>(edst, cursor);
  scan1_kernel<<<SCAN_NB, 256, 0, stream>>>(cursor, csr_off, blk);
  scan2_kernel<<<1, 512, 0, stream>>>(blk);
  scan3_kernel<<<SCAN_NB, 256, 0, stream>>>(csr_off, blk);
  fill_kernel<<<(N_EDGES + 255) / 256, 256, 0, stream>>>(edst, esrc, csr_off, cursor, csr_e, csr_s);

  const u16* wt_init = wblob + WOFF_I;
  const u16* wt_edge = wblob + WOFF_E;
  const u16* wt_gin0 = wblob + WOFF_G0;
  const u16* wt_gin  = wblob + WOFF_G;

  // ---- init edge states: hbf = relu([nf[src]|ef] @ W_init + b) ----
  mfma_gemm<5, PREP_INIT, EPI_BR, 1, 5><<<1875, 256, 0, stream>>>(
      wt_init, b_init, nfro, ef, esrc, nullptr, nullptr, nullptr, nullptr, hbf, N_EDGES);

  // ---- EdgeConv steps 0..2 (in place on hbf) ----
  for (int t = 0; t < 3; ++t) {
    segsum_hbf_kernel<<<N_NODES / 8, 256, 0, stream>>>(hbf, csr_off, csr_e, aggbf);
    mfma_gemm<4, PREP_EDGE, EPI_ABR, 1, 5><<<1875, 256, 0, stream>>>(
        wt_edge + (size_t)t * 16384, b_edge + (size_t)t * 128,
        aggbf, hbf, esrc, nullptr, nullptr, nullptr, nullptr, hbf, N_EDGES);
  }
  // ---- EdgeConv step 3: dual-write bf16 hbf + f32 h_out (nontemporal) ----
  segsum_hbf_kernel<<<N_NODES / 8, 256, 0, stream>>>(hbf, csr_off, csr_e, aggbf);
  mfma_gemm<4, PREP_EDGE, EPI_ABR, 2, 5><<<1875, 256, 0, stream>>>(
      wt_edge + (size_t)3 * 16384, b_edge + (size_t)3 * 128,
      aggbf, hbf, esrc, nullptr, nullptr, nullptr, h_out, hbf, N_EDGES);

  // ---- readout from final hbf into nfro high half ----
  segsum_readout_kernel<<<N_NODES / 8, 256, 0, stream>>>(hbf, csr_off, csr_e, nfro + 128);

  // ---- GIN step 0: fused K=256 GEMM with inline gathers over nfro ----
  mfma_gemm<8, PREP_GIN0, EPI_BR, 1, 3><<<521, 256, 0, stream>>>(
      wt_gin0, b_gin, nfro, nullptr, nullptr, csr_off, csr_s, eps, nullptr, xbf0, N_NODES);

  // ---- GIN steps 1..3 (xbf1 aliases dead aggbf) ----
  mfma_gemm<4, PREP_GINX, EPI_BR, 1, 3><<<521, 256, 0, stream>>>(
      wt_gin, b_gin + 128, xbf0, nullptr, nullptr, csr_off, csr_s, eps + 1, nullptr, xbf1, N_NODES);
  mfma_gemm<4, PREP_GINX, EPI_BR, 1, 3><<<521, 256, 0, stream>>>(
      wt_gin + 16384, b_gin + 256, xbf1, nullptr, nullptr, csr_off, csr_s, eps + 2, nullptr, xbf0, N_NODES);
  mfma_gemm<4, PREP_GINX, EPI_BR, 0, 3><<<521, 256, 0, stream>>>(
      wt_gin + 2 * 16384, b_gin + 384, xbf0, nullptr, nullptr, csr_off, csr_s, eps + 3, nullptr, xout, N_NODES);

  (void)in_sizes; (void)n_in; (void)out_size; (void)ws_size;
}

// Round 11
// 1030.407 us; speedup vs baseline: 3.3182x; 1.0003x over previous
//
#include <hip/hip_runtime.h>

#define N_NODES 100000
#define N_EDGES 600000
#define SCAN_NB ((N_NODES + 255) / 256)   // 391

// transposed bf16 weight blob offsets (u16 units)
#define WOFF_I  0                         // [128][160]  (K=144 padded to 160)
#define WOFF_E  20480                     // 4 x [128][128]
#define WOFF_G0 86016                     // [128][256]
#define WOFF_G  118784                    // 3 x [128][128]
#define WTOTAL  167936
#define NFCONV_THREADS (N_NODES * 128 / 8)   // 1.6M
#define HIST_THREADS ((N_EDGES + 7) / 8)     // 75000 (8 edges/thread)

typedef unsigned short u16;
typedef __attribute__((ext_vector_type(8))) short short8v;
typedef __attribute__((ext_vector_type(4))) short short4v;
typedef __attribute__((ext_vector_type(4))) float f32x4;
typedef __attribute__((ext_vector_type(4))) unsigned u32x4;
typedef __attribute__((ext_vector_type(8))) __bf16 bf16x8v;

__device__ __forceinline__ u16 f2bf(float f) {
  unsigned u = __builtin_bit_cast(unsigned, f);
  unsigned r = (u + 0x7fffu + ((u >> 16) & 1u)) >> 16;
  return (u16)r;
}
__device__ __forceinline__ float bf2f(u16 v) {
  unsigned u = ((unsigned)v) << 16;
  return __builtin_bit_cast(float, u);
}
__device__ __forceinline__ float bflo(unsigned u) {
  return __builtin_bit_cast(float, u << 16);
}
__device__ __forceinline__ float bfhi(unsigned u) {
  return __builtin_bit_cast(float, u & 0xffff0000u);
}
__device__ __forceinline__ short8v shfl_xor4_v(short8v v) {
  int4 iv = __builtin_bit_cast(int4, v);
  iv.x = __shfl_xor(iv.x, 4, 64);
  iv.y = __shfl_xor(iv.y, 4, 64);
  iv.z = __shfl_xor(iv.z, 4, 64);
  iv.w = __shfl_xor(iv.w, 4, 64);
  return __builtin_bit_cast(short8v, iv);
}

// ---- fused preamble: nf -> nfro low half; weights -> blob; dst histogram ----
__global__ __launch_bounds__(256) void convert_all_kernel(const float* __restrict__ nf,
                                                          u16* __restrict__ nfro,
                                                          const float* __restrict__ Wi,
                                                          const float* __restrict__ We,
                                                          const float* __restrict__ Wg0,
                                                          const float* __restrict__ Wg,
                                                          u16* __restrict__ wout,
                                                          const int* __restrict__ dst,
                                                          int* __restrict__ cnt) {
  int tid = blockIdx.x * 256 + threadIdx.x;
  if (tid < NFCONV_THREADS) {
    size_t idx = (size_t)tid * 8;
    float4 a = *(const float4*)(nf + idx);
    float4 b = *(const float4*)(nf + idx + 4);
    short8v o = {(short)f2bf(a.x), (short)f2bf(a.y), (short)f2bf(a.z), (short)f2bf(a.w),
                 (short)f2bf(b.x), (short)f2bf(b.y), (short)f2bf(b.z), (short)f2bf(b.w)};
    size_t row = idx >> 7, col = idx & 127;
    *(short8v*)(nfro + row * 256 + col) = o;
    return;
  }
  int e = tid - NFCONV_THREADS;
  if (e < WTOTAL) {
    float v;
    if (e < WOFF_E) {                       // init: [128][160], K=144
      int col = e / 160, k = e % 160;
      v = (k < 144) ? Wi[(size_t)k * 128 + col] : 0.f;
    } else if (e < WOFF_G0) {               // edge: 4 x [128][128]
      int r = e - WOFF_E;
      int m = r / 16384; r %= 16384;
      int col = r / 128, k = r % 128;
      v = We[(size_t)m * 16384 + (size_t)k * 128 + col];
    } else if (e < WOFF_G) {                // gin0: [128][256]
      int r = e - WOFF_G0;
      int col = r / 256, k = r % 256;
      v = Wg0[(size_t)k * 128 + col];
    } else {                                // gin: 3 x [128][128]
      int r = e - WOFF_G;
      int m = r / 16384; r %= 16384;
      int col = r / 128, k = r % 128;
      v = Wg[(size_t)m * 16384 + (size_t)k * 128 + col];
    }
    wout[e] = f2bf(v);
    return;
  }
  int hb = tid - NFCONV_THREADS - WTOTAL;   // histogram: 8 edges/thread
  if (hb < HIST_THREADS) {
    int e0 = hb * 8;
    int e1 = min(e0 + 8, N_EDGES);
    for (int ee = e0; ee < e1; ++ee) atomicAdd(&cnt[dst[ee]], 1);
  }
}

// ---------------- CSR build ----------------
__global__ __launch_bounds__(256) void scan1_kernel(int* __restrict__ cnt,
                                                    int* __restrict__ off,
                                                    int* __restrict__ blk) {
  __shared__ int s[256];
  int i = blockIdx.x * 256 + threadIdx.x;
  int v = (i < N_NODES) ? cnt[i] : 0;
  if (i < N_NODES) cnt[i] = 0;
  s[threadIdx.x] = v;
  __syncthreads();
  for (int d = 1; d < 256; d <<= 1) {
    int t = (threadIdx.x >= d) ? s[threadIdx.x - d] : 0;
    __syncthreads();
    s[threadIdx.x] += t;
    __syncthreads();
  }
  if (i < N_NODES) off[i] = s[threadIdx.x] - v;
  if (threadIdx.x == 255) blk[blockIdx.x] = s[255];
}

__global__ __launch_bounds__(512) void scan2_kernel(int* __restrict__ blk) {
  __shared__ int s[512];
  int v = (threadIdx.x < SCAN_NB) ? blk[threadIdx.x] : 0;
  s[threadIdx.x] = v;
  __syncthreads();
  for (int d = 1; d < 512; d <<= 1) {
    int t = (threadIdx.x >= d) ? s[threadIdx.x - d] : 0;
    __syncthreads();
    s[threadIdx.x] += t;
    __syncthreads();
  }
  if (threadIdx.x < SCAN_NB) blk[threadIdx.x] = s[threadIdx.x] - v;
}

__global__ __launch_bounds__(256) void scan3_kernel(int* __restrict__ off,
                                                    const int* __restrict__ blk) {
  int i = blockIdx.x * 256 + threadIdx.x;
  if (i < N_NODES) off[i] += blk[blockIdx.x];
  if (i == 0) off[N_NODES] = N_EDGES;
}

__global__ void fill_kernel(const int* __restrict__ dst, const int* __restrict__ src,
                            const int* __restrict__ off, int* __restrict__ cur,
                            int* __restrict__ csr_e, int* __restrict__ csr_s) {
  int e = blockIdx.x * 256 + threadIdx.x;
  if (e < N_EDGES) {
    int d = dst[e];
    int p = off[d] + atomicAdd(&cur[d], 1);
    csr_e[p] = e;
    csr_s[p] = src[e];
  }
}

// ---- segment sum over bf16 h: 4 nodes/wave (16-lane groups, 16B/lane = full row) ----
__global__ __launch_bounds__(256) void segsum_hbf_kernel(const u16* __restrict__ hbf,
                                                         const int* __restrict__ off,
                                                         const int* __restrict__ csr_e,
                                                         u16* __restrict__ aggb) {
  int node = blockIdx.x * 16 + (threadIdx.x >> 4);
  int hl = threadIdx.x & 15;
  int p0 = off[node], p1 = off[node + 1];
  int deg = p1 - p0;
  int e_l = (hl < deg) ? csr_e[p0 + hl] : 0;
  float a0 = 0.f, a1 = 0.f, a2 = 0.f, a3 = 0.f, a4 = 0.f, a5 = 0.f, a6 = 0.f, a7 = 0.f;
  int jmax = min(deg, 16);
  for (int j = 0; j < jmax; ++j) {
    int e = __shfl(e_l, j, 16);
    u32x4 u = *(const u32x4*)(hbf + (size_t)e * 128 + 8 * hl);
    a0 += bflo(u.x); a1 += bfhi(u.x); a2 += bflo(u.y); a3 += bfhi(u.y);
    a4 += bflo(u.z); a5 += bfhi(u.z); a6 += bflo(u.w); a7 += bfhi(u.w);
  }
  for (int p = p0 + 16; p < p1; ++p) {
    int e = csr_e[p];
    u32x4 u = *(const u32x4*)(hbf + (size_t)e * 128 + 8 * hl);
    a0 += bflo(u.x); a1 += bfhi(u.x); a2 += bflo(u.y); a3 += bfhi(u.y);
    a4 += bflo(u.z); a5 += bfhi(u.z); a6 += bflo(u.w); a7 += bfhi(u.w);
  }
  u32x4 o = {(unsigned)f2bf(a0) | (((unsigned)f2bf(a1)) << 16),
             (unsigned)f2bf(a2) | (((unsigned)f2bf(a3)) << 16),
             (unsigned)f2bf(a4) | (((unsigned)f2bf(a5)) << 16),
             (unsigned)f2bf(a6) | (((unsigned)f2bf(a7)) << 16)};
  *(u32x4*)(aggb + (size_t)node * 128 + 8 * hl) = o;
}

// ---- readout segsum over final hbf -> nfro[:,128:256] (NT loads; hbf dead after) ----
__global__ __launch_bounds__(256) void segsum_readout_kernel(const u16* __restrict__ hbf,
                                                             const int* __restrict__ off,
                                                             const int* __restrict__ csr_e,
                                                             u16* __restrict__ ro) {
  int node = blockIdx.x * 16 + (threadIdx.x >> 4);
  int hl = threadIdx.x & 15;
  int p0 = off[node], p1 = off[node + 1];
  int deg = p1 - p0;
  int e_l = (hl < deg) ? csr_e[p0 + hl] : 0;
  float a0 = 0.f, a1 = 0.f, a2 = 0.f, a3 = 0.f, a4 = 0.f, a5 = 0.f, a6 = 0.f, a7 = 0.f;
  int jmax = min(deg, 16);
  for (int j = 0; j < jmax; ++j) {
    int e = __shfl(e_l, j, 16);
    u32x4 u = __builtin_nontemporal_load((const u32x4*)(hbf + (size_t)e * 128 + 8 * hl));
    a0 += bflo(u.x); a1 += bfhi(u.x); a2 += bflo(u.y); a3 += bfhi(u.y);
    a4 += bflo(u.z); a5 += bfhi(u.z); a6 += bflo(u.w); a7 += bfhi(u.w);
  }
  for (int p = p0 + 16; p < p1; ++p) {
    int e = csr_e[p];
    u32x4 u = __builtin_nontemporal_load((const u32x4*)(hbf + (size_t)e * 128 + 8 * hl));
    a0 += bflo(u.x); a1 += bfhi(u.x); a2 += bflo(u.y); a3 += bfhi(u.y);
    a4 += bflo(u.z); a5 += bfhi(u.z); a6 += bflo(u.w); a7 += bfhi(u.w);
  }
  u32x4 o = {(unsigned)f2bf(a0) | (((unsigned)f2bf(a1)) << 16),
             (unsigned)f2bf(a2) | (((unsigned)f2bf(a3)) << 16),
             (unsigned)f2bf(a4) | (((unsigned)f2bf(a5)) << 16),
             (unsigned)f2bf(a6) | (((unsigned)f2bf(a7)) << 16)};
  *(u32x4*)(ro + (size_t)node * 256 + 8 * hl) = o;
}

// ---------------- unified MFMA GEMM ----------------
// Tile 64 rows x 128 cols, 256 threads (4 waves); wave w -> cols [32w,32w+32).
// Wt: TRANSPOSED bf16 weights [128 cols][KSTEPS*32] -> one short8v per fragment.
// TPB tiles per block; W fragments reused across tiles.
// KSTEPS=8 (gin0): W loaded in two 4-kstep halves (32 VGPRs) -> 4 blocks/CU.
// EDGE: h tile read ONCE (regs); rev via shfl_xor(4); residual routed via LDS.
// GIN: CSR neighbor gather fused into prep (nfro concat layout for GIN0).
#define PREP_INIT 0
#define PREP_EDGE 1
#define PREP_GIN0 2
#define PREP_GINX 3
#define EPI_BR  1
#define EPI_ABR 2

template<int KSTEPS, int PREPM, int EPIM, int OUTBF, int TPB>
__global__ __launch_bounds__(256, 4) void mfma_gemm(
    const u16* __restrict__ Wt,
    const float* __restrict__ bias,
    const void* __restrict__ P0,      // INIT/GIN0: nfro u16; EDGE: aggb u16; GINX: x u16
    const void* __restrict__ P1,      // INIT: ef f32; EDGE: hbf u16
    const int* __restrict__ srcIdx,   // INIT/EDGE: edge_src
    const int* __restrict__ csr_off,  // GIN: gather offsets
    const int* __restrict__ csr_s,    // GIN: gather sources
    const float* __restrict__ epsp,   // GIN: eps scalar
    float* __restrict__ OutF32,       // OUTBF==2: f32 dual output (h_out)
    void* __restrict__ Out, int numRows) {
  constexpr int RS = KSTEPS * 32 + 8;
  constexpr bool WSPLIT = (KSTEPS >= 8);
  constexpr int WREG = WSPLIT ? 4 : KSTEPS;
  __shared__ short amem[64 * RS];
  const int t = threadIdx.x;
  const int l = t & 63;
  const int w = t >> 6;
  const int g = l >> 4;
  const int n0 = l & 15;

  short8v wf[WREG][2];
  auto load_w = [&](int sbase) {
    #pragma unroll
    for (int s = 0; s < WREG; ++s)
      #pragma unroll
      for (int ct = 0; ct < 2; ++ct)
        wf[s][ct] = *(const short8v*)(Wt + (size_t)((2 * w + ct) * 16 + n0) * (KSTEPS * 32) + 32 * (sbase + s) + 8 * g);
  };
  if constexpr (!WSPLIT) load_w(0);

  float bb[2];
  #pragma unroll
  for (int ct = 0; ct < 2; ++ct) bb[ct] = bias[(2 * w + ct) * 16 + n0];
  float alpha = 0.f;
  if constexpr (PREPM == PREP_GIN0 || PREPM == PREP_GINX) alpha = 1.f + epsp[0];

  for (int it = 0; it < TPB; ++it) {
    const int base = (blockIdx.x * TPB + it) * 64;
    short8v hself[4];

    // ---- prep: stage A tile (bf16) ----
    if constexpr (PREPM == PREP_INIT) {
      const int i = t >> 2, q = t & 3;
      const int row = base + i;
      const int sn = srcIdx[row];
      const u16* nrow = (const u16*)P0 + (size_t)sn * 256 + q * 32;
      #pragma unroll
      for (int c = 0; c < 4; ++c)
        *(short8v*)(&amem[i * RS + q * 32 + 8 * c]) = *(const short8v*)(nrow + 8 * c);
      #pragma unroll
      for (int z = 0; z < 2; ++z) {
        int col = 128 + (2 * q + z) * 4;
        short4v o = {0, 0, 0, 0};
        if (col < 144) {
          f32x4 vv = __builtin_nontemporal_load(
              (const f32x4*)((const float*)P1 + (size_t)row * 16 + (col - 128)));
          o = {(short)f2bf(vv.x), (short)f2bf(vv.y), (short)f2bf(vv.z), (short)f2bf(vv.w)};
        }
        *(short4v*)(&amem[i * RS + col]) = o;
      }
    } else if constexpr (PREPM == PREP_EDGE) {
      const int i = t >> 2, q = t & 3;
      const int row = base + i;
      const int sn = srcIdx[row];
      const u16* arow = (const u16*)P0 + (size_t)sn * 128 + q * 32;
      const u16* hrow = (const u16*)P1 + (size_t)row * 128 + q * 32;
      short8v av[4];
      #pragma unroll
      for (int c = 0; c < 4; ++c) av[c] = *(const short8v*)(arow + 8 * c);
      #pragma unroll
      for (int c = 0; c < 4; ++c) hself[c] = *(const short8v*)(hrow + 8 * c);
      #pragma unroll
      for (int c = 0; c < 4; ++c) {
        short8v hrev = shfl_xor4_v(hself[c]);
        short8v o;
        #pragma unroll
        for (int j = 0; j < 8; ++j)
          o[j] = (short)f2bf(bf2f((u16)av[c][j]) - bf2f((u16)hrev[j]));
        *(short8v*)(&amem[i * RS + q * 32 + 8 * c]) = o;
      }
    } else if constexpr (PREPM == PREP_GIN0) {
      const int i2 = t >> 3, q = t & 7;
      #pragma unroll
      for (int half = 0; half < 2; ++half) {
        const int r = i2 + 32 * half;
        const int row = base + r;
        const int n = (row < numRows) ? row : (numRows - 1);
        const int p0 = csr_off[n], p1 = csr_off[n + 1];
        float acc[32];
        const u16* self = (const u16*)P0 + (size_t)n * 256 + 32 * q;
        #pragma unroll
        for (int c8 = 0; c8 < 4; ++c8) {
          short8v v = *(const short8v*)(self + 8 * c8);
          #pragma unroll
          for (int j = 0; j < 8; ++j) acc[8 * c8 + j] = alpha * bf2f((u16)v[j]);
        }
        for (int p = p0; p < p1; ++p) {
          const u16* nb = (const u16*)P0 + (size_t)csr_s[p] * 256 + 32 * q;
          #pragma unroll
          for (int c8 = 0; c8 < 4; ++c8) {
            short8v v = *(const short8v*)(nb + 8 * c8);
            #pragma unroll
            for (int j = 0; j < 8; ++j) acc[8 * c8 + j] += bf2f((u16)v[j]);
          }
        }
        #pragma unroll
        for (int c4 = 0; c4 < 8; ++c4) {
          short4v o = {(short)f2bf(acc[4 * c4 + 0]), (short)f2bf(acc[4 * c4 + 1]),
                       (short)f2bf(acc[4 * c4 + 2]), (short)f2bf(acc[4 * c4 + 3])};
          *(short4v*)(&amem[r * RS + 32 * q + 4 * c4]) = o;
        }
      }
    } else {  // PREP_GINX
      const int i = t >> 2, q = t & 3;
      const int row = base + i;
      const int n = (row < numRows) ? row : (numRows - 1);
      const int p0 = csr_off[n], p1 = csr_off[n + 1];
      float acc[32];
      const u16* self = (const u16*)P0 + (size_t)n * 128 + 32 * q;
      #pragma unroll
      for (int c8 = 0; c8 < 4; ++c8) {
        short8v v = *(const short8v*)(self + 8 * c8);
        #pragma unroll
        for (int j = 0; j < 8; ++j) acc[8 * c8 + j] = alpha * bf2f((u16)v[j]);
      }
      for (int p = p0; p < p1; ++p) {
        const u16* nb = (const u16*)P0 + (size_t)csr_s[p] * 128 + 32 * q;
        #pragma unroll
        for (int c8 = 0; c8 < 4; ++c8) {
          short8v v = *(const short8v*)(nb + 8 * c8);
          #pragma unroll
          for (int j = 0; j < 8; ++j) acc[8 * c8 + j] += bf2f((u16)v[j]);
        }
      }
      #pragma unroll
      for (int c4 = 0; c4 < 8; ++c4) {
        short4v o = {(short)f2bf(acc[4 * c4 + 0]), (short)f2bf(acc[4 * c4 + 1]),
                     (short)f2bf(acc[4 * c4 + 2]), (short)f2bf(acc[4 * c4 + 3])};
        *(short4v*)(&amem[i * RS + 32 * q + 4 * c4]) = o;
      }
    }
    __syncthreads();

    // ---- MFMA main loop ----
    f32x4 acc[4][2];
    #pragma unroll
    for (int rt = 0; rt < 4; ++rt)
      #pragma unroll
      for (int ct = 0; ct < 2; ++ct) acc[rt][ct] = (f32x4){0.f, 0.f, 0.f, 0.f};
    #pragma unroll
    for (int sb = 0; sb < (WSPLIT ? 2 : 1); ++sb) {
      if constexpr (WSPLIT) load_w(sb * 4);
      #pragma unroll
      for (int s2 = 0; s2 < WREG; ++s2) {
        const int s = sb * WREG + s2;
        bf16x8v af[4];
        #pragma unroll
        for (int rt = 0; rt < 4; ++rt) {
          short8v araw = *(const short8v*)(&amem[(16 * rt + n0) * RS + s * 32 + g * 8]);
          af[rt] = __builtin_bit_cast(bf16x8v, araw);
        }
        #pragma unroll
        for (int rt = 0; rt < 4; ++rt)
          #pragma unroll
          for (int ct = 0; ct < 2; ++ct)
            acc[rt][ct] = __builtin_amdgcn_mfma_f32_16x16x32_bf16(
                af[rt], __builtin_bit_cast(bf16x8v, wf[s2][ct]), acc[rt][ct], 0, 0, 0);
      }
    }

    // ---- EDGE residual: route reg-held h tile through LDS to C positions ----
    if constexpr (EPIM == EPI_ABR) {
      __syncthreads();
      {
        const int i = t >> 2, q = t & 3;
        #pragma unroll
        for (int c = 0; c < 4; ++c)
          *(short8v*)(&amem[i * RS + q * 32 + 8 * c]) = hself[c];
      }
      __syncthreads();
    }

    // ---- epilogue: C/D layout col=lane&15, row=(lane>>4)*4+reg ----
    if constexpr (OUTBF) {
      if constexpr (EPIM != EPI_ABR) __syncthreads();
      #pragma unroll
      for (int rt = 0; rt < 4; ++rt) {
        #pragma unroll
        for (int ct = 0; ct < 2; ++ct) {
          #pragma unroll
          for (int r = 0; r < 4; ++r) {
            int lrow = 16 * rt + 4 * g + r;
            int lcol = (2 * w + ct) * 16 + n0;
            float o = acc[rt][ct][r];
            if constexpr (EPIM == EPI_ABR) o += bf2f((u16)amem[lrow * RS + lcol]);
            o = fmaxf(o + bb[ct], 0.f);
            if constexpr (OUTBF == 2)
              __builtin_nontemporal_store(o, &OutF32[(size_t)(base + lrow) * 128 + lcol]);
            amem[lrow * RS + lcol] = (short)f2bf(o);
          }
        }
      }
      __syncthreads();
      {
        const int i = t >> 2, q = t & 3;
        const int row = base + i;
        if (row < numRows) {
          u16* orow = (u16*)Out + (size_t)row * 128 + q * 32;
          #pragma unroll
          for (int c = 0; c < 4; ++c)
            *(short8v*)(orow + 8 * c) = *(const short8v*)(&amem[i * RS + q * 32 + 8 * c]);
        }
      }
    } else {
      #pragma unroll
      for (int rt = 0; rt < 4; ++rt) {
        #pragma unroll
        for (int ct = 0; ct < 2; ++ct) {
          #pragma unroll
          for (int r = 0; r < 4; ++r) {
            int row = base + 16 * rt + 4 * g + r;
            if (row < numRows) {
              int lcol = (2 * w + ct) * 16 + n0;
              float o = acc[rt][ct][r];
              o = fmaxf(o + bb[ct], 0.f);
              __builtin_nontemporal_store(o, &((float*)Out)[(size_t)row * 128 + lcol]);
            }
          }
        }
      }
    }
    __syncthreads();  // amem reuse across tile iterations
  }
}

extern "C" void kernel_launch(void* const* d_in, const int* in_sizes, int n_in,
                              void* d_out, int out_size, void* d_ws, size_t ws_size,
                              hipStream_t stream) {
  const float* nf     = (const float*)d_in[0];
  const float* ef     = (const float*)d_in[1];
  const float* W_init = (const float*)d_in[2];
  const float* b_init = (const float*)d_in[3];
  const float* W_edge = (const float*)d_in[4];
  const float* b_edge = (const float*)d_in[5];
  const float* W_gin0 = (const float*)d_in[6];
  const float* W_gin  = (const float*)d_in[7];
  const float* b_gin  = (const float*)d_in[8];
  const float* eps    = (const float*)d_in[9];
  const int* esrc     = (const int*)d_in[10];
  const int* edst     = (const int*)d_in[11];
  // d_in[12] = edge_rev == e^1 by construction.

  float* xout  = (float*)d_out;                     // [N,128] f32
  float* h_out = xout + (size_t)N_NODES * 128;      // [E,128] f32 (final h)

  const size_t NB = (size_t)N_NODES * 128 * 2;      // bf16 node block (25.6MB)
  const size_t EB = (size_t)N_EDGES * 128 * 2;      // bf16 edge block (153.6MB)
  char* wsb = (char*)d_ws;
  u16* aggbf   = (u16*)wsb;                         // edge phase; later aliased by xbf1
  u16* xbf1    = (u16*)wsb;
  u16* hbf     = (u16*)(wsb + NB);
  u16* nfro    = (u16*)(wsb + NB + EB);             // [N,256] concat (nf | readout)
  u16* xbf0    = (u16*)(wsb + 3 * NB + EB);
  int* csr_off = (int*)(wsb + 4 * NB + EB);         // N+1
  int* cursor  = csr_off + (N_NODES + 1);           // N (histogram, zeroed by scan1)
  int* csr_e   = cursor + N_NODES;                  // E
  int* csr_s   = csr_e + N_EDGES;                   // E
  int* blk     = csr_s + N_EDGES;                   // SCAN_NB
  u16* wblob   = (u16*)(blk + SCAN_NB + 1);         // transposed bf16 weights

  // ---- preamble: memset histogram, then fused convert+hist ----
  hipMemsetAsync(cursor, 0, N_NODES * sizeof(int), stream);
  convert_all_kernel<<<(NFCONV_THREADS + WTOTAL + HIST_THREADS + 255) / 256, 256, 0, stream>>>(
      nf, nfro, W_init, W_edge, W_gin0, W_gin, wblob, edst, cursor);

  // ---- CSR by dst (3-phase parallel scan) ----
  scan1_kernel<<<SCAN_NB, 256, 0, stream>>>(cursor, csr_off, blk);
  scan2_kernel<<<1, 512, 0, stream>>>(blk);
  scan3_kernel<<<SCAN_NB, 256, 0, stream>>>(csr_off, blk);
  fill_kernel<<<(N_EDGES + 255) / 256, 256, 0, stream>>>(edst, esrc, csr_off, cursor, csr_e, csr_s);

  const u16* wt_init = wblob + WOFF_I;
  const u16* wt_edge = wblob + WOFF_E;
  const u16* wt_gin0 = wblob + WOFF_G0;
  const u16* wt_gin  = wblob + WOFF_G;

  // ---- init edge states: hbf = relu([nf[src]|ef] @ W_init + b) ----
  mfma_gemm<5, PREP_INIT, EPI_BR, 1, 5><<<1875, 256, 0, stream>>>(
      wt_init, b_init, nfro, ef, esrc, nullptr, nullptr, nullptr, nullptr, hbf, N_EDGES);

  // ---- EdgeConv steps 0..2 (in place on hbf) ----
  for (int t = 0; t < 3; ++t) {
    segsum_hbf_kernel<<<N_NODES / 16, 256, 0, stream>>>(hbf, csr_off, csr_e, aggbf);
    mfma_gemm<4, PREP_EDGE, EPI_ABR, 1, 5><<<1875, 256, 0, stream>>>(
        wt_edge + (size_t)t * 16384, b_edge + (size_t)t * 128,
        aggbf, hbf, esrc, nullptr, nullptr, nullptr, nullptr, hbf, N_EDGES);
  }
  // ---- EdgeConv step 3: dual-write bf16 hbf + f32 h_out (nontemporal) ----
  segsum_hbf_kernel<<<N_NODES / 16, 256, 0, stream>>>(hbf, csr_off, csr_e, aggbf);
  mfma_gemm<4, PREP_EDGE, EPI_ABR, 2, 5><<<1875, 256, 0, stream>>>(
      wt_edge + (size_t)3 * 16384, b_edge + (size_t)3 * 128,
      aggbf, hbf, esrc, nullptr, nullptr, nullptr, h_out, hbf, N_EDGES);

  // ---- readout from final hbf into nfro high half ----
  segsum_readout_kernel<<<N_NODES / 16, 256, 0, stream>>>(hbf, csr_off, csr_e, nfro + 128);

  // ---- GIN step 0: fused K=256 GEMM with inline gathers over nfro ----
  mfma_gemm<8, PREP_GIN0, EPI_BR, 1, 3><<<521, 256, 0, stream>>>(
      wt_gin0, b_gin, nfro, nullptr, nullptr, csr_off, csr_s, eps, nullptr, xbf0, N_NODES);

  // ---- GIN steps 1..3 (xbf1 aliases dead aggbf) ----
  mfma_gemm<4, PREP_GINX, EPI_BR, 1, 3><<<521, 256, 0, stream>>>(
      wt_gin, b_gin + 128, xbf0, nullptr, nullptr, csr_off, csr_s, eps + 1, nullptr, xbf1, N_NODES);
  mfma_gemm<4, PREP_GINX, EPI_BR, 1, 3><<<521, 256, 0, stream>>>(
      wt_gin + 16384, b_gin + 256, xbf1, nullptr, nullptr, csr_off, csr_s, eps + 2, nullptr, xbf0, N_NODES);
  mfma_gemm<4, PREP_GINX, EPI_BR, 0, 3><<<521, 256, 0, stream>>>(
      wt_gin + 2 * 16384, b_gin + 384, xbf0, nullptr, nullptr, csr_off, csr_s, eps + 3, nullptr, xout, N_NODES);

  (void)in_sizes; (void)n_in; (void)out_size; (void)ws_size;
}